// Round 1
// baseline (1242.241 us; speedup 1.0000x reference)
//
#include <hip/hip_runtime.h>
#include <stdint.h>

typedef _Float16 f16;
typedef _Float16 f16x2 __attribute__((ext_vector_type(2)));
typedef _Float16 f16x4 __attribute__((ext_vector_type(4)));
typedef _Float16 f16x8 __attribute__((ext_vector_type(8)));
typedef float f32x4 __attribute__((ext_vector_type(4)));

#define AS1 __attribute__((address_space(1)))
#define AS3 __attribute__((address_space(3)))

// ---------------- CSR build ----------------
__global__ void k_count(const int* __restrict__ dst, int* __restrict__ deg, int E){
  int i = blockIdx.x*256 + threadIdx.x;
  if (i < E) atomicAdd(&deg[dst[i]], 1);
}

__global__ void k_scan(const int* __restrict__ deg, int* __restrict__ rowptr, int N){
  __shared__ int ps[1024];
  int t = threadIdx.x;
  const int CH = 16;
  int i0 = t*CH;
  int sum = 0;
  for (int k=0;k<CH;k++){ int i=i0+k; if (i<N) sum += deg[i]; }
  ps[t]=sum; __syncthreads();
  for (int off=1; off<1024; off<<=1){
    int v = (t>=off)? ps[t-off] : 0;
    __syncthreads();
    ps[t] += v;
    __syncthreads();
  }
  int run = ps[t]-sum;  // exclusive prefix
  for (int k=0;k<CH;k++){
    int i=i0+k;
    if (i<=N) rowptr[i]=run;
    if (i<N) run += deg[i];
  }
}

__global__ void k_copy_i(const int* __restrict__ a, int* __restrict__ b, int n){
  int i = blockIdx.x*256 + threadIdx.x;
  if (i<n) b[i]=a[i];
}

__global__ void k_fill(const int* __restrict__ src, const int* __restrict__ dst,
                       int* __restrict__ cursor, int* __restrict__ colsrc,
                       int* __restrict__ eidx, int E){
  int i = blockIdx.x*256 + threadIdx.x;
  if (i>=E) return;
  int slot = atomicAdd(&cursor[dst[i]], 1);
  colsrc[slot] = src[i];
  eidx[slot] = i;
}

// ---------------- conversions ----------------
__global__ void k_convert_pad(const float* __restrict__ X, f16* __restrict__ Xh,
                              int rows, long total4, int cols){
  long idx = (long)blockIdx.x*256 + threadIdx.x;
  if (idx >= total4) return;
  long e = idx*4;
  int row = (int)(e / cols);
  f16x4 o;
  if (row < rows){
    float4 v = *(const float4*)(X + e);
    o[0]=(f16)v.x; o[1]=(f16)v.y; o[2]=(f16)v.z; o[3]=(f16)v.w;
  } else {
    o[0]=(f16)0.f; o[1]=(f16)0.f; o[2]=(f16)0.f; o[3]=(f16)0.f;
  }
  *(f16x4*)(Xh + e) = o;
}

// W is [K][Nc] row-major; WT is [Nc][K] (K-contiguous "B^T" operand)
__global__ void k_transpose(const float* __restrict__ W, f16* __restrict__ WT,
                            int K, int Nc){
  long idx = (long)blockIdx.x*256 + threadIdx.x;
  if (idx >= (long)Nc*K) return;
  int n = (int)(idx / K); int k = (int)(idx % K);
  WT[idx] = (f16)W[(long)k*Nc + n];
}

// pack [Wc(512x40) | rW(512x40) | zeros] -> WT[128][512]
__global__ void k_pack_wc(const float* __restrict__ Wc, const float* __restrict__ rW,
                          f16* __restrict__ WT){
  int idx = blockIdx.x*256 + threadIdx.x;
  if (idx >= 128*512) return;
  int n = idx >> 9; int k = idx & 511;
  float v = 0.f;
  if (n < 40) v = Wc[k*40 + n];
  else if (n < 80) v = rW[k*40 + (n-40)];
  WT[idx] = (f16)v;
}

// ---------------- GEMM: C[M][Nc] = A[M][K] * B[Nc][K]^T  (fp16 in, fp16 out)
// 128x128 tile, BK=64, 4 waves, global_load_lds(16B) with pre-swizzled source,
// XOR st-swizzle on ds_read (involution both sides), double-buffered LDS.
__global__ __launch_bounds__(256,2) void k_gemm(
    const f16* __restrict__ A, const f16* __restrict__ B, f16* __restrict__ C,
    int Nc, int K, int ntn)
{
  __shared__ f16 lds[2][2][128*64];   // 64 KiB
  const int bid = blockIdx.x;
  const int tr = bid / ntn, tc = bid % ntn;
  const int t = threadIdx.x;
  const int wave = t >> 6, lane = t & 63;
  const int wr = wave >> 1, wc = wave & 1;

  const f16* Ab = A + (long)tr*128*K;
  const f16* Bb = B + (long)tc*128*K;

  int srcoff[4], chunk[4];
  #pragma unroll
  for (int i=0;i<4;i++){
    int r = (wave*4+i)*8 + (lane>>3);       // staged row 0..127
    int ss = (lane&7) ^ (r&7);              // inverse-swizzled 16B slot
    srcoff[i] = r*K + ss*8;
    chunk[i] = (wave*4+i)*512;              // halves; wave-uniform LDS base
  }

  f32x4 zero4 = {0.f,0.f,0.f,0.f};
  f32x4 acc[4][4];
  #pragma unroll
  for (int m=0;m<4;m++)
    #pragma unroll
    for (int n=0;n<4;n++) acc[m][n] = zero4;

  int abyte[2][4], bbyte[2][4];
  #pragma unroll
  for (int ks=0;ks<2;ks++){
    #pragma unroll
    for (int m=0;m<4;m++){
      int r = wr*64 + m*16 + (lane&15);
      abyte[ks][m] = r*128 + (((ks*4 + (lane>>4))*16) ^ ((r&7)<<4));
      int c = wc*64 + m*16 + (lane&15);
      bbyte[ks][m] = c*128 + (((ks*4 + (lane>>4))*16) ^ ((c&7)<<4));
    }
  }

  const int nt = K >> 6;
  int cur = 0;

  #pragma unroll
  for (int i=0;i<4;i++){
    __builtin_amdgcn_global_load_lds((const AS1 void*)(Ab + srcoff[i]),
        (AS3 void*)(&lds[0][0][chunk[i]]), 16, 0, 0);
    __builtin_amdgcn_global_load_lds((const AS1 void*)(Bb + srcoff[i]),
        (AS3 void*)(&lds[0][1][chunk[i]]), 16, 0, 0);
  }
  __syncthreads();

  for (int kt=0; kt<nt; kt++){
    if (kt+1 < nt){
      int ko = (kt+1)<<6;
      #pragma unroll
      for (int i=0;i<4;i++){
        __builtin_amdgcn_global_load_lds((const AS1 void*)(Ab + ko + srcoff[i]),
            (AS3 void*)(&lds[cur^1][0][chunk[i]]), 16, 0, 0);
        __builtin_amdgcn_global_load_lds((const AS1 void*)(Bb + ko + srcoff[i]),
            (AS3 void*)(&lds[cur^1][1][chunk[i]]), 16, 0, 0);
      }
    }
    const char* As = (const char*)&lds[cur][0][0];
    const char* Bs = (const char*)&lds[cur][1][0];
    #pragma unroll
    for (int ks=0;ks<2;ks++){
      f16x8 af[4], bf[4];
      #pragma unroll
      for (int m=0;m<4;m++) af[m] = *(const f16x8*)(As + abyte[ks][m]);
      #pragma unroll
      for (int n=0;n<4;n++) bf[n] = *(const f16x8*)(Bs + bbyte[ks][n]);
      #pragma unroll
      for (int m=0;m<4;m++)
        #pragma unroll
        for (int n=0;n<4;n++)
          acc[m][n] = __builtin_amdgcn_mfma_f32_16x16x32_f16(af[m], bf[n], acc[m][n], 0, 0, 0);
    }
    __syncthreads();
    cur ^= 1;
  }

  // C/D layout: col = lane&15, row = (lane>>4)*4 + reg   [measured m89/m91]
  #pragma unroll
  for (int m=0;m<4;m++){
    int row0 = tr*128 + wr*64 + m*16 + ((lane>>4)<<2);
    #pragma unroll
    for (int n=0;n<4;n++){
      int col = tc*128 + wc*64 + n*16 + (lane&15);
      #pragma unroll
      for (int q=0;q<4;q++)
        C[(long)(row0+q)*Nc + col] = (f16)acc[m][n][q];
    }
  }
}

// ---------------- attention pieces ----------------
// el[n,h] = sum_d feat[n,h,d]*al[h,d]; one wave per head (block 512 = 8 waves)
__global__ __launch_bounds__(512) void k_eler(const f16* __restrict__ featH,
    const float* __restrict__ al, const float* __restrict__ ar,
    float* __restrict__ el, float* __restrict__ er){
  int n = blockIdx.x; int t = threadIdx.x;
  float v = (float)featH[(long)n*512 + t];
  float a = v*al[t], b = v*ar[t];
  #pragma unroll
  for (int off=32; off>0; off>>=1){
    a += __shfl_xor(a, off);
    b += __shfl_xor(b, off);
  }
  if ((t&63)==0){ int h = t>>6; el[n*8+h]=a; er[n*8+h]=b; }
}

// per (edge, head): ex = exp(leaky_relu(el[src]+er[dst])); denom[dst,h] += ex
// (segment-max omitted: alpha is max-invariant and scores are bounded)
__global__ void k_score(const int* __restrict__ src, const int* __restrict__ dst,
    const float* __restrict__ el, const float* __restrict__ er,
    float* __restrict__ exbuf, float* __restrict__ denom, int E){
  int idx = blockIdx.x*256 + threadIdx.x;
  if (idx >= E*8) return;
  int e = idx>>3, h = idx&7;
  float v = el[src[e]*8+h] + er[dst[e]*8+h];
  v = (v>0.f)? v : 0.2f*v;
  float ex = expf(v);
  exbuf[idx] = ex;
  atomicAdd(&denom[dst[e]*8+h], ex);
}

// encoder aggregation: block per dst node, 256 threads x 2 channels;
// out = elu(sum_e alpha*feat[src] + b); writes fp16 (+ optional fp32 to d_out)
__global__ __launch_bounds__(256) void k_agg(
    const int* __restrict__ rowptr, const int* __restrict__ colsrc,
    const int* __restrict__ eidx, const float* __restrict__ exbuf,
    const float* __restrict__ denom, const f16* __restrict__ featH,
    const float* __restrict__ bias, f16* __restrict__ outH,
    float* __restrict__ outF){
  int n = blockIdx.x; int t = threadIdx.x;
  __shared__ float inv[8];
  if (t < 8) inv[t] = 1.0f / denom[n*8+t];
  __syncthreads();
  int h = t >> 5;
  int c = t*2;
  float a0=0.f, a1=0.f;
  int j1 = rowptr[n+1];
  for (int j=rowptr[n]; j<j1; j++){
    int s = colsrc[j]; int e = eidx[j];
    float alpha = exbuf[e*8+h] * inv[h];
    f16x2 f = *(const f16x2*)(featH + (long)s*512 + c);
    a0 += alpha*(float)f[0];
    a1 += alpha*(float)f[1];
  }
  a0 += bias[c]; a1 += bias[c+1];
  a0 = (a0>0.f)? a0 : expf(a0)-1.f;   // ELU
  a1 = (a1>0.f)? a1 : expf(a1)-1.f;
  f16x2 o; o[0]=(f16)a0; o[1]=(f16)a1;
  *(f16x2*)(outH + (long)n*512 + c) = o;
  if (outF){
    outF[(long)n*512 + c]     = a0;
    outF[(long)n*512 + c + 1] = a1;
  }
}

// classifier el/er: featc stride 128, cols [0..40) are the Wc projection
__global__ void k_elerc(const f16* __restrict__ featcH,
    const float* __restrict__ alc, const float* __restrict__ arc,
    float* __restrict__ el, float* __restrict__ er, int N){
  int idx = blockIdx.x*256 + threadIdx.x;
  if (idx >= N*8) return;
  int n = idx>>3, h = idx&7;
  float a=0.f, b=0.f;
  #pragma unroll
  for (int cc=0; cc<5; cc++){
    float v = (float)featcH[(long)n*128 + h*5 + cc];
    a += v*alc[h*5+cc];
    b += v*arc[h*5+cc];
  }
  el[idx]=a; er[idx]=b;
}

// classifier conv: aggregate (N,8,5), add residual (cols 40..80) + bias, mean heads
__global__ __launch_bounds__(64) void k_cls(
    const int* __restrict__ rowptr, const int* __restrict__ colsrc,
    const int* __restrict__ eidx, const float* __restrict__ exbuf,
    const float* __restrict__ denom, const f16* __restrict__ featcH,
    const float* __restrict__ bc, float* __restrict__ pred){
  int n = blockIdx.x; int l = threadIdx.x;
  __shared__ float inv[8];
  __shared__ float lg[40];
  if (l<8) inv[l] = 1.0f/denom[n*8+l];
  __syncthreads();
  if (l<40){
    int h = l/5;
    float acc = 0.f;
    int j1 = rowptr[n+1];
    for (int j=rowptr[n]; j<j1; j++){
      int s = colsrc[j]; int e = eidx[j];
      acc += exbuf[e*8+h]*inv[h] * (float)featcH[(long)s*128 + l];
    }
    acc += (float)featcH[(long)n*128 + 40 + l];  // residual projection
    acc += bc[l];
    lg[l] = acc;
  }
  __syncthreads();
  if (l<5){
    float p=0.f;
    #pragma unroll
    for (int h=0;h<8;h++) p += lg[h*5+l];
    pred[(long)n*5 + l] = p*0.125f;
  }
}

// ---------------- host orchestration ----------------
extern "C" void kernel_launch(void* const* d_in, const int* in_sizes, int n_in,
                              void* d_out, int out_size, void* d_ws, size_t ws_size,
                              hipStream_t stream){
  const int N = 10000;
  const int Np = 10112;            // 79*128 (padded M)
  const int K0 = 4096, F = 512;

  const int* srcs[3] = {(const int*)d_in[0], (const int*)d_in[2], (const int*)d_in[4]};
  const int* dsts[3] = {(const int*)d_in[1], (const int*)d_in[3], (const int*)d_in[5]};
  int E[3] = {in_sizes[0], in_sizes[2], in_sizes[4]};
  const float* X[3] = {(const float*)d_in[6], (const float*)d_in[7], (const float*)d_in[8]};
  const float* W0  = (const float*)d_in[9];
  const float* al0 = (const float*)d_in[10];
  const float* ar0 = (const float*)d_in[11];
  const float* b0  = (const float*)d_in[12];
  const float* W1  = (const float*)d_in[13];
  const float* al1 = (const float*)d_in[14];
  const float* ar1 = (const float*)d_in[15];
  const float* b1  = (const float*)d_in[16];
  const float* Wcv[2] = {(const float*)d_in[17], (const float*)d_in[22]};
  const float* alc[2] = {(const float*)d_in[18], (const float*)d_in[23]};
  const float* arc[2] = {(const float*)d_in[19], (const float*)d_in[24]};
  const float* bcv[2] = {(const float*)d_in[20], (const float*)d_in[25]};
  const float* rWv[2] = {(const float*)d_in[21], (const float*)d_in[26]};

  float* out = (float*)d_out;
  float* pred[4]   = {out, out+50000, out+100000, out+150000};
  float* embOut[3] = {out+200000, out+200000+(long)N*512, out+200000+2L*(long)N*512};

  char* w = (char*)d_ws;
  size_t off = 0;
  auto alloc = [&](size_t bytes)->void*{
    void* p = (void*)(w + off);
    off += (bytes + 255) & ~((size_t)255);
    return p;
  };
  f16* Xh     = (f16*)alloc((size_t)Np*K0*2);
  f16* W0T    = (f16*)alloc((size_t)F*K0*2);
  f16* W1T    = (f16*)alloc((size_t)F*F*2);
  f16* WcT[2] = {(f16*)alloc(128*512*2), (f16*)alloc(128*512*2)};
  f16* feat0H = (f16*)alloc((size_t)Np*F*2);
  f16* h0H    = (f16*)alloc((size_t)Np*F*2);
  f16* feat1H = (f16*)alloc((size_t)Np*F*2);
  f16* embH[3] = {(f16*)alloc((size_t)Np*F*2), (f16*)alloc((size_t)Np*F*2), (f16*)alloc((size_t)Np*F*2)};
  f16* featcH = (f16*)alloc((size_t)Np*128*2);
  float* el    = (float*)alloc((size_t)N*8*4);
  float* er    = (float*)alloc((size_t)N*8*4);
  float* denom = (float*)alloc((size_t)N*8*4);
  int Emax = E[0]; if (E[1]>Emax) Emax=E[1]; if (E[2]>Emax) Emax=E[2];
  float* exbuf = (float*)alloc((size_t)Emax*8*4);
  int *deg[3], *rowptr[3], *colsrc[3], *eidx[3];
  for (int g=0; g<3; g++){
    deg[g]    = (int*)alloc((size_t)N*4);
    rowptr[g] = (int*)alloc((size_t)(N+1)*4);
    colsrc[g] = (int*)alloc((size_t)E[g]*4);
    eidx[g]   = (int*)alloc((size_t)E[g]*4);
  }
  (void)ws_size; (void)n_in; (void)out_size;

  // ---- CSR for each graph ----
  for (int g=0; g<3; g++){
    hipMemsetAsync(deg[g], 0, (size_t)N*4, stream);
    k_count<<<(E[g]+255)/256, 256, 0, stream>>>(dsts[g], deg[g], E[g]);
    k_scan<<<1, 1024, 0, stream>>>(deg[g], rowptr[g], N);
    k_copy_i<<<(N+255)/256, 256, 0, stream>>>(rowptr[g], deg[g], N);  // deg reused as cursor
    k_fill<<<(E[g]+255)/256, 256, 0, stream>>>(srcs[g], dsts[g], deg[g], colsrc[g], eidx[g], E[g]);
  }

  // ---- weight conversion / transpose ----
  k_transpose<<<(int)(((long)F*K0+255)/256), 256, 0, stream>>>(W0, W0T, K0, F);
  k_transpose<<<(int)(((long)F*F+255)/256), 256, 0, stream>>>(W1, W1T, F, F);
  k_pack_wc<<<(128*512+255)/256, 256, 0, stream>>>(Wcv[0], rWv[0], WcT[0]);
  k_pack_wc<<<(128*512+255)/256, 256, 0, stream>>>(Wcv[1], rWv[1], WcT[1]);

  const int Mt = Np/128;  // 79
  // ---- encoder on each graph ----
  for (int g=0; g<3; g++){
    long tot4 = (long)Np*K0/4;
    k_convert_pad<<<(int)((tot4+255)/256), 256, 0, stream>>>(X[g], Xh, N, tot4, K0);
    k_gemm<<<Mt*4, 256, 0, stream>>>(Xh, W0T, feat0H, F, K0, 4);
    k_eler<<<N, 512, 0, stream>>>(feat0H, al0, ar0, el, er);
    hipMemsetAsync(denom, 0, (size_t)N*8*4, stream);
    k_score<<<(int)(((long)E[g]*8+255)/256), 256, 0, stream>>>(srcs[g], dsts[g], el, er, exbuf, denom, E[g]);
    k_agg<<<N, 256, 0, stream>>>(rowptr[g], colsrc[g], eidx[g], exbuf, denom, feat0H, b0, h0H, (float*)nullptr);
    k_gemm<<<Mt*4, 256, 0, stream>>>(h0H, W1T, feat1H, F, F, 4);
    k_eler<<<N, 512, 0, stream>>>(feat1H, al1, ar1, el, er);
    hipMemsetAsync(denom, 0, (size_t)N*8*4, stream);
    k_score<<<(int)(((long)E[g]*8+255)/256), 256, 0, stream>>>(srcs[g], dsts[g], el, er, exbuf, denom, E[g]);
    k_agg<<<N, 256, 0, stream>>>(rowptr[g], colsrc[g], eidx[g], exbuf, denom, feat1H, b1, embH[g], embOut[g]);
  }

  // ---- classifiers: (graph, cls) = (0,0),(1,1),(t,0),(t,1) ----
  const int task_g[4] = {0,1,2,2};
  const int task_c[4] = {0,1,0,1};
  for (int ti=0; ti<4; ti++){
    int g = task_g[ti], ci = task_c[ti];
    k_gemm<<<Mt, 256, 0, stream>>>(embH[g], WcT[ci], featcH, 128, F, 1);
    k_elerc<<<(N*8+255)/256, 256, 0, stream>>>(featcH, alc[ci], arc[ci], el, er, N);
    hipMemsetAsync(denom, 0, (size_t)N*8*4, stream);
    k_score<<<(int)(((long)E[g]*8+255)/256), 256, 0, stream>>>(srcs[g], dsts[g], el, er, exbuf, denom, E[g]);
    k_cls<<<N, 64, 0, stream>>>(rowptr[g], colsrc[g], eidx[g], exbuf, denom, featcH, bcv[ci], pred[ti]);
  }
}

// Round 2
// 871.002 us; speedup vs baseline: 1.4262x; 1.4262x over previous
//
#include <hip/hip_runtime.h>
#include <stdint.h>

typedef _Float16 f16;
typedef _Float16 f16x2 __attribute__((ext_vector_type(2)));
typedef _Float16 f16x4 __attribute__((ext_vector_type(4)));
typedef _Float16 f16x8 __attribute__((ext_vector_type(8)));
typedef float f32x4 __attribute__((ext_vector_type(4)));

#define AS1 __attribute__((address_space(1)))
#define AS3 __attribute__((address_space(3)))

// ---------------- CSR build ----------------
__global__ void k_count(const int* __restrict__ dst, int* __restrict__ deg, int E){
  int i = blockIdx.x*256 + threadIdx.x;
  if (i < E) atomicAdd(&deg[dst[i]], 1);
}

__global__ void k_scan(const int* __restrict__ deg, int* __restrict__ rowptr, int N){
  __shared__ int ps[1024];
  int t = threadIdx.x;
  const int CH = 16;
  int i0 = t*CH;
  int sum = 0;
  for (int k=0;k<CH;k++){ int i=i0+k; if (i<N) sum += deg[i]; }
  ps[t]=sum; __syncthreads();
  for (int off=1; off<1024; off<<=1){
    int v = (t>=off)? ps[t-off] : 0;
    __syncthreads();
    ps[t] += v;
    __syncthreads();
  }
  int run = ps[t]-sum;  // exclusive prefix
  for (int k=0;k<CH;k++){
    int i=i0+k;
    if (i<=N) rowptr[i]=run;
    if (i<N) run += deg[i];
  }
}

__global__ void k_copy_i(const int* __restrict__ a, int* __restrict__ b, int n){
  int i = blockIdx.x*256 + threadIdx.x;
  if (i<n) b[i]=a[i];
}

__global__ void k_fill(const int* __restrict__ src, const int* __restrict__ dst,
                       int* __restrict__ cursor, int* __restrict__ colsrc, int E){
  int i = blockIdx.x*256 + threadIdx.x;
  if (i>=E) return;
  int slot = atomicAdd(&cursor[dst[i]], 1);
  colsrc[slot] = src[i];
}

// ---------------- conversions ----------------
__global__ void k_convert_pad(const float* __restrict__ X, f16* __restrict__ Xh,
                              int rows, long total4, int cols){
  long idx = (long)blockIdx.x*256 + threadIdx.x;
  if (idx >= total4) return;
  long e = idx*4;
  int row = (int)(e / cols);
  f16x4 o;
  if (row < rows){
    float4 v = *(const float4*)(X + e);
    o[0]=(f16)v.x; o[1]=(f16)v.y; o[2]=(f16)v.z; o[3]=(f16)v.w;
  } else {
    o[0]=(f16)0.f; o[1]=(f16)0.f; o[2]=(f16)0.f; o[3]=(f16)0.f;
  }
  *(f16x4*)(Xh + e) = o;
}

// coalesced tiled transpose: W[K][Nc] fp32 -> WT[Nc][K] f16. K,Nc multiples of 32.
__global__ void k_transpose_t(const float* __restrict__ W, f16* __restrict__ WT,
                              int K, int Nc){
  __shared__ float tile[32][33];
  int n0 = blockIdx.x*32, k0 = blockIdx.y*32;
  int tx = threadIdx.x, ty = threadIdx.y;
  #pragma unroll
  for (int i=0;i<32;i+=8)
    tile[ty+i][tx] = W[(long)(k0+ty+i)*Nc + n0+tx];
  __syncthreads();
  #pragma unroll
  for (int i=0;i<32;i+=8)
    WT[(long)(n0+ty+i)*K + k0+tx] = (f16)tile[tx][ty+i];
}

// pack [Wc(512x40) | rW(512x40) | zeros] -> WT[128][512]
__global__ void k_pack_wc(const float* __restrict__ Wc, const float* __restrict__ rW,
                          f16* __restrict__ WT){
  int idx = blockIdx.x*256 + threadIdx.x;
  if (idx >= 128*512) return;
  int n = idx >> 9; int k = idx & 511;
  float v = 0.f;
  if (n < 40) v = Wc[k*40 + n];
  else if (n < 80) v = rW[k*40 + (n-40)];
  WT[idx] = (f16)v;
}

// ---------------- GEMM: C[M][Nc] = A[M][K] * B[Nc][K]^T (fp16 in/out, fp32 acc)
// 64x128 tile, BK=64, 4 waves (each 32x64), 48KiB LDS -> 3 blocks/CU,
// global_load_lds(16B) with pre-swizzled source + XOR-swizzled ds_read,
// bijective XCD-chunked blockIdx swizzle (m204).
__global__ __launch_bounds__(256,3) void k_gemm(
    const f16* __restrict__ A, const f16* __restrict__ B, f16* __restrict__ C,
    int Nc, int K, int ntn)
{
  __shared__ f16 lds[2][12288];   // per buf: A 64x64 (8KB) + B 128x64 (16KB)
  const int nwg = gridDim.x;
  const int bid = blockIdx.x;
  const int q = nwg >> 3, r = nwg & 7;
  const int xcd = bid & 7, bidx = bid >> 3;
  const int wid = (xcd < r ? xcd*(q+1) : r*(q+1) + (xcd-r)*q) + bidx;
  const int tr = wid / ntn, tc = wid % ntn;

  const int t = threadIdx.x;
  const int wave = t >> 6, lane = t & 63;
  const int wr = wave >> 1, wc = wave & 1;

  const f16* Ab = A + (long)tr*64*K;
  const f16* Bb = B + (long)tc*128*K;

  // staging: slot pre-swizzle identical for all loads (rows are 0 mod 8 per group)
  const int slot = (lane&7) ^ (lane>>3);
  const int rbase = wave*8 + (lane>>3);
  // A loads i=0..1: row = i*32 + rbase ; B loads i=0..3: row = i*32 + rbase
  // LDS dest f16 idx: A: i*2048 + wave*512 ; B: 4096 + i*2048 + wave*512

  f32x4 zero4 = {0.f,0.f,0.f,0.f};
  f32x4 acc[2][4];
  #pragma unroll
  for (int m=0;m<2;m++)
    #pragma unroll
    for (int n=0;n<4;n++) acc[m][n] = zero4;

  int abyte[2][2], bbyte[2][4];
  #pragma unroll
  for (int ks=0;ks<2;ks++){
    #pragma unroll
    for (int m=0;m<2;m++){
      int row = wr*32 + m*16 + (lane&15);
      abyte[ks][m] = row*128 + (((ks*4 + (lane>>4))*16) ^ ((row&7)<<4));
    }
    #pragma unroll
    for (int n=0;n<4;n++){
      int brow = wc*64 + n*16 + (lane&15);
      bbyte[ks][n] = 8192 + brow*128 + (((ks*4 + (lane>>4))*16) ^ ((brow&7)<<4));
    }
  }

  const int nt = K >> 6;
  int cur = 0;

  #pragma unroll
  for (int i=0;i<2;i++)
    __builtin_amdgcn_global_load_lds((const AS1 void*)(Ab + (i*32+rbase)*K + slot*8),
        (AS3 void*)(&lds[0][i*2048 + wave*512]), 16, 0, 0);
  #pragma unroll
  for (int i=0;i<4;i++)
    __builtin_amdgcn_global_load_lds((const AS1 void*)(Bb + (i*32+rbase)*K + slot*8),
        (AS3 void*)(&lds[0][4096 + i*2048 + wave*512]), 16, 0, 0);
  __syncthreads();

  for (int kt=0; kt<nt; kt++){
    if (kt+1 < nt){
      int ko = (kt+1)<<6;
      #pragma unroll
      for (int i=0;i<2;i++)
        __builtin_amdgcn_global_load_lds((const AS1 void*)(Ab + ko + (i*32+rbase)*K + slot*8),
            (AS3 void*)(&lds[cur^1][i*2048 + wave*512]), 16, 0, 0);
      #pragma unroll
      for (int i=0;i<4;i++)
        __builtin_amdgcn_global_load_lds((const AS1 void*)(Bb + ko + (i*32+rbase)*K + slot*8),
            (AS3 void*)(&lds[cur^1][4096 + i*2048 + wave*512]), 16, 0, 0);
    }
    const char* Ls = (const char*)&lds[cur][0];
    #pragma unroll
    for (int ks=0;ks<2;ks++){
      f16x8 af[2], bf[4];
      #pragma unroll
      for (int m=0;m<2;m++) af[m] = *(const f16x8*)(Ls + abyte[ks][m]);
      #pragma unroll
      for (int n=0;n<4;n++) bf[n] = *(const f16x8*)(Ls + bbyte[ks][n]);
      #pragma unroll
      for (int m=0;m<2;m++)
        #pragma unroll
        for (int n=0;n<4;n++)
          acc[m][n] = __builtin_amdgcn_mfma_f32_16x16x32_f16(af[m], bf[n], acc[m][n], 0, 0, 0);
    }
    __syncthreads();
    cur ^= 1;
  }

  // C/D layout: col = lane&15, row = (lane>>4)*4 + reg
  #pragma unroll
  for (int m=0;m<2;m++){
    int row0 = tr*64 + wr*32 + m*16 + ((lane>>4)<<2);
    #pragma unroll
    for (int n=0;n<4;n++){
      int col = tc*128 + wc*64 + n*16 + (lane&15);
      #pragma unroll
      for (int q2=0;q2<4;q2++)
        C[(long)(row0+q2)*Nc + col] = (f16)acc[m][n][q2];
    }
  }
}

// ---------------- attention pieces ----------------
// el[n,h] = sum_d feat[n,h,d]*al[h,d]; one wave per head (block 512 = 8 waves)
__global__ __launch_bounds__(512) void k_eler(const f16* __restrict__ featH,
    const float* __restrict__ al, const float* __restrict__ ar,
    float* __restrict__ el, float* __restrict__ er){
  int n = blockIdx.x; int t = threadIdx.x;
  float v = (float)featH[(long)n*512 + t];
  float a = v*al[t], b = v*ar[t];
  #pragma unroll
  for (int off=32; off>0; off>>=1){
    a += __shfl_xor(a, off);
    b += __shfl_xor(b, off);
  }
  if ((t&63)==0){ int h = t>>6; el[n*8+h]=a; er[n*8+h]=b; }
}

#define MAXD 128

// fused softmax+aggregation: block per dst node, 256 threads.
// phase 1: compute exp(leakyrelu(el[src]+er[n])) per (edge,head), block-reduce denom.
// phase 2: out = elu(sum alpha*feat[src] + b); writes f16 (+ optional f32).
__global__ __launch_bounds__(256) void k_agg(
    const int* __restrict__ rowptr, const int* __restrict__ colsrc,
    const float* __restrict__ el, const float* __restrict__ er,
    const f16* __restrict__ featH, const float* __restrict__ bias,
    f16* __restrict__ outH, float* __restrict__ outF){
  int n = blockIdx.x; int t = threadIdx.x;
  __shared__ float sm[MAXD*8];
  __shared__ int   scol[MAXD];
  __shared__ float red[256];
  __shared__ float inv[8];
  __shared__ float ern[8];
  if (t < 8) ern[t] = er[n*8+t];
  __syncthreads();
  int j0 = rowptr[n], deg = rowptr[n+1]-j0;
  // phase 1
  {
    int h = t & 7;
    float dsum = 0.f;
    for (int jj = t>>3; jj < deg; jj += 32){
      int s = colsrc[j0+jj];
      float v = el[s*8+h] + ern[h];
      v = (v>0.f)? v : 0.2f*v;
      float ex = __expf(v);
      dsum += ex;
      if (jj < MAXD){
        sm[jj*8+h] = ex;
        if (h==0) scol[jj] = s;
      }
    }
    red[t] = dsum; __syncthreads();
    if (t<128) red[t] += red[t+128]; __syncthreads();
    if (t<64)  red[t] += red[t+64];  __syncthreads();
    if (t<32)  red[t] += red[t+32];  __syncthreads();
    if (t<16)  red[t] += red[t+16];  __syncthreads();
    if (t<8)   inv[t] = 1.0f / (red[t] + red[t+8]);
    __syncthreads();
  }
  // phase 2
  int h = t >> 5;
  int c = t*2;
  float a0=0.f, a1=0.f;
  float ivh = inv[h];
  for (int jj=0; jj<deg; jj++){
    int s; float ex;
    if (jj < MAXD){ s = scol[jj]; ex = sm[jj*8+h]; }
    else {
      s = colsrc[j0+jj];
      float v = el[s*8+h] + ern[h];
      v = (v>0.f)? v : 0.2f*v;
      ex = __expf(v);
    }
    float alpha = ex * ivh;
    f16x2 f = *(const f16x2*)(featH + (long)s*512 + c);
    a0 += alpha*(float)f[0];
    a1 += alpha*(float)f[1];
  }
  a0 += bias[c]; a1 += bias[c+1];
  a0 = (a0>0.f)? a0 : __expf(a0)-1.f;   // ELU
  a1 = (a1>0.f)? a1 : __expf(a1)-1.f;
  f16x2 o; o[0]=(f16)a0; o[1]=(f16)a1;
  *(f16x2*)(outH + (long)n*512 + c) = o;
  if (outF){
    outF[(long)n*512 + c]     = a0;
    outF[(long)n*512 + c + 1] = a1;
  }
}

// classifier el/er: featc stride 128, cols [0..40) are the Wc projection
__global__ void k_elerc(const f16* __restrict__ featcH,
    const float* __restrict__ alc, const float* __restrict__ arc,
    float* __restrict__ el, float* __restrict__ er, int N){
  int idx = blockIdx.x*256 + threadIdx.x;
  if (idx >= N*8) return;
  int n = idx>>3, h = idx&7;
  float a=0.f, b=0.f;
  #pragma unroll
  for (int cc=0; cc<5; cc++){
    float v = (float)featcH[(long)n*128 + h*5 + cc];
    a += v*alc[h*5+cc];
    b += v*arc[h*5+cc];
  }
  el[idx]=a; er[idx]=b;
}

// fused classifier conv: 1 wave per node; softmax + aggregate (N,8,5),
// residual (cols 40..80) + bias, mean over heads.
__global__ __launch_bounds__(64) void k_cls(
    const int* __restrict__ rowptr, const int* __restrict__ colsrc,
    const float* __restrict__ el, const float* __restrict__ er,
    const f16* __restrict__ featcH, const float* __restrict__ bc,
    float* __restrict__ pred){
  int n = blockIdx.x; int l = threadIdx.x;
  __shared__ float sm[MAXD*8];
  __shared__ int   scol[MAXD];
  __shared__ float inv[8];
  __shared__ float ern[8];
  __shared__ float lg[40];
  if (l<8) ern[l] = er[n*8+l];
  __syncthreads();
  int j0 = rowptr[n], deg = rowptr[n+1]-j0;
  // phase 1
  {
    int h = l & 7;
    float dsum = 0.f;
    for (int jj = l>>3; jj < deg; jj += 8){
      int s = colsrc[j0+jj];
      float v = el[s*8+h] + ern[h];
      v = (v>0.f)? v : 0.2f*v;
      float ex = __expf(v);
      dsum += ex;
      if (jj < MAXD){
        sm[jj*8+h] = ex;
        if (h==0) scol[jj] = s;
      }
    }
    dsum += __shfl_xor(dsum, 8);
    dsum += __shfl_xor(dsum, 16);
    dsum += __shfl_xor(dsum, 32);
    if (l<8) inv[l] = 1.0f/dsum;
  }
  __syncthreads();
  // phase 2
  if (l<40){
    int h = l/5;
    float ivh = inv[h];
    float acc = 0.f;
    for (int jj=0; jj<deg; jj++){
      int s; float ex;
      if (jj < MAXD){ s = scol[jj]; ex = sm[jj*8+h]; }
      else {
        s = colsrc[j0+jj];
        float v = el[s*8+h] + ern[h];
        v = (v>0.f)? v : 0.2f*v;
        ex = __expf(v);
      }
      acc += ex*ivh * (float)featcH[(long)s*128 + l];
    }
    acc += (float)featcH[(long)n*128 + 40 + l];  // residual projection
    acc += bc[l];
    lg[l] = acc;
  }
  __syncthreads();
  if (l<5){
    float p=0.f;
    #pragma unroll
    for (int h=0;h<8;h++) p += lg[h*5+l];
    pred[(long)n*5 + l] = p*0.125f;
  }
}

// ---------------- host orchestration ----------------
extern "C" void kernel_launch(void* const* d_in, const int* in_sizes, int n_in,
                              void* d_out, int out_size, void* d_ws, size_t ws_size,
                              hipStream_t stream){
  const int N = 10000;
  const int Np = 10112;            // 158*64 (padded M)
  const int K0 = 4096, F = 512;

  const int* srcs[3] = {(const int*)d_in[0], (const int*)d_in[2], (const int*)d_in[4]};
  const int* dsts[3] = {(const int*)d_in[1], (const int*)d_in[3], (const int*)d_in[5]};
  int E[3] = {in_sizes[0], in_sizes[2], in_sizes[4]};
  const float* X[3] = {(const float*)d_in[6], (const float*)d_in[7], (const float*)d_in[8]};
  const float* W0  = (const float*)d_in[9];
  const float* al0 = (const float*)d_in[10];
  const float* ar0 = (const float*)d_in[11];
  const float* b0  = (const float*)d_in[12];
  const float* W1  = (const float*)d_in[13];
  const float* al1 = (const float*)d_in[14];
  const float* ar1 = (const float*)d_in[15];
  const float* b1  = (const float*)d_in[16];
  const float* Wcv[2] = {(const float*)d_in[17], (const float*)d_in[22]};
  const float* alc[2] = {(const float*)d_in[18], (const float*)d_in[23]};
  const float* arc[2] = {(const float*)d_in[19], (const float*)d_in[24]};
  const float* bcv[2] = {(const float*)d_in[20], (const float*)d_in[25]};
  const float* rWv[2] = {(const float*)d_in[21], (const float*)d_in[26]};

  float* out = (float*)d_out;
  float* pred[4]   = {out, out+50000, out+100000, out+150000};
  float* embOut[3] = {out+200000, out+200000+(long)N*512, out+200000+2L*(long)N*512};

  char* w = (char*)d_ws;
  size_t off = 0;
  auto alloc = [&](size_t bytes)->void*{
    void* p = (void*)(w + off);
    off += (bytes + 255) & ~((size_t)255);
    return p;
  };
  f16* Xh     = (f16*)alloc((size_t)Np*K0*2);
  f16* W0T    = (f16*)alloc((size_t)F*K0*2);
  f16* W1T    = (f16*)alloc((size_t)F*F*2);
  f16* WcT[2] = {(f16*)alloc(128*512*2), (f16*)alloc(128*512*2)};
  f16* feat0H = (f16*)alloc((size_t)Np*F*2);
  f16* h0H    = (f16*)alloc((size_t)Np*F*2);
  f16* feat1H = (f16*)alloc((size_t)Np*F*2);
  f16* embH[3] = {(f16*)alloc((size_t)Np*F*2), (f16*)alloc((size_t)Np*F*2), (f16*)alloc((size_t)Np*F*2)};
  f16* featcH = (f16*)alloc((size_t)Np*128*2);
  float* el    = (float*)alloc((size_t)N*8*4);
  float* er    = (float*)alloc((size_t)N*8*4);
  int *deg[3], *rowptr[3], *colsrc[3];
  for (int g=0; g<3; g++){
    deg[g]    = (int*)alloc((size_t)N*4);
    rowptr[g] = (int*)alloc((size_t)(N+1)*4);
    colsrc[g] = (int*)alloc((size_t)E[g]*4);
  }
  (void)ws_size; (void)n_in; (void)out_size;

  // ---- CSR for each graph ----
  for (int g=0; g<3; g++){
    hipMemsetAsync(deg[g], 0, (size_t)N*4, stream);
    k_count<<<(E[g]+255)/256, 256, 0, stream>>>(dsts[g], deg[g], E[g]);
    k_scan<<<1, 1024, 0, stream>>>(deg[g], rowptr[g], N);
    k_copy_i<<<(N+255)/256, 256, 0, stream>>>(rowptr[g], deg[g], N);  // deg reused as cursor
    k_fill<<<(E[g]+255)/256, 256, 0, stream>>>(srcs[g], dsts[g], deg[g], colsrc[g], E[g]);
  }

  // ---- weight conversion / transpose ----
  k_transpose_t<<<dim3(F/32, K0/32), dim3(32,8), 0, stream>>>(W0, W0T, K0, F);
  k_transpose_t<<<dim3(F/32, F/32), dim3(32,8), 0, stream>>>(W1, W1T, F, F);
  k_pack_wc<<<(128*512+255)/256, 256, 0, stream>>>(Wcv[0], rWv[0], WcT[0]);
  k_pack_wc<<<(128*512+255)/256, 256, 0, stream>>>(Wcv[1], rWv[1], WcT[1]);

  const int Mt = Np/64;  // 158
  // ---- encoder on each graph ----
  for (int g=0; g<3; g++){
    long tot4 = (long)Np*K0/4;
    k_convert_pad<<<(int)((tot4+255)/256), 256, 0, stream>>>(X[g], Xh, N, tot4, K0);
    k_gemm<<<Mt*4, 256, 0, stream>>>(Xh, W0T, feat0H, F, K0, 4);
    k_eler<<<N, 512, 0, stream>>>(feat0H, al0, ar0, el, er);
    k_agg<<<N, 256, 0, stream>>>(rowptr[g], colsrc[g], el, er, feat0H, b0, h0H, (float*)nullptr);
    k_gemm<<<Mt*4, 256, 0, stream>>>(h0H, W1T, feat1H, F, F, 4);
    k_eler<<<N, 512, 0, stream>>>(feat1H, al1, ar1, el, er);
    k_agg<<<N, 256, 0, stream>>>(rowptr[g], colsrc[g], el, er, feat1H, b1, embH[g], embOut[g]);
  }

  // ---- classifiers: (graph, cls) = (0,0),(1,1),(t,0),(t,1) ----
  const int task_g[4] = {0,1,2,2};
  const int task_c[4] = {0,1,0,1};
  for (int ti=0; ti<4; ti++){
    int g = task_g[ti], ci = task_c[ti];
    k_gemm<<<Mt, 256, 0, stream>>>(embH[g], WcT[ci], featcH, 128, F, 1);
    k_elerc<<<(N*8+255)/256, 256, 0, stream>>>(featcH, alc[ci], arc[ci], el, er, N);
    k_cls<<<N, 64, 0, stream>>>(rowptr[g], colsrc[g], el, er, featcH, bcv[ci], pred[ti]);
  }
}

// Round 3
// 803.542 us; speedup vs baseline: 1.5460x; 1.0840x over previous
//
#include <hip/hip_runtime.h>
#include <stdint.h>

typedef _Float16 f16;
typedef _Float16 f16x2 __attribute__((ext_vector_type(2)));
typedef _Float16 f16x8 __attribute__((ext_vector_type(8)));
typedef float f32x4 __attribute__((ext_vector_type(4)));

#define AS1 __attribute__((address_space(1)))
#define AS3 __attribute__((address_space(3)))

#define NN 10000
#define NP 10112
#define KK0 4096
#define FF 512

// ---------------- CSR build (batched over 3 graphs) ----------------
__global__ void k_count_b(const int* __restrict__ d0, const int* __restrict__ d1,
                          const int* __restrict__ d2, int E0, int E1, int E2,
                          int nb0, int nb1, int* __restrict__ deg){
  int b = blockIdx.x;
  const int* d; int Eg, base, lb;
  if (b < nb0){ d=d0; Eg=E0; base=0; lb=b; }
  else if (b < nb0+nb1){ d=d1; Eg=E1; base=NN; lb=b-nb0; }
  else { d=d2; Eg=E2; base=2*NN; lb=b-nb0-nb1; }
  int i = lb*256 + threadIdx.x;
  if (i < Eg) atomicAdd(&deg[base + d[i]], 1);
}

// one block per graph; writes rowptr and cursor
__global__ __launch_bounds__(1024) void k_scan_b(const int* __restrict__ deg_all,
    int* __restrict__ rowptr_all, int* __restrict__ cursor_all){
  int g = blockIdx.x;
  const int* deg = deg_all + g*NN;
  int* rowptr = rowptr_all + g*(NN+1);
  int* cursor = cursor_all + g*NN;
  __shared__ int ps[1024];
  int t = threadIdx.x;
  const int CH = 16;
  int i0 = t*CH;
  int sum = 0;
  for (int k=0;k<CH;k++){ int i=i0+k; if (i<NN) sum += deg[i]; }
  ps[t]=sum; __syncthreads();
  for (int off=1; off<1024; off<<=1){
    int v = (t>=off)? ps[t-off] : 0;
    __syncthreads();
    ps[t] += v;
    __syncthreads();
  }
  int run = ps[t]-sum;
  for (int k=0;k<CH;k++){
    int i=i0+k;
    if (i<=NN) rowptr[i]=run;
    if (i<NN){ cursor[i]=run; run += deg[i]; }
  }
}

__global__ void k_fill_b(const int* __restrict__ s0, const int* __restrict__ d0,
                         const int* __restrict__ s1, const int* __restrict__ d1,
                         const int* __restrict__ s2, const int* __restrict__ d2,
                         int E0, int E1, int E2, int nb0, int nb1,
                         int* __restrict__ cursor_all,
                         int* __restrict__ c0, int* __restrict__ c1, int* __restrict__ c2){
  int b = blockIdx.x;
  const int *s, *d; int Eg, lb; int* cur; int* col;
  if (b < nb0){ s=s0; d=d0; Eg=E0; lb=b; cur=cursor_all; col=c0; }
  else if (b < nb0+nb1){ s=s1; d=d1; Eg=E1; lb=b-nb0; cur=cursor_all+NN; col=c1; }
  else { s=s2; d=d2; Eg=E2; lb=b-nb0-nb1; cur=cursor_all+2*NN; col=c2; }
  int i = lb*256 + threadIdx.x;
  if (i >= Eg) return;
  int slot = atomicAdd(&cur[d[i]], 1);
  col[slot] = s[i];
}

// ---------------- weight prep ----------------
// coalesced tiled transpose: W[K][Nc] fp32 -> WT[Nc][K] f16
__global__ void k_transpose_t(const float* __restrict__ W, f16* __restrict__ WT,
                              int K, int Nc){
  __shared__ float tile[32][33];
  int n0 = blockIdx.x*32, k0 = blockIdx.y*32;
  int tx = threadIdx.x, ty = threadIdx.y;
  #pragma unroll
  for (int i=0;i<32;i+=8)
    tile[ty+i][tx] = W[(long)(k0+ty+i)*Nc + n0+tx];
  __syncthreads();
  #pragma unroll
  for (int i=0;i<32;i+=8)
    WT[(long)(n0+ty+i)*K + k0+tx] = (f16)tile[tx][ty+i];
}

// pack [Wc(512x40) | rW(512x40) | zeros] -> WT[128][512]
__global__ void k_pack_wc(const float* __restrict__ Wc, const float* __restrict__ rW,
                          f16* __restrict__ WT){
  int idx = blockIdx.x*256 + threadIdx.x;
  if (idx >= 128*512) return;
  int n = idx >> 9; int k = idx & 511;
  float v = 0.f;
  if (n < 40) v = Wc[k*40 + n];
  else if (n < 80) v = rW[k*40 + (n-40)];
  WT[idx] = (f16)v;
}

// ---------------- GEMM0: fused fp32->f16 convert + GEMM, batched over 3 graphs
// C[g] (Np x 512) = X[g] (f32, N x 4096, pad rows=0) * W0T^T
// 64x128 tile, BK=64, 4 waves. A: reg-staged (f32 load -> cvt -> swizzled ds_write,
// depth-2 pipeline). B: global_load_lds(16B) pre-swizzled source. Double-buffered.
__global__ __launch_bounds__(256,3) void k_gemm0(
    const float* __restrict__ X0, const float* __restrict__ X1, const float* __restrict__ X2,
    f16* __restrict__ C0, f16* __restrict__ C1, f16* __restrict__ C2,
    const f16* __restrict__ B)
{
  __shared__ f16 lds[2][12288];   // per buf: A 64x64 (8KB) + B 128x64 (16KB)
  const int bid = blockIdx.x;
  const int task = bid / 632;
  const int orig = bid - task*632;
  const int wid = (orig & 7)*79 + (orig >> 3);   // 632 = 8*79, bijective
  const int tr = wid >> 2, tc = wid & 3;
  const float* A = task==0 ? X0 : (task==1 ? X1 : X2);
  f16* C = task==0 ? C0 : (task==1 ? C1 : C2);

  const int t = threadIdx.x;
  const int wave = t >> 6, lane = t & 63;
  const int wr = wave >> 1, wc = wave & 1;

  const f16* Bb = B + (long)tc*128*KK0;

  // B staging constants
  const int slot = (lane&7) ^ (lane>>3);
  const int rbase = wave*8 + (lane>>3);

  // A reg-staging constants: thread covers rows {t>>3, t>>3+32}, k8-group t&7
  const int arow0 = t >> 3;
  const int ak8 = t & 7;
  f32x4 ar[2][2][2];   // [set][row-slot][half]

  #define LOADA(kt, set) { \
    _Pragma("unroll") \
    for (int s=0;s<2;s++){ \
      int grow = tr*64 + arow0 + s*32; \
      int rc = grow < NN ? grow : NN-1; \
      const float* gp = A + (long)rc*KK0 + (kt)*64 + ak8*8; \
      ar[set][s][0] = *(const f32x4*)gp; \
      ar[set][s][1] = *(const f32x4*)(gp+4); \
    } }

  #define WRITEA(set, buf) { \
    _Pragma("unroll") \
    for (int s=0;s<2;s++){ \
      int row = arow0 + s*32; \
      bool ok = (tr*64 + row) < NN; \
      f16x8 v; \
      _Pragma("unroll") \
      for (int j=0;j<4;j++){ \
        v[j]   = ok ? (f16)ar[set][s][0][j] : (f16)0.f; \
        v[4+j] = ok ? (f16)ar[set][s][1][j] : (f16)0.f; \
      } \
      *(f16x8*)(&lds[buf][row*64 + ((ak8 ^ (row&7))*8)]) = v; \
    } }

  #define GLDSB(kt, buf) { \
    int ko = (kt)*64; \
    _Pragma("unroll") \
    for (int i=0;i<4;i++) \
      __builtin_amdgcn_global_load_lds((const AS1 void*)(Bb + ko + (i*32+rbase)*KK0 + slot*8), \
          (AS3 void*)(&lds[buf][4096 + i*2048 + wave*512]), 16, 0, 0); \
    }

  f32x4 zero4 = {0.f,0.f,0.f,0.f};
  f32x4 acc[2][4];
  #pragma unroll
  for (int m=0;m<2;m++)
    #pragma unroll
    for (int n=0;n<4;n++) acc[m][n] = zero4;

  int abyte[2][2], bbyte[2][4];
  #pragma unroll
  for (int ks=0;ks<2;ks++){
    #pragma unroll
    for (int m=0;m<2;m++){
      int row = wr*32 + m*16 + (lane&15);
      abyte[ks][m] = row*128 + (((ks*4 + (lane>>4))*16) ^ ((row&7)<<4));
    }
    #pragma unroll
    for (int n=0;n<4;n++){
      int brow = wc*64 + n*16 + (lane&15);
      bbyte[ks][n] = 8192 + brow*128 + (((ks*4 + (lane>>4))*16) ^ ((brow&7)<<4));
    }
  }

  const int nt = KK0 >> 6;   // 64
  // prologue
  LOADA(0, 0);
  LOADA(1, 1);
  GLDSB(0, 0);
  WRITEA(0, 0);
  __syncthreads();

  int cur = 0;
  for (int kt=0; kt<nt; kt++){
    if (kt+1 < nt){
      WRITEA((kt+1)&1, cur^1);    // regs drained at previous barrier
      GLDSB(kt+1, cur^1);
    }
    if (kt+2 < nt) LOADA(kt+2, kt&1);
    const char* Ls = (const char*)&lds[cur][0];
    #pragma unroll
    for (int ks=0;ks<2;ks++){
      f16x8 af[2], bf[4];
      #pragma unroll
      for (int m=0;m<2;m++) af[m] = *(const f16x8*)(Ls + abyte[ks][m]);
      #pragma unroll
      for (int n=0;n<4;n++) bf[n] = *(const f16x8*)(Ls + bbyte[ks][n]);
      #pragma unroll
      for (int m=0;m<2;m++)
        #pragma unroll
        for (int n=0;n<4;n++)
          acc[m][n] = __builtin_amdgcn_mfma_f32_16x16x32_f16(af[m], bf[n], acc[m][n], 0, 0, 0);
    }
    __syncthreads();
    cur ^= 1;
  }

  #pragma unroll
  for (int m=0;m<2;m++){
    int row0 = tr*64 + wr*32 + m*16 + ((lane>>4)<<2);
    #pragma unroll
    for (int n=0;n<4;n++){
      int col = tc*128 + wc*64 + n*16 + (lane&15);
      #pragma unroll
      for (int q2=0;q2<4;q2++)
        C[(long)(row0+q2)*FF + col] = (f16)acc[m][n][q2];
    }
  }
  #undef LOADA
  #undef WRITEA
  #undef GLDSB
}

// ---------------- batched f16 GEMM (GEMM1 x3 tasks, classifier x4 tasks)
struct GemmTasks { const f16* A[4]; const f16* B[4]; f16* C[4]; };

__global__ __launch_bounds__(256,3) void k_gemmb(GemmTasks p, int ntpb, int ntn,
                                                 int Nc, int K){
  __shared__ f16 lds[2][12288];
  const int bid = blockIdx.x;
  const int task = bid / ntpb;
  const int orig = bid - task*ntpb;
  const int q = ntpb >> 3, r = ntpb & 7;
  const int xcd = orig & 7, bx = orig >> 3;
  const int wid = (xcd < r ? xcd*(q+1) : r*(q+1) + (xcd-r)*q) + bx;
  const int tr = wid / ntn, tc = wid - tr*ntn;

  const f16* A = p.A[task];
  const f16* B = p.B[task];
  f16* C = p.C[task];

  const int t = threadIdx.x;
  const int wave = t >> 6, lane = t & 63;
  const int wr = wave >> 1, wc = wave & 1;

  const f16* Ab = A + (long)tr*64*K;
  const f16* Bb = B + (long)tc*128*K;

  const int slot = (lane&7) ^ (lane>>3);
  const int rbase = wave*8 + (lane>>3);

  f32x4 zero4 = {0.f,0.f,0.f,0.f};
  f32x4 acc[2][4];
  #pragma unroll
  for (int m=0;m<2;m++)
    #pragma unroll
    for (int n=0;n<4;n++) acc[m][n] = zero4;

  int abyte[2][2], bbyte[2][4];
  #pragma unroll
  for (int ks=0;ks<2;ks++){
    #pragma unroll
    for (int m=0;m<2;m++){
      int row = wr*32 + m*16 + (lane&15);
      abyte[ks][m] = row*128 + (((ks*4 + (lane>>4))*16) ^ ((row&7)<<4));
    }
    #pragma unroll
    for (int n=0;n<4;n++){
      int brow = wc*64 + n*16 + (lane&15);
      bbyte[ks][n] = 8192 + brow*128 + (((ks*4 + (lane>>4))*16) ^ ((brow&7)<<4));
    }
  }

  const int nt = K >> 6;
  int cur = 0;

  #pragma unroll
  for (int i=0;i<2;i++)
    __builtin_amdgcn_global_load_lds((const AS1 void*)(Ab + (i*32+rbase)*K + slot*8),
        (AS3 void*)(&lds[0][i*2048 + wave*512]), 16, 0, 0);
  #pragma unroll
  for (int i=0;i<4;i++)
    __builtin_amdgcn_global_load_lds((const AS1 void*)(Bb + (i*32+rbase)*K + slot*8),
        (AS3 void*)(&lds[0][4096 + i*2048 + wave*512]), 16, 0, 0);
  __syncthreads();

  for (int kt=0; kt<nt; kt++){
    if (kt+1 < nt){
      int ko = (kt+1)<<6;
      #pragma unroll
      for (int i=0;i<2;i++)
        __builtin_amdgcn_global_load_lds((const AS1 void*)(Ab + ko + (i*32+rbase)*K + slot*8),
            (AS3 void*)(&lds[cur^1][i*2048 + wave*512]), 16, 0, 0);
      #pragma unroll
      for (int i=0;i<4;i++)
        __builtin_amdgcn_global_load_lds((const AS1 void*)(Bb + ko + (i*32+rbase)*K + slot*8),
            (AS3 void*)(&lds[cur^1][4096 + i*2048 + wave*512]), 16, 0, 0);
    }
    const char* Ls = (const char*)&lds[cur][0];
    #pragma unroll
    for (int ks=0;ks<2;ks++){
      f16x8 af[2], bf[4];
      #pragma unroll
      for (int m=0;m<2;m++) af[m] = *(const f16x8*)(Ls + abyte[ks][m]);
      #pragma unroll
      for (int n=0;n<4;n++) bf[n] = *(const f16x8*)(Ls + bbyte[ks][n]);
      #pragma unroll
      for (int m=0;m<2;m++)
        #pragma unroll
        for (int n=0;n<4;n++)
          acc[m][n] = __builtin_amdgcn_mfma_f32_16x16x32_f16(af[m], bf[n], acc[m][n], 0, 0, 0);
    }
    __syncthreads();
    cur ^= 1;
  }

  #pragma unroll
  for (int m=0;m<2;m++){
    int row0 = tr*64 + wr*32 + m*16 + ((lane>>4)<<2);
    #pragma unroll
    for (int n=0;n<4;n++){
      int col = tc*128 + wc*64 + n*16 + (lane&15);
      #pragma unroll
      for (int q2=0;q2<4;q2++)
        C[(long)(row0+q2)*Nc + col] = (f16)acc[m][n][q2];
    }
  }
}

// ---------------- attention pieces (batched over graphs/tasks) ----------------
__global__ __launch_bounds__(512) void k_eler_b(
    const f16* __restrict__ f0, const f16* __restrict__ f1, const f16* __restrict__ f2,
    const float* __restrict__ al, const float* __restrict__ ar_,
    float* __restrict__ el, float* __restrict__ er){
  int b = blockIdx.x;
  int g = b / NN, n = b - g*NN;
  const f16* f = g==0?f0:(g==1?f1:f2);
  int t = threadIdx.x;
  float v = (float)f[(long)n*FF + t];
  float a = v*al[t], bb = v*ar_[t];
  #pragma unroll
  for (int off=32; off>0; off>>=1){
    a += __shfl_xor(a, off);
    bb += __shfl_xor(bb, off);
  }
  if ((t&63)==0){ int h = t>>6; long o = ((long)(g*NN+n))*8+h; el[o]=a; er[o]=bb; }
}

#define MAXD 128

struct AggArgs {
  const int* rp[3]; const int* cs[3];
  const float* el; const float* er;
  const f16* feat[3];
  const float* bias;
  f16* outH[3];
  float* outF[3];
};

__global__ __launch_bounds__(256) void k_agg_b(AggArgs a){
  int b = blockIdx.x;
  int g = b / NN, n = b - g*NN;
  const int* rowptr = a.rp[g];
  const int* colsrc = a.cs[g];
  const float* el = a.el + (long)g*NN*8;
  const f16* featH = a.feat[g];
  int t = threadIdx.x;
  __shared__ float sm[MAXD*8];
  __shared__ int   scol[MAXD];
  __shared__ float red[256];
  __shared__ float inv[8];
  __shared__ float ern[8];
  if (t < 8) ern[t] = a.er[((long)g*NN+n)*8+t];
  __syncthreads();
  int j0 = rowptr[n], deg = rowptr[n+1]-j0;
  {
    int h = t & 7;
    float dsum = 0.f;
    for (int jj = t>>3; jj < deg; jj += 32){
      int s = colsrc[j0+jj];
      float v = el[s*8+h] + ern[h];
      v = (v>0.f)? v : 0.2f*v;
      float ex = __expf(v);
      dsum += ex;
      if (jj < MAXD){
        sm[jj*8+h] = ex;
        if (h==0) scol[jj] = s;
      }
    }
    red[t] = dsum; __syncthreads();
    if (t<128) red[t] += red[t+128]; __syncthreads();
    if (t<64)  red[t] += red[t+64];  __syncthreads();
    if (t<32)  red[t] += red[t+32];  __syncthreads();
    if (t<16)  red[t] += red[t+16];  __syncthreads();
    if (t<8)   inv[t] = 1.0f / (red[t] + red[t+8]);
    __syncthreads();
  }
  int h = t >> 5;
  int c = t*2;
  float a0=0.f, a1=0.f;
  float ivh = inv[h];
  for (int jj=0; jj<deg; jj++){
    int s; float ex;
    if (jj < MAXD){ s = scol[jj]; ex = sm[jj*8+h]; }
    else {
      s = colsrc[j0+jj];
      float v = el[s*8+h] + ern[h];
      v = (v>0.f)? v : 0.2f*v;
      ex = __expf(v);
    }
    float alpha = ex * ivh;
    f16x2 f = *(const f16x2*)(featH + (long)s*FF + c);
    a0 += alpha*(float)f[0];
    a1 += alpha*(float)f[1];
  }
  a0 += a.bias[c]; a1 += a.bias[c+1];
  a0 = (a0>0.f)? a0 : __expf(a0)-1.f;
  a1 = (a1>0.f)? a1 : __expf(a1)-1.f;
  f16x2 o; o[0]=(f16)a0; o[1]=(f16)a1;
  *(f16x2*)(a.outH[g] + (long)n*FF + c) = o;
  float* oF = a.outF[g];
  if (oF){
    oF[(long)n*FF + c]     = a0;
    oF[(long)n*FF + c + 1] = a1;
  }
}

// classifier el/er over 4 tasks
__global__ void k_elerc_b(const f16* __restrict__ fc,
    const float* __restrict__ alc0, const float* __restrict__ arc0,
    const float* __restrict__ alc1, const float* __restrict__ arc1,
    float* __restrict__ el, float* __restrict__ er){
  int idx = blockIdx.x*256 + threadIdx.x;
  if (idx >= 4*NN*8) return;
  int ti = idx / (NN*8);
  int rem = idx - ti*NN*8;
  int n = rem>>3, hh = rem&7;
  const f16* featc = fc + (long)ti*NP*128;
  const float* al = (ti&1) ? alc1 : alc0;
  const float* ar_ = (ti&1) ? arc1 : arc0;
  float a=0.f, bsum=0.f;
  #pragma unroll
  for (int cc=0; cc<5; cc++){
    float v = (float)featc[(long)n*128 + hh*5 + cc];
    a += v*al[hh*5+cc];
    bsum += v*ar_[hh*5+cc];
  }
  el[idx]=a; er[idx]=bsum;
}

struct ClsArgs {
  const int* rp[3]; const int* cs[3];
  const float* el; const float* er;
  const f16* fc;
  const float* bc[2];
  float* pred;
};

__global__ __launch_bounds__(64) void k_cls_b(ClsArgs a){
  int b = blockIdx.x;
  int ti = b / NN, n = b - ti*NN;
  int g = ti<2 ? ti : 2;
  int ci = ti&1;
  const int* rowptr = a.rp[g];
  const int* colsrc = a.cs[g];
  const float* el = a.el + (long)ti*NN*8;
  const f16* featc = a.fc + (long)ti*NP*128;
  const float* bc = a.bc[ci];
  float* pred = a.pred + (long)ti*5*NN;
  int l = threadIdx.x;
  __shared__ float sm[MAXD*8];
  __shared__ int   scol[MAXD];
  __shared__ float inv[8];
  __shared__ float ern[8];
  __shared__ float lg[40];
  if (l<8) ern[l] = a.er[((long)ti*NN+n)*8+l];
  __syncthreads();
  int j0 = rowptr[n], deg = rowptr[n+1]-j0;
  {
    int h = l & 7;
    float dsum = 0.f;
    for (int jj = l>>3; jj < deg; jj += 8){
      int s = colsrc[j0+jj];
      float v = el[s*8+h] + ern[h];
      v = (v>0.f)? v : 0.2f*v;
      float ex = __expf(v);
      dsum += ex;
      if (jj < MAXD){
        sm[jj*8+h] = ex;
        if (h==0) scol[jj] = s;
      }
    }
    dsum += __shfl_xor(dsum, 8);
    dsum += __shfl_xor(dsum, 16);
    dsum += __shfl_xor(dsum, 32);
    if (l<8) inv[l] = 1.0f/dsum;
  }
  __syncthreads();
  if (l<40){
    int h = l/5;
    float ivh = inv[h];
    float acc = 0.f;
    for (int jj=0; jj<deg; jj++){
      int s; float ex;
      if (jj < MAXD){ s = scol[jj]; ex = sm[jj*8+h]; }
      else {
        s = colsrc[j0+jj];
        float v = el[s*8+h] + ern[h];
        v = (v>0.f)? v : 0.2f*v;
        ex = __expf(v);
      }
      acc += ex*ivh * (float)featc[(long)s*128 + l];
    }
    acc += (float)featc[(long)n*128 + 40 + l];
    acc += bc[l];
    lg[l] = acc;
  }
  __syncthreads();
  if (l<5){
    float p=0.f;
    #pragma unroll
    for (int h=0;h<8;h++) p += lg[h*5+l];
    pred[(long)n*5 + l] = p*0.125f;
  }
}

// ---------------- host orchestration ----------------
extern "C" void kernel_launch(void* const* d_in, const int* in_sizes, int n_in,
                              void* d_out, int out_size, void* d_ws, size_t ws_size,
                              hipStream_t stream){
  const int* srcs[3] = {(const int*)d_in[0], (const int*)d_in[2], (const int*)d_in[4]};
  const int* dsts[3] = {(const int*)d_in[1], (const int*)d_in[3], (const int*)d_in[5]};
  int E[3] = {in_sizes[0], in_sizes[2], in_sizes[4]};
  const float* X[3] = {(const float*)d_in[6], (const float*)d_in[7], (const float*)d_in[8]};
  const float* W0  = (const float*)d_in[9];
  const float* al0 = (const float*)d_in[10];
  const float* ar0 = (const float*)d_in[11];
  const float* b0  = (const float*)d_in[12];
  const float* W1  = (const float*)d_in[13];
  const float* al1 = (const float*)d_in[14];
  const float* ar1 = (const float*)d_in[15];
  const float* b1  = (const float*)d_in[16];
  const float* Wcv[2] = {(const float*)d_in[17], (const float*)d_in[22]};
  const float* alc[2] = {(const float*)d_in[18], (const float*)d_in[23]};
  const float* arc[2] = {(const float*)d_in[19], (const float*)d_in[24]};
  const float* bcv[2] = {(const float*)d_in[20], (const float*)d_in[25]};
  const float* rWv[2] = {(const float*)d_in[21], (const float*)d_in[26]};

  float* out = (float*)d_out;
  float* embOut[3] = {out+200000, out+200000+(long)NN*FF, out+200000+2L*NN*FF};

  char* w = (char*)d_ws;
  size_t off = 0;
  auto alloc = [&](size_t bytes)->void*{
    void* p = (void*)(w + off);
    off += (bytes + 255) & ~((size_t)255);
    return p;
  };
  f16* W0T = (f16*)alloc((size_t)FF*KK0*2);
  f16* W1T = (f16*)alloc((size_t)FF*FF*2);
  f16* WcT[2] = {(f16*)alloc(128*512*2), (f16*)alloc(128*512*2)};
  f16* feat0H[3], *h0H[3], *feat1H[3], *embH[3];
  for (int g=0;g<3;g++) feat0H[g] = (f16*)alloc((size_t)NP*FF*2);
  for (int g=0;g<3;g++) h0H[g]    = (f16*)alloc((size_t)NP*FF*2);
  for (int g=0;g<3;g++) feat1H[g] = (f16*)alloc((size_t)NP*FF*2);
  for (int g=0;g<3;g++) embH[g]   = (f16*)alloc((size_t)NP*FF*2);
  f16* featc = (f16*)alloc((size_t)4*NP*128*2);
  float* el_e = (float*)alloc((size_t)3*NN*8*4);
  float* er_e = (float*)alloc((size_t)3*NN*8*4);
  float* el_c = (float*)alloc((size_t)4*NN*8*4);
  float* er_c = (float*)alloc((size_t)4*NN*8*4);
  int* deg    = (int*)alloc((size_t)3*NN*4);
  int* cursor = (int*)alloc((size_t)3*NN*4);
  int* rowptr = (int*)alloc((size_t)3*(NN+1)*4);
  int* colsrc[3];
  for (int g=0;g<3;g++) colsrc[g] = (int*)alloc((size_t)E[g]*4);
  (void)ws_size; (void)n_in; (void)out_size;

  // ---- CSR (3 graphs, batched) ----
  int nb[3] = {(E[0]+255)/256, (E[1]+255)/256, (E[2]+255)/256};
  hipMemsetAsync(deg, 0, (size_t)3*NN*4, stream);
  k_count_b<<<nb[0]+nb[1]+nb[2], 256, 0, stream>>>(dsts[0], dsts[1], dsts[2],
      E[0], E[1], E[2], nb[0], nb[1], deg);
  k_scan_b<<<3, 1024, 0, stream>>>(deg, rowptr, cursor);
  k_fill_b<<<nb[0]+nb[1]+nb[2], 256, 0, stream>>>(srcs[0], dsts[0], srcs[1], dsts[1],
      srcs[2], dsts[2], E[0], E[1], E[2], nb[0], nb[1], cursor,
      colsrc[0], colsrc[1], colsrc[2]);

  // ---- weight prep ----
  k_transpose_t<<<dim3(FF/32, KK0/32), dim3(32,8), 0, stream>>>(W0, W0T, KK0, FF);
  k_transpose_t<<<dim3(FF/32, FF/32), dim3(32,8), 0, stream>>>(W1, W1T, FF, FF);
  k_pack_wc<<<(128*512+255)/256, 256, 0, stream>>>(Wcv[0], rWv[0], WcT[0]);
  k_pack_wc<<<(128*512+255)/256, 256, 0, stream>>>(Wcv[1], rWv[1], WcT[1]);

  const int* rp[3] = {rowptr, rowptr+(NN+1), rowptr+2*(NN+1)};

  // ---- layer 0: fused convert+GEMM, then attention ----
  k_gemm0<<<3*632, 256, 0, stream>>>(X[0], X[1], X[2],
      feat0H[0], feat0H[1], feat0H[2], W0T);
  k_eler_b<<<3*NN, 512, 0, stream>>>(feat0H[0], feat0H[1], feat0H[2], al0, ar0, el_e, er_e);
  {
    AggArgs a;
    for (int g=0;g<3;g++){ a.rp[g]=rp[g]; a.cs[g]=colsrc[g]; a.feat[g]=feat0H[g];
                           a.outH[g]=h0H[g]; a.outF[g]=nullptr; }
    a.el = el_e; a.er = er_e; a.bias = b0;
    k_agg_b<<<3*NN, 256, 0, stream>>>(a);
  }

  // ---- layer 1: GEMM (3 tasks) + attention ----
  {
    GemmTasks p;
    for (int i=0;i<4;i++){ int g = i<3?i:0; p.A[i]=h0H[g]; p.B[i]=W1T; p.C[i]=feat1H[g]; }
    k_gemmb<<<3*632, 256, 0, stream>>>(p, 632, 4, FF, FF);
  }
  k_eler_b<<<3*NN, 512, 0, stream>>>(feat1H[0], feat1H[1], feat1H[2], al1, ar1, el_e, er_e);
  {
    AggArgs a;
    for (int g=0;g<3;g++){ a.rp[g]=rp[g]; a.cs[g]=colsrc[g]; a.feat[g]=feat1H[g];
                           a.outH[g]=embH[g]; a.outF[g]=embOut[g]; }
    a.el = el_e; a.er = er_e; a.bias = b1;
    k_agg_b<<<3*NN, 256, 0, stream>>>(a);
  }

  // ---- classifiers (4 tasks batched): (g,c) = (0,0),(1,1),(2,0),(2,1) ----
  {
    GemmTasks p;
    const int tg[4] = {0,1,2,2};
    for (int i=0;i<4;i++){ p.A[i]=embH[tg[i]]; p.B[i]=WcT[i&1]; p.C[i]=featc + (long)i*NP*128; }
    k_gemmb<<<4*158, 256, 0, stream>>>(p, 158, 1, 128, FF);
  }
  k_elerc_b<<<(4*NN*8+255)/256, 256, 0, stream>>>(featc, alc[0], arc[0], alc[1], arc[1], el_c, er_c);
  {
    ClsArgs a;
    for (int g=0;g<3;g++){ a.rp[g]=rp[g]; a.cs[g]=colsrc[g]; }
    a.el = el_c; a.er = er_c; a.fc = featc;
    a.bc[0] = bcv[0]; a.bc[1] = bcv[1];
    a.pred = out;
    k_cls_b<<<4*NN, 64, 0, stream>>>(a);
  }
}

// Round 4
// 692.693 us; speedup vs baseline: 1.7933x; 1.1600x over previous
//
#include <hip/hip_runtime.h>
#include <stdint.h>

typedef _Float16 f16;
typedef _Float16 f16x2 __attribute__((ext_vector_type(2)));
typedef _Float16 f16x8 __attribute__((ext_vector_type(8)));
typedef float f32x4 __attribute__((ext_vector_type(4)));

#define AS1 __attribute__((address_space(1)))
#define AS3 __attribute__((address_space(3)))

#define NN 10000
#define NP 10112
#define KK0 4096
#define FF 512

// ---------------- CSR build (batched over 3 graphs) ----------------
__global__ void k_count_b(const int* __restrict__ d0, const int* __restrict__ d1,
                          const int* __restrict__ d2, int E0, int E1, int E2,
                          int nb0, int nb1, int* __restrict__ deg){
  int b = blockIdx.x;
  const int* d; int Eg, base, lb;
  if (b < nb0){ d=d0; Eg=E0; base=0; lb=b; }
  else if (b < nb0+nb1){ d=d1; Eg=E1; base=NN; lb=b-nb0; }
  else { d=d2; Eg=E2; base=2*NN; lb=b-nb0-nb1; }
  int i = lb*256 + threadIdx.x;
  if (i < Eg) atomicAdd(&deg[base + d[i]], 1);
}

// one block per graph; writes rowptr and cursor
__global__ __launch_bounds__(1024) void k_scan_b(const int* __restrict__ deg_all,
    int* __restrict__ rowptr_all, int* __restrict__ cursor_all){
  int g = blockIdx.x;
  const int* deg = deg_all + g*NN;
  int* rowptr = rowptr_all + g*(NN+1);
  int* cursor = cursor_all + g*NN;
  __shared__ int ps[1024];
  int t = threadIdx.x;
  const int CH = 16;
  int i0 = t*CH;
  int sum = 0;
  for (int k=0;k<CH;k++){ int i=i0+k; if (i<NN) sum += deg[i]; }
  ps[t]=sum; __syncthreads();
  for (int off=1; off<1024; off<<=1){
    int v = (t>=off)? ps[t-off] : 0;
    __syncthreads();
    ps[t] += v;
    __syncthreads();
  }
  int run = ps[t]-sum;
  for (int k=0;k<CH;k++){
    int i=i0+k;
    if (i<=NN) rowptr[i]=run;
    if (i<NN){ cursor[i]=run; run += deg[i]; }
  }
}

__global__ void k_fill_b(const int* __restrict__ s0, const int* __restrict__ d0,
                         const int* __restrict__ s1, const int* __restrict__ d1,
                         const int* __restrict__ s2, const int* __restrict__ d2,
                         int E0, int E1, int E2, int nb0, int nb1,
                         int* __restrict__ cursor_all,
                         int* __restrict__ c0, int* __restrict__ c1, int* __restrict__ c2){
  int b = blockIdx.x;
  const int *s, *d; int Eg, lb; int* cur; int* col;
  if (b < nb0){ s=s0; d=d0; Eg=E0; lb=b; cur=cursor_all; col=c0; }
  else if (b < nb0+nb1){ s=s1; d=d1; Eg=E1; lb=b-nb0; cur=cursor_all+NN; col=c1; }
  else { s=s2; d=d2; Eg=E2; lb=b-nb0-nb1; cur=cursor_all+2*NN; col=c2; }
  int i = lb*256 + threadIdx.x;
  if (i >= Eg) return;
  int slot = atomicAdd(&cur[d[i]], 1);
  col[slot] = s[i];
}

// ---------------- weight prep ----------------
__global__ void k_transpose_t(const float* __restrict__ W, f16* __restrict__ WT,
                              int K, int Nc){
  __shared__ float tile[32][33];
  int n0 = blockIdx.x*32, k0 = blockIdx.y*32;
  int tx = threadIdx.x, ty = threadIdx.y;
  #pragma unroll
  for (int i=0;i<32;i+=8)
    tile[ty+i][tx] = W[(long)(k0+ty+i)*Nc + n0+tx];
  __syncthreads();
  #pragma unroll
  for (int i=0;i<32;i+=8)
    WT[(long)(n0+ty+i)*K + k0+tx] = (f16)tile[tx][ty+i];
}

__global__ void k_pack_wc(const float* __restrict__ Wc, const float* __restrict__ rW,
                          f16* __restrict__ WT){
  int idx = blockIdx.x*256 + threadIdx.x;
  if (idx >= 128*512) return;
  int n = idx >> 9; int k = idx & 511;
  float v = 0.f;
  if (n < 40) v = Wc[k*40 + n];
  else if (n < 80) v = rW[k*40 + (n-40)];
  WT[idx] = (f16)v;
}

// ---------------- GEMM0: fused fp32->f16 convert + GEMM + el/er epilogue
// C[g] (Np x 512) = X[g] (f32) * W0T^T.  64x128 tile, BK=64, 4 waves.
// A: reg-staged single-set (STATIC indices only), B: global_load_lds(16B).
__global__ __launch_bounds__(256,3) void k_gemm0(
    const float* __restrict__ X0, const float* __restrict__ X1, const float* __restrict__ X2,
    f16* __restrict__ C0, f16* __restrict__ C1, f16* __restrict__ C2,
    const f16* __restrict__ B,
    const float* __restrict__ alp, const float* __restrict__ arp,
    float* __restrict__ elp, float* __restrict__ erp)
{
  __shared__ f16 lds[2][12288];   // per buf: A 64x64 (8KB) + B 128x64 (16KB)
  const int bid = blockIdx.x;
  const int task = bid / 632;
  const int orig = bid - task*632;
  const int wid = (orig & 7)*79 + (orig >> 3);   // bijective (632 = 8*79)
  const int tr = wid >> 2, tc = wid & 3;
  const float* A = task==0 ? X0 : (task==1 ? X1 : X2);
  f16* C = task==0 ? C0 : (task==1 ? C1 : C2);

  const int t = threadIdx.x;
  const int wave = t >> 6, lane = t & 63;
  const int wr = wave >> 1, wc = wave & 1;

  const f16* Bb = B + (long)tc*128*KK0;
  const int slot = (lane&7) ^ (lane>>3);
  const int rbase = wave*8 + (lane>>3);

  // A staging: thread covers rows {t>>3, t>>3+32}, 8-f32 group t&7
  const int arow0 = t >> 3;
  const int ak8 = t & 7;
  const float* gA[2];
  bool okA[2];
  #pragma unroll
  for (int s=0;s<2;s++){
    int grow = tr*64 + arow0 + s*32;
    okA[s] = grow < NN;
    gA[s] = A + (long)(okA[s] ? grow : 0)*KK0 + ak8*8;
  }
  f32x4 arE[2][2];   // [row-slot][half] -- static indices ONLY

  #define LOADA(kt) { \
    _Pragma("unroll") \
    for (int s=0;s<2;s++){ \
      arE[s][0] = *(const f32x4*)(gA[s] + (kt)*64); \
      arE[s][1] = *(const f32x4*)(gA[s] + (kt)*64 + 4); \
    } }

  #define WRITEA(buf) { \
    _Pragma("unroll") \
    for (int s=0;s<2;s++){ \
      int row = arow0 + s*32; \
      f16x8 v; \
      _Pragma("unroll") \
      for (int j=0;j<4;j++){ \
        v[j]   = okA[s] ? (f16)arE[s][0][j] : (f16)0.f; \
        v[4+j] = okA[s] ? (f16)arE[s][1][j] : (f16)0.f; \
      } \
      *(f16x8*)(&lds[buf][row*64 + ((ak8 ^ (row&7))*8)]) = v; \
    } }

  #define GLDSB(kt, buf) { \
    int ko = (kt)*64; \
    _Pragma("unroll") \
    for (int i=0;i<4;i++) \
      __builtin_amdgcn_global_load_lds((const AS1 void*)(Bb + ko + (i*32+rbase)*KK0 + slot*8), \
          (AS3 void*)(&lds[buf][4096 + i*2048 + wave*512]), 16, 0, 0); \
    }

  f32x4 zero4 = {0.f,0.f,0.f,0.f};
  f32x4 acc[2][4];
  #pragma unroll
  for (int m=0;m<2;m++)
    #pragma unroll
    for (int n=0;n<4;n++) acc[m][n] = zero4;

  int abyte[2][2], bbyte[2][4];
  #pragma unroll
  for (int ks=0;ks<2;ks++){
    #pragma unroll
    for (int m=0;m<2;m++){
      int row = wr*32 + m*16 + (lane&15);
      abyte[ks][m] = row*128 + (((ks*4 + (lane>>4))*16) ^ ((row&7)<<4));
    }
    #pragma unroll
    for (int n=0;n<4;n++){
      int brow = wc*64 + n*16 + (lane&15);
      bbyte[ks][n] = 8192 + brow*128 + (((ks*4 + (lane>>4))*16) ^ ((brow&7)<<4));
    }
  }

  const int nt = KK0 >> 6;   // 64
  // prologue: stage tile 0
  LOADA(0);
  GLDSB(0, 0);
  WRITEA(0);
  __syncthreads();

  int cur = 0;
  for (int kt=0; kt<nt; kt++){
    if (kt+1 < nt){
      LOADA(kt+1);
      GLDSB(kt+1, cur^1);
    }
    const char* Ls = (const char*)&lds[cur][0];
    #pragma unroll
    for (int ks=0;ks<2;ks++){
      f16x8 af[2], bf[4];
      #pragma unroll
      for (int m=0;m<2;m++) af[m] = *(const f16x8*)(Ls + abyte[ks][m]);
      #pragma unroll
      for (int n=0;n<4;n++) bf[n] = *(const f16x8*)(Ls + bbyte[ks][n]);
      #pragma unroll
      for (int m=0;m<2;m++)
        #pragma unroll
        for (int n=0;n<4;n++)
          acc[m][n] = __builtin_amdgcn_mfma_f32_16x16x32_f16(af[m], bf[n], acc[m][n], 0, 0, 0);
    }
    if (kt+1 < nt) WRITEA(cur^1);   // vmcnt wait for LOADA lands here, after MFMA
    __syncthreads();
    cur ^= 1;
  }
  #undef LOADA
  #undef WRITEA
  #undef GLDSB

  // C write
  #pragma unroll
  for (int m=0;m<2;m++){
    int row0 = tr*64 + wr*32 + m*16 + ((lane>>4)<<2);
    #pragma unroll
    for (int n=0;n<4;n++){
      int col = tc*128 + wc*64 + n*16 + (lane&15);
      #pragma unroll
      for (int q2=0;q2<4;q2++)
        C[(long)(row0+q2)*FF + col] = (f16)acc[m][n][q2];
    }
  }

  // el/er epilogue: this wave's cols = head (tc*2+wc), d = n*16+(lane&15)
  {
    int head = tc*2 + wc;
    const float* alh = alp + head*64;
    const float* arh = arp + head*64;
    float alv[4], arv[4];
    #pragma unroll
    for (int n=0;n<4;n++){ int d = n*16 + (lane&15); alv[n]=alh[d]; arv[n]=arh[d]; }
    float* elo = elp + (long)task*NN*8;
    float* ero = erp + (long)task*NN*8;
    #pragma unroll
    for (int m=0;m<2;m++){
      float e0,e1,e2,e3,r0,r1,r2,r3;
      #pragma unroll
      for (int q=0;q<4;q++){
        float e=0.f, r=0.f;
        #pragma unroll
        for (int n=0;n<4;n++){ e += acc[m][n][q]*alv[n]; r += acc[m][n][q]*arv[n]; }
        #pragma unroll
        for (int off=1; off<16; off<<=1){ e += __shfl_xor(e, off); r += __shfl_xor(r, off); }
        if (q==0){e0=e;r0=r;} else if (q==1){e1=e;r1=r;} else if (q==2){e2=e;r2=r;} else {e3=e;r3=r;}
      }
      int q = lane&15;
      if (q < 4){
        int node = tr*64 + wr*32 + m*16 + ((lane>>4)<<2) + q;
        if (node < NN){
          float ev = q==0?e0:(q==1?e1:(q==2?e2:e3));
          float rv = q==0?r0:(q==1?r1:(q==2?r2:r3));
          long o = (long)node*8 + head;
          elo[o] = ev;
          ero[o] = rv;
        }
      }
    }
  }
}

// ---------------- batched f16 GEMM (layer1 x3 tasks, classifier x4 tasks)
// optional el/er epilogue when alp != nullptr (requires Nc==512, ntn==4)
struct GemmTasks { const f16* A[4]; const f16* B[4]; f16* C[4]; };

__global__ __launch_bounds__(256,3) void k_gemmb(GemmTasks p, int ntpb, int ntn,
                                                 int Nc, int K,
                                                 const float* __restrict__ alp,
                                                 const float* __restrict__ arp,
                                                 float* __restrict__ elp,
                                                 float* __restrict__ erp){
  __shared__ f16 lds[2][12288];
  const int bid = blockIdx.x;
  const int task = bid / ntpb;
  const int orig = bid - task*ntpb;
  const int q = ntpb >> 3, r = ntpb & 7;
  const int xcd = orig & 7, bx = orig >> 3;
  const int wid = (xcd < r ? xcd*(q+1) : r*(q+1) + (xcd-r)*q) + bx;
  const int tr = wid / ntn, tc = wid - tr*ntn;

  const f16* A = p.A[task];
  const f16* B = p.B[task];
  f16* C = p.C[task];

  const int t = threadIdx.x;
  const int wave = t >> 6, lane = t & 63;
  const int wr = wave >> 1, wc = wave & 1;

  const f16* Ab = A + (long)tr*64*K;
  const f16* Bb = B + (long)tc*128*K;

  const int slot = (lane&7) ^ (lane>>3);
  const int rbase = wave*8 + (lane>>3);

  f32x4 zero4 = {0.f,0.f,0.f,0.f};
  f32x4 acc[2][4];
  #pragma unroll
  for (int m=0;m<2;m++)
    #pragma unroll
    for (int n=0;n<4;n++) acc[m][n] = zero4;

  int abyte[2][2], bbyte[2][4];
  #pragma unroll
  for (int ks=0;ks<2;ks++){
    #pragma unroll
    for (int m=0;m<2;m++){
      int row = wr*32 + m*16 + (lane&15);
      abyte[ks][m] = row*128 + (((ks*4 + (lane>>4))*16) ^ ((row&7)<<4));
    }
    #pragma unroll
    for (int n=0;n<4;n++){
      int brow = wc*64 + n*16 + (lane&15);
      bbyte[ks][n] = 8192 + brow*128 + (((ks*4 + (lane>>4))*16) ^ ((brow&7)<<4));
    }
  }

  const int nt = K >> 6;
  int cur = 0;

  #pragma unroll
  for (int i=0;i<2;i++)
    __builtin_amdgcn_global_load_lds((const AS1 void*)(Ab + (i*32+rbase)*K + slot*8),
        (AS3 void*)(&lds[0][i*2048 + wave*512]), 16, 0, 0);
  #pragma unroll
  for (int i=0;i<4;i++)
    __builtin_amdgcn_global_load_lds((const AS1 void*)(Bb + (i*32+rbase)*K + slot*8),
        (AS3 void*)(&lds[0][4096 + i*2048 + wave*512]), 16, 0, 0);
  __syncthreads();

  for (int kt=0; kt<nt; kt++){
    if (kt+1 < nt){
      int ko = (kt+1)<<6;
      #pragma unroll
      for (int i=0;i<2;i++)
        __builtin_amdgcn_global_load_lds((const AS1 void*)(Ab + ko + (i*32+rbase)*K + slot*8),
            (AS3 void*)(&lds[cur^1][i*2048 + wave*512]), 16, 0, 0);
      #pragma unroll
      for (int i=0;i<4;i++)
        __builtin_amdgcn_global_load_lds((const AS1 void*)(Bb + ko + (i*32+rbase)*K + slot*8),
            (AS3 void*)(&lds[cur^1][4096 + i*2048 + wave*512]), 16, 0, 0);
    }
    const char* Ls = (const char*)&lds[cur][0];
    #pragma unroll
    for (int ks=0;ks<2;ks++){
      f16x8 af[2], bf[4];
      #pragma unroll
      for (int m=0;m<2;m++) af[m] = *(const f16x8*)(Ls + abyte[ks][m]);
      #pragma unroll
      for (int n=0;n<4;n++) bf[n] = *(const f16x8*)(Ls + bbyte[ks][n]);
      #pragma unroll
      for (int m=0;m<2;m++)
        #pragma unroll
        for (int n=0;n<4;n++)
          acc[m][n] = __builtin_amdgcn_mfma_f32_16x16x32_f16(af[m], bf[n], acc[m][n], 0, 0, 0);
    }
    __syncthreads();
    cur ^= 1;
  }

  #pragma unroll
  for (int m=0;m<2;m++){
    int row0 = tr*64 + wr*32 + m*16 + ((lane>>4)<<2);
    #pragma unroll
    for (int n=0;n<4;n++){
      int col = tc*128 + wc*64 + n*16 + (lane&15);
      #pragma unroll
      for (int q2=0;q2<4;q2++)
        C[(long)(row0+q2)*Nc + col] = (f16)acc[m][n][q2];
    }
  }

  if (alp){
    int head = tc*2 + wc;
    const float* alh = alp + head*64;
    const float* arh = arp + head*64;
    float alv[4], arv[4];
    #pragma unroll
    for (int n=0;n<4;n++){ int d = n*16 + (lane&15); alv[n]=alh[d]; arv[n]=arh[d]; }
    float* elo = elp + (long)task*NN*8;
    float* ero = erp + (long)task*NN*8;
    #pragma unroll
    for (int m=0;m<2;m++){
      float e0,e1,e2,e3,r0,r1,r2,r3;
      #pragma unroll
      for (int qq=0;qq<4;qq++){
        float e=0.f, rr=0.f;
        #pragma unroll
        for (int n=0;n<4;n++){ e += acc[m][n][qq]*alv[n]; rr += acc[m][n][qq]*arv[n]; }
        #pragma unroll
        for (int off=1; off<16; off<<=1){ e += __shfl_xor(e, off); rr += __shfl_xor(rr, off); }
        if (qq==0){e0=e;r0=rr;} else if (qq==1){e1=e;r1=rr;} else if (qq==2){e2=e;r2=rr;} else {e3=e;r3=rr;}
      }
      int qq = lane&15;
      if (qq < 4){
        int node = tr*64 + wr*32 + m*16 + ((lane>>4)<<2) + qq;
        if (node < NN){
          float ev = qq==0?e0:(qq==1?e1:(qq==2?e2:e3));
          float rv = qq==0?r0:(qq==1?r1:(qq==2?r2:r3));
          long o = (long)node*8 + head;
          elo[o] = ev;
          ero[o] = rv;
        }
      }
    }
  }
}

// ---------------- attention aggregation (batched over graphs) ----------------
#define MAXD 128

struct AggArgs {
  const int* rp[3]; const int* cs[3];
  const float* el; const float* er;
  const f16* feat[3];
  const float* bias;
  f16* outH[3];
  float* outF[3];
};

__global__ __launch_bounds__(256) void k_agg_b(AggArgs a){
  int b = blockIdx.x;
  int g = b / NN, n = b - g*NN;
  const int* rowptr = a.rp[g];
  const int* colsrc = a.cs[g];
  const float* el = a.el + (long)g*NN*8;
  const f16* featH = a.feat[g];
  int t = threadIdx.x;
  __shared__ float sm[MAXD*8];
  __shared__ int   scol[MAXD];
  __shared__ float red[256];
  __shared__ float inv[8];
  __shared__ float ern[8];
  if (t < 8) ern[t] = a.er[((long)g*NN+n)*8+t];
  __syncthreads();
  int j0 = rowptr[n], deg = rowptr[n+1]-j0;
  {
    int h = t & 7;
    float dsum = 0.f;
    for (int jj = t>>3; jj < deg; jj += 32){
      int s = colsrc[j0+jj];
      float v = el[s*8+h] + ern[h];
      v = (v>0.f)? v : 0.2f*v;
      float ex = __expf(v);
      dsum += ex;
      if (jj < MAXD){
        sm[jj*8+h] = ex;
        if (h==0) scol[jj] = s;
      }
    }
    red[t] = dsum; __syncthreads();
    if (t<128) red[t] += red[t+128]; __syncthreads();
    if (t<64)  red[t] += red[t+64];  __syncthreads();
    if (t<32)  red[t] += red[t+32];  __syncthreads();
    if (t<16)  red[t] += red[t+16];  __syncthreads();
    if (t<8)   inv[t] = 1.0f / (red[t] + red[t+8]);
    __syncthreads();
  }
  int h = t >> 5;
  int c = t*2;
  float a0=0.f, a1=0.f;
  float ivh = inv[h];
  for (int jj=0; jj<deg; jj++){
    int s; float ex;
    if (jj < MAXD){ s = scol[jj]; ex = sm[jj*8+h]; }
    else {
      s = colsrc[j0+jj];
      float v = el[s*8+h] + ern[h];
      v = (v>0.f)? v : 0.2f*v;
      ex = __expf(v);
    }
    float alpha = ex * ivh;
    f16x2 f = *(const f16x2*)(featH + (long)s*FF + c);
    a0 += alpha*(float)f[0];
    a1 += alpha*(float)f[1];
  }
  a0 += a.bias[c]; a1 += a.bias[c+1];
  a0 = (a0>0.f)? a0 : __expf(a0)-1.f;
  a1 = (a1>0.f)? a1 : __expf(a1)-1.f;
  f16x2 o; o[0]=(f16)a0; o[1]=(f16)a1;
  *(f16x2*)(a.outH[g] + (long)n*FF + c) = o;
  float* oF = a.outF[g];
  if (oF){
    oF[(long)n*FF + c]     = a0;
    oF[(long)n*FF + c + 1] = a1;
  }
}

// classifier el/er over 4 tasks
__global__ void k_elerc_b(const f16* __restrict__ fc,
    const float* __restrict__ alc0, const float* __restrict__ arc0,
    const float* __restrict__ alc1, const float* __restrict__ arc1,
    float* __restrict__ el, float* __restrict__ er){
  int idx = blockIdx.x*256 + threadIdx.x;
  if (idx >= 4*NN*8) return;
  int ti = idx / (NN*8);
  int rem = idx - ti*NN*8;
  int n = rem>>3, hh = rem&7;
  const f16* featc = fc + (long)ti*NP*128;
  const float* al = (ti&1) ? alc1 : alc0;
  const float* ar_ = (ti&1) ? arc1 : arc0;
  float a=0.f, bsum=0.f;
  #pragma unroll
  for (int cc=0; cc<5; cc++){
    float v = (float)featc[(long)n*128 + hh*5 + cc];
    a += v*al[hh*5+cc];
    bsum += v*ar_[hh*5+cc];
  }
  el[idx]=a; er[idx]=bsum;
}

struct ClsArgs {
  const int* rp[3]; const int* cs[3];
  const float* el; const float* er;
  const f16* fc;
  const float* bc[2];
  float* pred;
};

__global__ __launch_bounds__(64) void k_cls_b(ClsArgs a){
  int b = blockIdx.x;
  int ti = b / NN, n = b - ti*NN;
  int g = ti<2 ? ti : 2;
  int ci = ti&1;
  const int* rowptr = a.rp[g];
  const int* colsrc = a.cs[g];
  const float* el = a.el + (long)ti*NN*8;
  const f16* featc = a.fc + (long)ti*NP*128;
  const float* bc = a.bc[ci];
  float* pred = a.pred + (long)ti*5*NN;
  int l = threadIdx.x;
  __shared__ float sm[MAXD*8];
  __shared__ int   scol[MAXD];
  __shared__ float inv[8];
  __shared__ float ern[8];
  __shared__ float lg[40];
  if (l<8) ern[l] = a.er[((long)ti*NN+n)*8+l];
  __syncthreads();
  int j0 = rowptr[n], deg = rowptr[n+1]-j0;
  {
    int h = l & 7;
    float dsum = 0.f;
    for (int jj = l>>3; jj < deg; jj += 8){
      int s = colsrc[j0+jj];
      float v = el[s*8+h] + ern[h];
      v = (v>0.f)? v : 0.2f*v;
      float ex = __expf(v);
      dsum += ex;
      if (jj < MAXD){
        sm[jj*8+h] = ex;
        if (h==0) scol[jj] = s;
      }
    }
    dsum += __shfl_xor(dsum, 8);
    dsum += __shfl_xor(dsum, 16);
    dsum += __shfl_xor(dsum, 32);
    if (l<8) inv[l] = 1.0f/dsum;
  }
  __syncthreads();
  if (l<40){
    int h = l/5;
    float ivh = inv[h];
    float acc = 0.f;
    for (int jj=0; jj<deg; jj++){
      int s; float ex;
      if (jj < MAXD){ s = scol[jj]; ex = sm[jj*8+h]; }
      else {
        s = colsrc[j0+jj];
        float v = el[s*8+h] + ern[h];
        v = (v>0.f)? v : 0.2f*v;
        ex = __expf(v);
      }
      acc += ex*ivh * (float)featc[(long)s*128 + l];
    }
    acc += (float)featc[(long)n*128 + 40 + l];
    acc += bc[l];
    lg[l] = acc;
  }
  __syncthreads();
  if (l<5){
    float p=0.f;
    #pragma unroll
    for (int h=0;h<8;h++) p += lg[h*5+l];
    pred[(long)n*5 + l] = p*0.125f;
  }
}

// ---------------- host orchestration ----------------
extern "C" void kernel_launch(void* const* d_in, const int* in_sizes, int n_in,
                              void* d_out, int out_size, void* d_ws, size_t ws_size,
                              hipStream_t stream){
  const int* srcs[3] = {(const int*)d_in[0], (const int*)d_in[2], (const int*)d_in[4]};
  const int* dsts[3] = {(const int*)d_in[1], (const int*)d_in[3], (const int*)d_in[5]};
  int E[3] = {in_sizes[0], in_sizes[2], in_sizes[4]};
  const float* X[3] = {(const float*)d_in[6], (const float*)d_in[7], (const float*)d_in[8]};
  const float* W0  = (const float*)d_in[9];
  const float* al0 = (const float*)d_in[10];
  const float* ar0 = (const float*)d_in[11];
  const float* b0  = (const float*)d_in[12];
  const float* W1  = (const float*)d_in[13];
  const float* al1 = (const float*)d_in[14];
  const float* ar1 = (const float*)d_in[15];
  const float* b1  = (const float*)d_in[16];
  const float* Wcv[2] = {(const float*)d_in[17], (const float*)d_in[22]};
  const float* alc[2] = {(const float*)d_in[18], (const float*)d_in[23]};
  const float* arc[2] = {(const float*)d_in[19], (const float*)d_in[24]};
  const float* bcv[2] = {(const float*)d_in[20], (const float*)d_in[25]};
  const float* rWv[2] = {(const float*)d_in[21], (const float*)d_in[26]};

  float* out = (float*)d_out;
  float* embOut[3] = {out+200000, out+200000+(long)NN*FF, out+200000+2L*NN*FF};

  char* w = (char*)d_ws;
  size_t off = 0;
  auto alloc = [&](size_t bytes)->void*{
    void* p = (void*)(w + off);
    off += (bytes + 255) & ~((size_t)255);
    return p;
  };
  f16* W0T = (f16*)alloc((size_t)FF*KK0*2);
  f16* W1T = (f16*)alloc((size_t)FF*FF*2);
  f16* WcT[2] = {(f16*)alloc(128*512*2), (f16*)alloc(128*512*2)};
  f16* feat0H[3], *h0H[3], *feat1H[3], *embH[3];
  for (int g=0;g<3;g++) feat0H[g] = (f16*)alloc((size_t)NP*FF*2);
  for (int g=0;g<3;g++) h0H[g]    = (f16*)alloc((size_t)NP*FF*2);
  for (int g=0;g<3;g++) feat1H[g] = (f16*)alloc((size_t)NP*FF*2);
  for (int g=0;g<3;g++) embH[g]   = (f16*)alloc((size_t)NP*FF*2);
  f16* featc = (f16*)alloc((size_t)4*NP*128*2);
  float* el_e = (float*)alloc((size_t)3*NN*8*4);
  float* er_e = (float*)alloc((size_t)3*NN*8*4);
  float* el_c = (float*)alloc((size_t)4*NN*8*4);
  float* er_c = (float*)alloc((size_t)4*NN*8*4);
  int* deg    = (int*)alloc((size_t)3*NN*4);
  int* cursor = (int*)alloc((size_t)3*NN*4);
  int* rowptr = (int*)alloc((size_t)3*(NN+1)*4);
  int* colsrc[3];
  for (int g=0;g<3;g++) colsrc[g] = (int*)alloc((size_t)E[g]*4);
  (void)ws_size; (void)n_in; (void)out_size;

  // ---- CSR (3 graphs, batched) ----
  int nb[3] = {(E[0]+255)/256, (E[1]+255)/256, (E[2]+255)/256};
  hipMemsetAsync(deg, 0, (size_t)3*NN*4, stream);
  k_count_b<<<nb[0]+nb[1]+nb[2], 256, 0, stream>>>(dsts[0], dsts[1], dsts[2],
      E[0], E[1], E[2], nb[0], nb[1], deg);
  k_scan_b<<<3, 1024, 0, stream>>>(deg, rowptr, cursor);
  k_fill_b<<<nb[0]+nb[1]+nb[2], 256, 0, stream>>>(srcs[0], dsts[0], srcs[1], dsts[1],
      srcs[2], dsts[2], E[0], E[1], E[2], nb[0], nb[1], cursor,
      colsrc[0], colsrc[1], colsrc[2]);

  // ---- weight prep ----
  k_transpose_t<<<dim3(FF/32, KK0/32), dim3(32,8), 0, stream>>>(W0, W0T, KK0, FF);
  k_transpose_t<<<dim3(FF/32, FF/32), dim3(32,8), 0, stream>>>(W1, W1T, FF, FF);
  k_pack_wc<<<(128*512+255)/256, 256, 0, stream>>>(Wcv[0], rWv[0], WcT[0]);
  k_pack_wc<<<(128*512+255)/256, 256, 0, stream>>>(Wcv[1], rWv[1], WcT[1]);

  const int* rp[3] = {rowptr, rowptr+(NN+1), rowptr+2*(NN+1)};

  // ---- layer 0: fused convert+GEMM+eler, then aggregation ----
  k_gemm0<<<3*632, 256, 0, stream>>>(X[0], X[1], X[2],
      feat0H[0], feat0H[1], feat0H[2], W0T, al0, ar0, el_e, er_e);
  {
    AggArgs a;
    for (int g=0;g<3;g++){ a.rp[g]=rp[g]; a.cs[g]=colsrc[g]; a.feat[g]=feat0H[g];
                           a.outH[g]=h0H[g]; a.outF[g]=nullptr; }
    a.el = el_e; a.er = er_e; a.bias = b0;
    k_agg_b<<<3*NN, 256, 0, stream>>>(a);
  }

  // ---- layer 1: GEMM+eler (3 tasks) + aggregation ----
  {
    GemmTasks p;
    for (int i=0;i<4;i++){ int g = i<3?i:0; p.A[i]=h0H[g]; p.B[i]=W1T; p.C[i]=feat1H[g]; }
    k_gemmb<<<3*632, 256, 0, stream>>>(p, 632, 4, FF, FF, al1, ar1, el_e, er_e);
  }
  {
    AggArgs a;
    for (int g=0;g<3;g++){ a.rp[g]=rp[g]; a.cs[g]=colsrc[g]; a.feat[g]=feat1H[g];
                           a.outH[g]=embH[g]; a.outF[g]=embOut[g]; }
    a.el = el_e; a.er = er_e; a.bias = b1;
    k_agg_b<<<3*NN, 256, 0, stream>>>(a);
  }

  // ---- classifiers (4 tasks batched): (g,c) = (0,0),(1,1),(2,0),(2,1) ----
  {
    GemmTasks p;
    const int tg[4] = {0,1,2,2};
    for (int i=0;i<4;i++){ p.A[i]=embH[tg[i]]; p.B[i]=WcT[i&1]; p.C[i]=featc + (long)i*NP*128; }
    k_gemmb<<<4*158, 256, 0, stream>>>(p, 158, 1, 128, FF,
        (const float*)nullptr, (const float*)nullptr, (float*)nullptr, (float*)nullptr);
  }
  k_elerc_b<<<(4*NN*8+255)/256, 256, 0, stream>>>(featc, alc[0], arc[0], alc[1], arc[1], el_c, er_c);
  {
    ClsArgs a;
    for (int g=0;g<3;g++){ a.rp[g]=rp[g]; a.cs[g]=colsrc[g]; }
    a.el = el_c; a.er = er_c; a.fc = featc;
    a.bc[0] = bcv[0]; a.bc[1] = bcv[1];
    a.pred = out;
    k_cls_b<<<4*NN, 64, 0, stream>>>(a);
  }
}

// Round 5
// 617.084 us; speedup vs baseline: 2.0131x; 1.1225x over previous
//
#include <hip/hip_runtime.h>
#include <stdint.h>

typedef _Float16 f16;
typedef _Float16 f16x2 __attribute__((ext_vector_type(2)));
typedef _Float16 f16x8 __attribute__((ext_vector_type(8)));
typedef float f32x4 __attribute__((ext_vector_type(4)));

#define AS1 __attribute__((address_space(1)))
#define AS3 __attribute__((address_space(3)))

#define NN 10000
#define NP 10112
#define KK0 4096
#define FF 512

// ---------------- CSR build (batched over 3 graphs) ----------------
__global__ void k_count_b(const int* __restrict__ d0, const int* __restrict__ d1,
                          const int* __restrict__ d2, int E0, int E1, int E2,
                          int nb0, int nb1, int* __restrict__ deg){
  int b = blockIdx.x;
  const int* d; int Eg, base, lb;
  if (b < nb0){ d=d0; Eg=E0; base=0; lb=b; }
  else if (b < nb0+nb1){ d=d1; Eg=E1; base=NN; lb=b-nb0; }
  else { d=d2; Eg=E2; base=2*NN; lb=b-nb0-nb1; }
  int i = lb*256 + threadIdx.x;
  if (i < Eg) atomicAdd(&deg[base + d[i]], 1);
}

// one block per graph; writes rowptr and cursor
__global__ __launch_bounds__(1024) void k_scan_b(const int* __restrict__ deg_all,
    int* __restrict__ rowptr_all, int* __restrict__ cursor_all){
  int g = blockIdx.x;
  const int* deg = deg_all + g*NN;
  int* rowptr = rowptr_all + g*(NN+1);
  int* cursor = cursor_all + g*NN;
  __shared__ int ps[1024];
  int t = threadIdx.x;
  const int CH = 16;
  int i0 = t*CH;
  int sum = 0;
  for (int k=0;k<CH;k++){ int i=i0+k; if (i<NN) sum += deg[i]; }
  ps[t]=sum; __syncthreads();
  for (int off=1; off<1024; off<<=1){
    int v = (t>=off)? ps[t-off] : 0;
    __syncthreads();
    ps[t] += v;
    __syncthreads();
  }
  int run = ps[t]-sum;
  for (int k=0;k<CH;k++){
    int i=i0+k;
    if (i<=NN) rowptr[i]=run;
    if (i<NN){ cursor[i]=run; run += deg[i]; }
  }
}

__global__ void k_fill_b(const int* __restrict__ s0, const int* __restrict__ d0,
                         const int* __restrict__ s1, const int* __restrict__ d1,
                         const int* __restrict__ s2, const int* __restrict__ d2,
                         int E0, int E1, int E2, int nb0, int nb1,
                         int* __restrict__ cursor_all,
                         int* __restrict__ c0, int* __restrict__ c1, int* __restrict__ c2){
  int b = blockIdx.x;
  const int *s, *d; int Eg, lb; int* cur; int* col;
  if (b < nb0){ s=s0; d=d0; Eg=E0; lb=b; cur=cursor_all; col=c0; }
  else if (b < nb0+nb1){ s=s1; d=d1; Eg=E1; lb=b-nb0; cur=cursor_all+NN; col=c1; }
  else { s=s2; d=d2; Eg=E2; lb=b-nb0-nb1; cur=cursor_all+2*NN; col=c2; }
  int i = lb*256 + threadIdx.x;
  if (i >= Eg) return;
  int slot = atomicAdd(&cur[d[i]], 1);
  col[slot] = s[i];
}

// ---------------- weight prep ----------------
__global__ void k_transpose_t(const float* __restrict__ W, f16* __restrict__ WT,
                              int K, int Nc){
  __shared__ float tile[32][33];
  int n0 = blockIdx.x*32, k0 = blockIdx.y*32;
  int tx = threadIdx.x, ty = threadIdx.y;
  #pragma unroll
  for (int i=0;i<32;i+=8)
    tile[ty+i][tx] = W[(long)(k0+ty+i)*Nc + n0+tx];
  __syncthreads();
  #pragma unroll
  for (int i=0;i<32;i+=8)
    WT[(long)(n0+ty+i)*K + k0+tx] = (f16)tile[tx][ty+i];
}

__global__ void k_pack_wc(const float* __restrict__ Wc, const float* __restrict__ rW,
                          f16* __restrict__ WT){
  int idx = blockIdx.x*256 + threadIdx.x;
  if (idx >= 128*512) return;
  int n = idx >> 9; int k = idx & 511;
  float v = 0.f;
  if (n < 40) v = Wc[k*40 + n];
  else if (n < 80) v = rW[k*40 + (n-40)];
  WT[idx] = (f16)v;
}

// ---------------- GEMM0: fused fp32->f16 convert + GEMM + el/er epilogue
// Counted-vmcnt pipeline: A-prefetch (reg-staged, depth 2) survives the barrier;
// barrier waits vmcnt(4) so only B-stage (gload_lds) is drained each iter.
__global__ __launch_bounds__(256,3) void k_gemm0(
    const float* __restrict__ X0, const float* __restrict__ X1, const float* __restrict__ X2,
    f16* __restrict__ C0, f16* __restrict__ C1, f16* __restrict__ C2,
    const f16* __restrict__ B,
    const float* __restrict__ alp, const float* __restrict__ arp,
    float* __restrict__ elp, float* __restrict__ erp)
{
  __shared__ f16 lds[2][12288];   // per buf: A 64x64 f16 (8KB) + B 128x64 (16KB)
  const int bid = blockIdx.x;
  const int task = bid / 632;
  const int orig = bid - task*632;
  const int wid = (orig & 7)*79 + (orig >> 3);   // bijective (632 = 8*79)
  const int tr = wid >> 2, tc = wid & 3;
  const float* A = task==0 ? X0 : (task==1 ? X1 : X2);
  f16* C = task==0 ? C0 : (task==1 ? C1 : C2);

  const int t = threadIdx.x;
  const int wave = t >> 6, lane = t & 63;
  const int wr = wave >> 1, wc = wave & 1;

  const f16* Bb = B + (long)tc*128*KK0;
  const int slot = (lane&7) ^ (lane>>3);
  const int rbase = wave*8 + (lane>>3);

  // A staging: thread covers rows {t>>3, t>>3+32}, 8-f32 group t&7
  const int arow0 = t >> 3;
  const int ak8 = t & 7;
  const float* gA[2];
  bool okA[2];
  #pragma unroll
  for (int s=0;s<2;s++){
    int grow = tr*64 + arow0 + s*32;
    okA[s] = grow < NN;
    gA[s] = A + (long)(okA[s] ? grow : 0)*KK0 + ak8*8;
  }
  f32x4 arE[2][2];   // [row-slot][half] -- static indices ONLY

  #define LOADA(kt) { \
    _Pragma("unroll") \
    for (int s=0;s<2;s++){ \
      arE[s][0] = *(const f32x4*)(gA[s] + (kt)*64); \
      arE[s][1] = *(const f32x4*)(gA[s] + (kt)*64 + 4); \
    } }

  #define WRITEA(buf) { \
    _Pragma("unroll") \
    for (int s=0;s<2;s++){ \
      int row = arow0 + s*32; \
      f16x8 v; \
      _Pragma("unroll") \
      for (int j=0;j<4;j++){ \
        v[j]   = okA[s] ? (f16)arE[s][0][j] : (f16)0.f; \
        v[4+j] = okA[s] ? (f16)arE[s][1][j] : (f16)0.f; \
      } \
      *(f16x8*)(&lds[buf][row*64 + ((ak8 ^ (row&7))*8)]) = v; \
    } }

  #define GLDSB(kt, buf) { \
    int ko = (kt)*64; \
    _Pragma("unroll") \
    for (int i=0;i<4;i++) \
      __builtin_amdgcn_global_load_lds((const AS1 void*)(Bb + ko + (i*32+rbase)*KK0 + slot*8), \
          (AS3 void*)(&lds[buf][4096 + i*2048 + wave*512]), 16, 0, 0); \
    }

  f32x4 zero4 = {0.f,0.f,0.f,0.f};
  f32x4 acc[2][4];
  #pragma unroll
  for (int m=0;m<2;m++)
    #pragma unroll
    for (int n=0;n<4;n++) acc[m][n] = zero4;

  int abyte[2][2], bbyte[2][4];
  #pragma unroll
  for (int ks=0;ks<2;ks++){
    #pragma unroll
    for (int m=0;m<2;m++){
      int row = wr*32 + m*16 + (lane&15);
      abyte[ks][m] = row*128 + (((ks*4 + (lane>>4))*16) ^ ((row&7)<<4));
    }
    #pragma unroll
    for (int n=0;n<4;n++){
      int brow = wc*64 + n*16 + (lane&15);
      bbyte[ks][n] = 8192 + brow*128 + (((ks*4 + (lane>>4))*16) ^ ((brow&7)<<4));
    }
  }

  const int nt = KK0 >> 6;   // 64

  // prologue: stage tile 0, start A-prefetch of tile 1
  LOADA(0);                                  // vmcnt queue: L_A(0)=4
  __builtin_amdgcn_sched_barrier(0);
  GLDSB(0, 0);                               // + S_B(0)=4
  __builtin_amdgcn_sched_barrier(0);
  WRITEA(0);                                 // compiler waits L_A(0) (vmcnt 4)
  __builtin_amdgcn_sched_barrier(0);
  LOADA(1);                                  // + L_A(1)=4
  __builtin_amdgcn_sched_barrier(0);
  asm volatile("s_waitcnt vmcnt(4) lgkmcnt(0)" ::: "memory");  // S_B(0) done; L_A(1) flying
  __builtin_amdgcn_s_barrier();

  int cur = 0;
  for (int kt=0; kt<nt; kt++){
    if (kt+1 < nt){
      WRITEA(cur^1);                         // waits L_A(kt+1) (only thing outstanding)
      __builtin_amdgcn_sched_barrier(0);
      GLDSB(kt+1, cur^1);                    // S_B(kt+1)=4
      __builtin_amdgcn_sched_barrier(0);
    }
    if (kt+2 < nt){
      LOADA(kt+2);                           // L_A(kt+2)=4, issued AFTER S_B
      __builtin_amdgcn_sched_barrier(0);
    }
    const char* Ls = (const char*)&lds[cur][0];
    #pragma unroll
    for (int ks=0;ks<2;ks++){
      f16x8 af[2], bf[4];
      #pragma unroll
      for (int m=0;m<2;m++) af[m] = *(const f16x8*)(Ls + abyte[ks][m]);
      #pragma unroll
      for (int n=0;n<4;n++) bf[n] = *(const f16x8*)(Ls + bbyte[ks][n]);
      #pragma unroll
      for (int m=0;m<2;m++)
        #pragma unroll
        for (int n=0;n<4;n++)
          acc[m][n] = __builtin_amdgcn_mfma_f32_16x16x32_f16(af[m], bf[n], acc[m][n], 0, 0, 0);
    }
    if (kt+1 < nt){
      __builtin_amdgcn_sched_barrier(0);
      if (kt+2 < nt)
        asm volatile("s_waitcnt vmcnt(4) lgkmcnt(0)" ::: "memory");  // drain S_B, keep L_A
      else
        asm volatile("s_waitcnt vmcnt(0) lgkmcnt(0)" ::: "memory");  // no trailing L_A
      __builtin_amdgcn_s_barrier();
    }
    cur ^= 1;
  }
  #undef LOADA
  #undef WRITEA
  #undef GLDSB

  // C write
  #pragma unroll
  for (int m=0;m<2;m++){
    int row0 = tr*64 + wr*32 + m*16 + ((lane>>4)<<2);
    #pragma unroll
    for (int n=0;n<4;n++){
      int col = tc*128 + wc*64 + n*16 + (lane&15);
      #pragma unroll
      for (int q2=0;q2<4;q2++)
        C[(long)(row0+q2)*FF + col] = (f16)acc[m][n][q2];
    }
  }

  // el/er epilogue: this wave's cols = head (tc*2+wc), d = n*16+(lane&15)
  {
    int head = tc*2 + wc;
    const float* alh = alp + head*64;
    const float* arh = arp + head*64;
    float alv[4], arv[4];
    #pragma unroll
    for (int n=0;n<4;n++){ int d = n*16 + (lane&15); alv[n]=alh[d]; arv[n]=arh[d]; }
    float* elo = elp + (long)task*NN*8;
    float* ero = erp + (long)task*NN*8;
    #pragma unroll
    for (int m=0;m<2;m++){
      float e0,e1,e2,e3,r0,r1,r2,r3;
      #pragma unroll
      for (int q=0;q<4;q++){
        float e=0.f, r=0.f;
        #pragma unroll
        for (int n=0;n<4;n++){ e += acc[m][n][q]*alv[n]; r += acc[m][n][q]*arv[n]; }
        #pragma unroll
        for (int off=1; off<16; off<<=1){ e += __shfl_xor(e, off); r += __shfl_xor(r, off); }
        if (q==0){e0=e;r0=r;} else if (q==1){e1=e;r1=r;} else if (q==2){e2=e;r2=r;} else {e3=e;r3=r;}
      }
      int q = lane&15;
      if (q < 4){
        int node = tr*64 + wr*32 + m*16 + ((lane>>4)<<2) + q;
        if (node < NN){
          float ev = q==0?e0:(q==1?e1:(q==2?e2:e3));
          float rv = q==0?r0:(q==1?r1:(q==2?r2:r3));
          long o = (long)node*8 + head;
          elo[o] = ev;
          ero[o] = rv;
        }
      }
    }
  }
}

// ---------------- batched f16 GEMM (layer1 x3 tasks, classifier x4 tasks)
// optional el/er epilogue when alp != nullptr (requires Nc==512, ntn==4)
struct GemmTasks { const f16* A[4]; const f16* B[4]; f16* C[4]; };

__global__ __launch_bounds__(256,3) void k_gemmb(GemmTasks p, int ntpb, int ntn,
                                                 int Nc, int K,
                                                 const float* __restrict__ alp,
                                                 const float* __restrict__ arp,
                                                 float* __restrict__ elp,
                                                 float* __restrict__ erp){
  __shared__ f16 lds[2][12288];
  const int bid = blockIdx.x;
  const int task = bid / ntpb;
  const int orig = bid - task*ntpb;
  const int q = ntpb >> 3, r = ntpb & 7;
  const int xcd = orig & 7, bx = orig >> 3;
  const int wid = (xcd < r ? xcd*(q+1) : r*(q+1) + (xcd-r)*q) + bx;
  const int tr = wid / ntn, tc = wid - tr*ntn;

  const f16* A = p.A[task];
  const f16* B = p.B[task];
  f16* C = p.C[task];

  const int t = threadIdx.x;
  const int wave = t >> 6, lane = t & 63;
  const int wr = wave >> 1, wc = wave & 1;

  const f16* Ab = A + (long)tr*64*K;
  const f16* Bb = B + (long)tc*128*K;

  const int slot = (lane&7) ^ (lane>>3);
  const int rbase = wave*8 + (lane>>3);

  f32x4 zero4 = {0.f,0.f,0.f,0.f};
  f32x4 acc[2][4];
  #pragma unroll
  for (int m=0;m<2;m++)
    #pragma unroll
    for (int n=0;n<4;n++) acc[m][n] = zero4;

  int abyte[2][2], bbyte[2][4];
  #pragma unroll
  for (int ks=0;ks<2;ks++){
    #pragma unroll
    for (int m=0;m<2;m++){
      int row = wr*32 + m*16 + (lane&15);
      abyte[ks][m] = row*128 + (((ks*4 + (lane>>4))*16) ^ ((row&7)<<4));
    }
    #pragma unroll
    for (int n=0;n<4;n++){
      int brow = wc*64 + n*16 + (lane&15);
      bbyte[ks][n] = 8192 + brow*128 + (((ks*4 + (lane>>4))*16) ^ ((brow&7)<<4));
    }
  }

  const int nt = K >> 6;
  int cur = 0;

  #pragma unroll
  for (int i=0;i<2;i++)
    __builtin_amdgcn_global_load_lds((const AS1 void*)(Ab + (i*32+rbase)*K + slot*8),
        (AS3 void*)(&lds[0][i*2048 + wave*512]), 16, 0, 0);
  #pragma unroll
  for (int i=0;i<4;i++)
    __builtin_amdgcn_global_load_lds((const AS1 void*)(Bb + (i*32+rbase)*K + slot*8),
        (AS3 void*)(&lds[0][4096 + i*2048 + wave*512]), 16, 0, 0);
  __syncthreads();

  for (int kt=0; kt<nt; kt++){
    if (kt+1 < nt){
      int ko = (kt+1)<<6;
      #pragma unroll
      for (int i=0;i<2;i++)
        __builtin_amdgcn_global_load_lds((const AS1 void*)(Ab + ko + (i*32+rbase)*K + slot*8),
            (AS3 void*)(&lds[cur^1][i*2048 + wave*512]), 16, 0, 0);
      #pragma unroll
      for (int i=0;i<4;i++)
        __builtin_amdgcn_global_load_lds((const AS1 void*)(Bb + ko + (i*32+rbase)*K + slot*8),
            (AS3 void*)(&lds[cur^1][4096 + i*2048 + wave*512]), 16, 0, 0);
    }
    const char* Ls = (const char*)&lds[cur][0];
    #pragma unroll
    for (int ks=0;ks<2;ks++){
      f16x8 af[2], bf[4];
      #pragma unroll
      for (int m=0;m<2;m++) af[m] = *(const f16x8*)(Ls + abyte[ks][m]);
      #pragma unroll
      for (int n=0;n<4;n++) bf[n] = *(const f16x8*)(Ls + bbyte[ks][n]);
      #pragma unroll
      for (int m=0;m<2;m++)
        #pragma unroll
        for (int n=0;n<4;n++)
          acc[m][n] = __builtin_amdgcn_mfma_f32_16x16x32_f16(af[m], bf[n], acc[m][n], 0, 0, 0);
    }
    __syncthreads();
    cur ^= 1;
  }

  #pragma unroll
  for (int m=0;m<2;m++){
    int row0 = tr*64 + wr*32 + m*16 + ((lane>>4)<<2);
    #pragma unroll
    for (int n=0;n<4;n++){
      int col = tc*128 + wc*64 + n*16 + (lane&15);
      #pragma unroll
      for (int q2=0;q2<4;q2++)
        C[(long)(row0+q2)*Nc + col] = (f16)acc[m][n][q2];
    }
  }

  if (alp){
    int head = tc*2 + wc;
    const float* alh = alp + head*64;
    const float* arh = arp + head*64;
    float alv[4], arv[4];
    #pragma unroll
    for (int n=0;n<4;n++){ int d = n*16 + (lane&15); alv[n]=alh[d]; arv[n]=arh[d]; }
    float* elo = elp + (long)task*NN*8;
    float* ero = erp + (long)task*NN*8;
    #pragma unroll
    for (int m=0;m<2;m++){
      float e0,e1,e2,e3,r0,r1,r2,r3;
      #pragma unroll
      for (int qq=0;qq<4;qq++){
        float e=0.f, rr=0.f;
        #pragma unroll
        for (int n=0;n<4;n++){ e += acc[m][n][qq]*alv[n]; rr += acc[m][n][qq]*arv[n]; }
        #pragma unroll
        for (int off=1; off<16; off<<=1){ e += __shfl_xor(e, off); rr += __shfl_xor(rr, off); }
        if (qq==0){e0=e;r0=rr;} else if (qq==1){e1=e;r1=rr;} else if (qq==2){e2=e;r2=rr;} else {e3=e;r3=rr;}
      }
      int qq = lane&15;
      if (qq < 4){
        int node = tr*64 + wr*32 + m*16 + ((lane>>4)<<2) + qq;
        if (node < NN){
          float ev = qq==0?e0:(qq==1?e1:(qq==2?e2:e3));
          float rv = qq==0?r0:(qq==1?r1:(qq==2?r2:r3));
          long o = (long)node*8 + head;
          elo[o] = ev;
          ero[o] = rv;
        }
      }
    }
  }
}

// ---------------- attention aggregation (batched over graphs) ----------------
#define MAXD 128

struct AggArgs {
  const int* rp[3]; const int* cs[3];
  const float* el; const float* er;
  const f16* feat[3];
  const float* bias;
  f16* outH[3];
  float* outF[3];
};

__global__ __launch_bounds__(256) void k_agg_b(AggArgs a){
  int b = blockIdx.x;
  int g = b / NN, n = b - g*NN;
  const int* rowptr = a.rp[g];
  const int* colsrc = a.cs[g];
  const float* el = a.el + (long)g*NN*8;
  const f16* featH = a.feat[g];
  int t = threadIdx.x;
  __shared__ float sm[MAXD*8];
  __shared__ int   scol[MAXD];
  __shared__ float red[256];
  __shared__ float inv[8];
  __shared__ float ern[8];
  if (t < 8) ern[t] = a.er[((long)g*NN+n)*8+t];
  __syncthreads();
  int j0 = rowptr[n], deg = rowptr[n+1]-j0;
  {
    int h = t & 7;
    float dsum = 0.f;
    for (int jj = t>>3; jj < deg; jj += 32){
      int s = colsrc[j0+jj];
      float v = el[s*8+h] + ern[h];
      v = (v>0.f)? v : 0.2f*v;
      float ex = __expf(v);
      dsum += ex;
      if (jj < MAXD){
        sm[jj*8+h] = ex;
        if (h==0) scol[jj] = s;
      }
    }
    red[t] = dsum; __syncthreads();
    if (t<128) red[t] += red[t+128]; __syncthreads();
    if (t<64)  red[t] += red[t+64];  __syncthreads();
    if (t<32)  red[t] += red[t+32];  __syncthreads();
    if (t<16)  red[t] += red[t+16];  __syncthreads();
    if (t<8)   inv[t] = 1.0f / (red[t] + red[t+8]);
    __syncthreads();
  }
  int h = t >> 5;
  int c = t*2;
  float a0=0.f, a1=0.f;
  float ivh = inv[h];
  for (int jj=0; jj<deg; jj++){
    int s; float ex;
    if (jj < MAXD){ s = scol[jj]; ex = sm[jj*8+h]; }
    else {
      s = colsrc[j0+jj];
      float v = el[s*8+h] + ern[h];
      v = (v>0.f)? v : 0.2f*v;
      ex = __expf(v);
    }
    float alpha = ex * ivh;
    f16x2 f = *(const f16x2*)(featH + (long)s*FF + c);
    a0 += alpha*(float)f[0];
    a1 += alpha*(float)f[1];
  }
  a0 += a.bias[c]; a1 += a.bias[c+1];
  a0 = (a0>0.f)? a0 : __expf(a0)-1.f;
  a1 = (a1>0.f)? a1 : __expf(a1)-1.f;
  f16x2 o; o[0]=(f16)a0; o[1]=(f16)a1;
  *(f16x2*)(a.outH[g] + (long)n*FF + c) = o;
  float* oF = a.outF[g];
  if (oF){
    oF[(long)n*FF + c]     = a0;
    oF[(long)n*FF + c + 1] = a1;
  }
}

// classifier el/er over 4 tasks
__global__ void k_elerc_b(const f16* __restrict__ fc,
    const float* __restrict__ alc0, const float* __restrict__ arc0,
    const float* __restrict__ alc1, const float* __restrict__ arc1,
    float* __restrict__ el, float* __restrict__ er){
  int idx = blockIdx.x*256 + threadIdx.x;
  if (idx >= 4*NN*8) return;
  int ti = idx / (NN*8);
  int rem = idx - ti*NN*8;
  int n = rem>>3, hh = rem&7;
  const f16* featc = fc + (long)ti*NP*128;
  const float* al = (ti&1) ? alc1 : alc0;
  const float* ar_ = (ti&1) ? arc1 : arc0;
  float a=0.f, bsum=0.f;
  #pragma unroll
  for (int cc=0; cc<5; cc++){
    float v = (float)featc[(long)n*128 + hh*5 + cc];
    a += v*al[hh*5+cc];
    bsum += v*ar_[hh*5+cc];
  }
  el[idx]=a; er[idx]=bsum;
}

struct ClsArgs {
  const int* rp[3]; const int* cs[3];
  const float* el; const float* er;
  const f16* fc;
  const float* bc[2];
  float* pred;
};

__global__ __launch_bounds__(64) void k_cls_b(ClsArgs a){
  int b = blockIdx.x;
  int ti = b / NN, n = b - ti*NN;
  int g = ti<2 ? ti : 2;
  int ci = ti&1;
  const int* rowptr = a.rp[g];
  const int* colsrc = a.cs[g];
  const float* el = a.el + (long)ti*NN*8;
  const f16* featc = a.fc + (long)ti*NP*128;
  const float* bc = a.bc[ci];
  float* pred = a.pred + (long)ti*5*NN;
  int l = threadIdx.x;
  __shared__ float sm[MAXD*8];
  __shared__ int   scol[MAXD];
  __shared__ float inv[8];
  __shared__ float ern[8];
  __shared__ float lg[40];
  if (l<8) ern[l] = a.er[((long)ti*NN+n)*8+l];
  __syncthreads();
  int j0 = rowptr[n], deg = rowptr[n+1]-j0;
  {
    int h = l & 7;
    float dsum = 0.f;
    for (int jj = l>>3; jj < deg; jj += 8){
      int s = colsrc[j0+jj];
      float v = el[s*8+h] + ern[h];
      v = (v>0.f)? v : 0.2f*v;
      float ex = __expf(v);
      dsum += ex;
      if (jj < MAXD){
        sm[jj*8+h] = ex;
        if (h==0) scol[jj] = s;
      }
    }
    dsum += __shfl_xor(dsum, 8);
    dsum += __shfl_xor(dsum, 16);
    dsum += __shfl_xor(dsum, 32);
    if (l<8) inv[l] = 1.0f/dsum;
  }
  __syncthreads();
  if (l<40){
    int h = l/5;
    float ivh = inv[h];
    float acc = 0.f;
    for (int jj=0; jj<deg; jj++){
      int s; float ex;
      if (jj < MAXD){ s = scol[jj]; ex = sm[jj*8+h]; }
      else {
        s = colsrc[j0+jj];
        float v = el[s*8+h] + ern[h];
        v = (v>0.f)? v : 0.2f*v;
        ex = __expf(v);
      }
      acc += ex*ivh * (float)featc[(long)s*128 + l];
    }
    acc += (float)featc[(long)n*128 + 40 + l];
    acc += bc[l];
    lg[l] = acc;
  }
  __syncthreads();
  if (l<5){
    float p=0.f;
    #pragma unroll
    for (int h=0;h<8;h++) p += lg[h*5+l];
    pred[(long)n*5 + l] = p*0.125f;
  }
}

// ---------------- host orchestration ----------------
extern "C" void kernel_launch(void* const* d_in, const int* in_sizes, int n_in,
                              void* d_out, int out_size, void* d_ws, size_t ws_size,
                              hipStream_t stream){
  const int* srcs[3] = {(const int*)d_in[0], (const int*)d_in[2], (const int*)d_in[4]};
  const int* dsts[3] = {(const int*)d_in[1], (const int*)d_in[3], (const int*)d_in[5]};
  int E[3] = {in_sizes[0], in_sizes[2], in_sizes[4]};
  const float* X[3] = {(const float*)d_in[6], (const float*)d_in[7], (const float*)d_in[8]};
  const float* W0  = (const float*)d_in[9];
  const float* al0 = (const float*)d_in[10];
  const float* ar0 = (const float*)d_in[11];
  const float* b0  = (const float*)d_in[12];
  const float* W1  = (const float*)d_in[13];
  const float* al1 = (const float*)d_in[14];
  const float* ar1 = (const float*)d_in[15];
  const float* b1  = (const float*)d_in[16];
  const float* Wcv[2] = {(const float*)d_in[17], (const float*)d_in[22]};
  const float* alc[2] = {(const float*)d_in[18], (const float*)d_in[23]};
  const float* arc[2] = {(const float*)d_in[19], (const float*)d_in[24]};
  const float* bcv[2] = {(const float*)d_in[20], (const float*)d_in[25]};
  const float* rWv[2] = {(const float*)d_in[21], (const float*)d_in[26]};

  float* out = (float*)d_out;
  float* embOut[3] = {out+200000, out+200000+(long)NN*FF, out+200000+2L*NN*FF};

  char* w = (char*)d_ws;
  size_t off = 0;
  auto alloc = [&](size_t bytes)->void*{
    void* p = (void*)(w + off);
    off += (bytes + 255) & ~((size_t)255);
    return p;
  };
  f16* W0T = (f16*)alloc((size_t)FF*KK0*2);
  f16* W1T = (f16*)alloc((size_t)FF*FF*2);
  f16* WcT[2] = {(f16*)alloc(128*512*2), (f16*)alloc(128*512*2)};
  f16* feat0H[3], *h0H[3], *feat1H[3], *embH[3];
  for (int g=0;g<3;g++) feat0H[g] = (f16*)alloc((size_t)NP*FF*2);
  for (int g=0;g<3;g++) h0H[g]    = (f16*)alloc((size_t)NP*FF*2);
  for (int g=0;g<3;g++) feat1H[g] = (f16*)alloc((size_t)NP*FF*2);
  for (int g=0;g<3;g++) embH[g]   = (f16*)alloc((size_t)NP*FF*2);
  f16* featc = (f16*)alloc((size_t)4*NP*128*2);
  float* el_e = (float*)alloc((size_t)3*NN*8*4);
  float* er_e = (float*)alloc((size_t)3*NN*8*4);
  float* el_c = (float*)alloc((size_t)4*NN*8*4);
  float* er_c = (float*)alloc((size_t)4*NN*8*4);
  int* deg    = (int*)alloc((size_t)3*NN*4);
  int* cursor = (int*)alloc((size_t)3*NN*4);
  int* rowptr = (int*)alloc((size_t)3*(NN+1)*4);
  int* colsrc[3];
  for (int g=0;g<3;g++) colsrc[g] = (int*)alloc((size_t)E[g]*4);
  (void)ws_size; (void)n_in; (void)out_size;

  // ---- CSR (3 graphs, batched) ----
  int nb[3] = {(E[0]+255)/256, (E[1]+255)/256, (E[2]+255)/256};
  hipMemsetAsync(deg, 0, (size_t)3*NN*4, stream);
  k_count_b<<<nb[0]+nb[1]+nb[2], 256, 0, stream>>>(dsts[0], dsts[1], dsts[2],
      E[0], E[1], E[2], nb[0], nb[1], deg);
  k_scan_b<<<3, 1024, 0, stream>>>(deg, rowptr, cursor);
  k_fill_b<<<nb[0]+nb[1]+nb[2], 256, 0, stream>>>(srcs[0], dsts[0], srcs[1], dsts[1],
      srcs[2], dsts[2], E[0], E[1], E[2], nb[0], nb[1], cursor,
      colsrc[0], colsrc[1], colsrc[2]);

  // ---- weight prep ----
  k_transpose_t<<<dim3(FF/32, KK0/32), dim3(32,8), 0, stream>>>(W0, W0T, KK0, FF);
  k_transpose_t<<<dim3(FF/32, FF/32), dim3(32,8), 0, stream>>>(W1, W1T, FF, FF);
  k_pack_wc<<<(128*512+255)/256, 256, 0, stream>>>(Wcv[0], rWv[0], WcT[0]);
  k_pack_wc<<<(128*512+255)/256, 256, 0, stream>>>(Wcv[1], rWv[1], WcT[1]);

  const int* rp[3] = {rowptr, rowptr+(NN+1), rowptr+2*(NN+1)};

  // ---- layer 0: fused convert+GEMM+eler, then aggregation ----
  k_gemm0<<<3*632, 256, 0, stream>>>(X[0], X[1], X[2],
      feat0H[0], feat0H[1], feat0H[2], W0T, al0, ar0, el_e, er_e);
  {
    AggArgs a;
    for (int g=0;g<3;g++){ a.rp[g]=rp[g]; a.cs[g]=colsrc[g]; a.feat[g]=feat0H[g];
                           a.outH[g]=h0H[g]; a.outF[g]=nullptr; }
    a.el = el_e; a.er = er_e; a.bias = b0;
    k_agg_b<<<3*NN, 256, 0, stream>>>(a);
  }

  // ---- layer 1: GEMM+eler (3 tasks) + aggregation ----
  {
    GemmTasks p;
    for (int i=0;i<4;i++){ int g = i<3?i:0; p.A[i]=h0H[g]; p.B[i]=W1T; p.C[i]=feat1H[g]; }
    k_gemmb<<<3*632, 256, 0, stream>>>(p, 632, 4, FF, FF, al1, ar1, el_e, er_e);
  }
  {
    AggArgs a;
    for (int g=0;g<3;g++){ a.rp[g]=rp[g]; a.cs[g]=colsrc[g]; a.feat[g]=feat1H[g];
                           a.outH[g]=embH[g]; a.outF[g]=embOut[g]; }
    a.el = el_e; a.er = er_e; a.bias = b1;
    k_agg_b<<<3*NN, 256, 0, stream>>>(a);
  }

  // ---- classifiers (4 tasks batched): (g,c) = (0,0),(1,1),(2,0),(2,1) ----
  {
    GemmTasks p;
    const int tg[4] = {0,1,2,2};
    for (int i=0;i<4;i++){ p.A[i]=embH[tg[i]]; p.B[i]=WcT[i&1]; p.C[i]=featc + (long)i*NP*128; }
    k_gemmb<<<4*158, 256, 0, stream>>>(p, 158, 1, 128, FF,
        (const float*)nullptr, (const float*)nullptr, (float*)nullptr, (float*)nullptr);
  }
  k_elerc_b<<<(4*NN*8+255)/256, 256, 0, stream>>>(featc, alc[0], arc[0], alc[1], arc[1], el_c, er_c);
  {
    ClsArgs a;
    for (int g=0;g<3;g++){ a.rp[g]=rp[g]; a.cs[g]=colsrc[g]; }
    a.el = el_c; a.er = er_c; a.fc = featc;
    a.bc[0] = bcv[0]; a.bc[1] = bcv[1];
    a.pred = out;
    k_cls_b<<<4*NN, 64, 0, stream>>>(a);
  }
}

// Round 6
// 615.355 us; speedup vs baseline: 2.0187x; 1.0028x over previous
//
#include <hip/hip_runtime.h>
#include <stdint.h>

typedef _Float16 f16;
typedef _Float16 f16x2 __attribute__((ext_vector_type(2)));
typedef _Float16 f16x8 __attribute__((ext_vector_type(8)));
typedef float f32x4 __attribute__((ext_vector_type(4)));

#define AS1 __attribute__((address_space(1)))
#define AS3 __attribute__((address_space(3)))

#define NN 10000
#define NP 10112
#define KK0 4096
#define FF 512

// ---------------- CSR build (batched over 3 graphs) ----------------
__global__ void k_count_b(const int* __restrict__ d0, const int* __restrict__ d1,
                          const int* __restrict__ d2, int E0, int E1, int E2,
                          int nb0, int nb1, int* __restrict__ deg){
  int b = blockIdx.x;
  const int* d; int Eg, base, lb;
  if (b < nb0){ d=d0; Eg=E0; base=0; lb=b; }
  else if (b < nb0+nb1){ d=d1; Eg=E1; base=NN; lb=b-nb0; }
  else { d=d2; Eg=E2; base=2*NN; lb=b-nb0-nb1; }
  int i = lb*256 + threadIdx.x;
  if (i < Eg) atomicAdd(&deg[base + d[i]], 1);
}

__global__ __launch_bounds__(1024) void k_scan_b(const int* __restrict__ deg_all,
    int* __restrict__ rowptr_all, int* __restrict__ cursor_all){
  int g = blockIdx.x;
  const int* deg = deg_all + g*NN;
  int* rowptr = rowptr_all + g*(NN+1);
  int* cursor = cursor_all + g*NN;
  __shared__ int ps[1024];
  int t = threadIdx.x;
  const int CH = 16;
  int i0 = t*CH;
  int sum = 0;
  for (int k=0;k<CH;k++){ int i=i0+k; if (i<NN) sum += deg[i]; }
  ps[t]=sum; __syncthreads();
  for (int off=1; off<1024; off<<=1){
    int v = (t>=off)? ps[t-off] : 0;
    __syncthreads();
    ps[t] += v;
    __syncthreads();
  }
  int run = ps[t]-sum;
  for (int k=0;k<CH;k++){
    int i=i0+k;
    if (i<=NN) rowptr[i]=run;
    if (i<NN){ cursor[i]=run; run += deg[i]; }
  }
}

__global__ void k_fill_b(const int* __restrict__ s0, const int* __restrict__ d0,
                         const int* __restrict__ s1, const int* __restrict__ d1,
                         const int* __restrict__ s2, const int* __restrict__ d2,
                         int E0, int E1, int E2, int nb0, int nb1,
                         int* __restrict__ cursor_all,
                         int* __restrict__ c0, int* __restrict__ c1, int* __restrict__ c2){
  int b = blockIdx.x;
  const int *s, *d; int Eg, lb; int* cur; int* col;
  if (b < nb0){ s=s0; d=d0; Eg=E0; lb=b; cur=cursor_all; col=c0; }
  else if (b < nb0+nb1){ s=s1; d=d1; Eg=E1; lb=b-nb0; cur=cursor_all+NN; col=c1; }
  else { s=s2; d=d2; Eg=E2; lb=b-nb0-nb1; cur=cursor_all+2*NN; col=c2; }
  int i = lb*256 + threadIdx.x;
  if (i >= Eg) return;
  int slot = atomicAdd(&cur[d[i]], 1);
  col[slot] = s[i];
}

// ---------------- weight prep ----------------
__global__ void k_transpose_t(const float* __restrict__ W, f16* __restrict__ WT,
                              int K, int Nc){
  __shared__ float tile[32][33];
  int n0 = blockIdx.x*32, k0 = blockIdx.y*32;
  int tx = threadIdx.x, ty = threadIdx.y;
  #pragma unroll
  for (int i=0;i<32;i+=8)
    tile[ty+i][tx] = W[(long)(k0+ty+i)*Nc + n0+tx];
  __syncthreads();
  #pragma unroll
  for (int i=0;i<32;i+=8)
    WT[(long)(n0+ty+i)*K + k0+tx] = (f16)tile[tx][ty+i];
}

__global__ void k_pack_wc(const float* __restrict__ Wc, const float* __restrict__ rW,
                          f16* __restrict__ WT){
  int idx = blockIdx.x*256 + threadIdx.x;
  if (idx >= 128*512) return;
  int n = idx >> 9; int k = idx & 511;
  float v = 0.f;
  if (n < 40) v = Wc[k*40 + n];
  else if (n < 80) v = rW[k*40 + (n-40)];
  WT[idx] = (f16)v;
}

// ---------------- wide-tile GEMM: C (Np x 512) = A * B^T, 3 tasks in one grid
// BM=64, BN=512 (full width -> A read ONCE), 512 threads = 8 waves, wave = 64x64
// sub-tile = one head. LDS 2 x (A 8KB + B 64KB) = 144KB, 1 block/CU.
// CVT=true: A fp32 (reg-staged convert, counted-vmcnt pipeline), K=4096.
// CVT=false: A f16 via global_load_lds, K=512.
template<bool CVT>
__global__ __launch_bounds__(512,1) void k_gemmw(
    const void* __restrict__ A0v, const void* __restrict__ A1v, const void* __restrict__ A2v,
    f16* __restrict__ C0, f16* __restrict__ C1, f16* __restrict__ C2,
    const f16* __restrict__ B,
    const float* __restrict__ alp, const float* __restrict__ arp,
    float* __restrict__ elp, float* __restrict__ erp)
{
  constexpr int K = CVT ? KK0 : FF;
  constexpr int nt = K >> 6;
  __shared__ f16 lds[2][36864];   // per buf: A 64x64 (8KB) + B 512x64 (64KB)

  const int nwg = gridDim.x;               // 474
  const int qd = nwg>>3, rd = nwg&7;
  const int xcd = blockIdx.x & 7, bx = blockIdx.x >> 3;
  const int wid = (xcd < rd ? xcd*(qd+1) : rd*(qd+1) + (xcd-rd)*qd) + bx;
  const int task = wid / 158;
  const int tr = wid - task*158;

  f16* C = task==0?C0:(task==1?C1:C2);

  const int t = threadIdx.x;
  const int wave = t >> 6, lane = t & 63;
  const int slot = (lane&7) ^ (lane>>3);
  const int arow = t >> 3;                  // 0..63
  const int ak8 = t & 7;

  // B staging: 8 x global_load_lds per thread (512 rows x 64 k)
  #define GLDSB(kt, buf) { \
    int ko = (kt)*64; \
    _Pragma("unroll") \
    for (int i=0;i<8;i++){ \
      int br = i*64 + wave*8 + (lane>>3); \
      __builtin_amdgcn_global_load_lds((const AS1 void*)(B + (long)br*K + ko + slot*8), \
          (AS3 void*)(&lds[buf][4096 + i*4096 + wave*512]), 16, 0, 0); \
    } }

  // fragment addresses (byte offsets into lds[buf])
  int abyte[2][4], bbyte[2][4];
  #pragma unroll
  for (int ks=0;ks<2;ks++){
    #pragma unroll
    for (int m=0;m<4;m++){
      int row = m*16 + (lane&15);
      abyte[ks][m] = row*128 + (((ks*4 + (lane>>4))*16) ^ ((row&7)<<4));
    }
    #pragma unroll
    for (int n=0;n<4;n++){
      int brow = wave*64 + n*16 + (lane&15);
      bbyte[ks][n] = 8192 + brow*128 + (((ks*4 + (lane>>4))*16) ^ ((brow&7)<<4));
    }
  }

  f32x4 zero4 = {0.f,0.f,0.f,0.f};
  f32x4 acc[4][4];
  #pragma unroll
  for (int m=0;m<4;m++)
    #pragma unroll
    for (int n=0;n<4;n++) acc[m][n] = zero4;

  #define MFMA_TILE(buf) { \
    const char* Ls = (const char*)&lds[buf][0]; \
    _Pragma("unroll") \
    for (int ks=0;ks<2;ks++){ \
      f16x8 af[4], bf[4]; \
      _Pragma("unroll") \
      for (int m=0;m<4;m++) af[m] = *(const f16x8*)(Ls + abyte[ks][m]); \
      _Pragma("unroll") \
      for (int n=0;n<4;n++) bf[n] = *(const f16x8*)(Ls + bbyte[ks][n]); \
      _Pragma("unroll") \
      for (int m=0;m<4;m++) \
        _Pragma("unroll") \
        for (int n=0;n<4;n++) \
          acc[m][n] = __builtin_amdgcn_mfma_f32_16x16x32_f16(af[m], bf[n], acc[m][n], 0, 0, 0); \
    } }

  int cur = 0;
  if constexpr (CVT){
    // ---- fp32 A, reg-staged conversion, counted-vmcnt pipeline ----
    const float* Af = task==0?(const float*)A0v:(task==1?(const float*)A1v:(const float*)A2v);
    const bool okA = (tr*64 + arow) < NN;
    const float* gA = Af + (long)(okA ? tr*64+arow : 0)*KK0 + ak8*8;
    f32x4 arE0, arE1;

    #define LOADA(kt) { arE0 = *(const f32x4*)(gA + (kt)*64); \
                        arE1 = *(const f32x4*)(gA + (kt)*64 + 4); }
    #define WRITEA(buf) { \
      f16x8 v; \
      _Pragma("unroll") \
      for (int j=0;j<4;j++){ \
        v[j]   = okA ? (f16)arE0[j] : (f16)0.f; \
        v[4+j] = okA ? (f16)arE1[j] : (f16)0.f; \
      } \
      *(f16x8*)(&lds[buf][arow*64 + ((ak8 ^ (arow&7))*8)]) = v; }

    LOADA(0);                      // vm: L_A(0)=2
    __builtin_amdgcn_sched_barrier(0);
    GLDSB(0, 0);                   // +8
    __builtin_amdgcn_sched_barrier(0);
    WRITEA(0);                     // compiler waits L_A(0) -> vmcnt(8)
    __builtin_amdgcn_sched_barrier(0);
    LOADA(1);                      // +2
    __builtin_amdgcn_sched_barrier(0);
    asm volatile("s_waitcnt vmcnt(2) lgkmcnt(0)" ::: "memory");  // B staged, L_A(1) flying
    __builtin_amdgcn_s_barrier();

    for (int kt=0; kt<nt; kt++){
      if (kt+1 < nt){
        WRITEA(cur^1);             // waits L_A(kt+1) (only outstanding)
        __builtin_amdgcn_sched_barrier(0);
        GLDSB(kt+1, cur^1);        // +8
        __builtin_amdgcn_sched_barrier(0);
      }
      if (kt+2 < nt){
        LOADA(kt+2);               // +2, after B-stage in queue order
        __builtin_amdgcn_sched_barrier(0);
      }
      MFMA_TILE(cur);
      if (kt+1 < nt){
        __builtin_amdgcn_sched_barrier(0);
        if (kt+2 < nt)
          asm volatile("s_waitcnt vmcnt(2) lgkmcnt(0)" ::: "memory");
        else
          asm volatile("s_waitcnt vmcnt(0) lgkmcnt(0)" ::: "memory");
        __builtin_amdgcn_s_barrier();
      }
      cur ^= 1;
    }
    #undef LOADA
    #undef WRITEA
  } else {
    // ---- f16 A via global_load_lds, simple double-buffered loop ----
    const f16* Ah = task==0?(const f16*)A0v:(task==1?(const f16*)A1v:(const f16*)A2v);
    const f16* Ab = Ah + (long)tr*64*K;
    const int aslot = ak8 ^ (arow&7);

    #define GLDSA(kt, buf) \
      __builtin_amdgcn_global_load_lds((const AS1 void*)(Ab + (long)arow*K + (kt)*64 + aslot*8), \
          (AS3 void*)(&lds[buf][wave*512]), 16, 0, 0);

    GLDSA(0, 0);
    GLDSB(0, 0);
    __syncthreads();
    for (int kt=0; kt<nt; kt++){
      if (kt+1 < nt){
        GLDSA(kt+1, cur^1);
        GLDSB(kt+1, cur^1);
      }
      MFMA_TILE(cur);
      __syncthreads();
      cur ^= 1;
    }
    #undef GLDSA
  }
  #undef GLDSB
  #undef MFMA_TILE

  // ---- C write: row = m*16 + (lane>>4)*4 + q, col = wave*64 + n*16 + (lane&15)
  #pragma unroll
  for (int m=0;m<4;m++){
    int row0 = tr*64 + m*16 + ((lane>>4)<<2);
    #pragma unroll
    for (int n=0;n<4;n++){
      int col = wave*64 + n*16 + (lane&15);
      #pragma unroll
      for (int q2=0;q2<4;q2++)
        C[(long)(row0+q2)*FF + col] = (f16)acc[m][n][q2];
    }
  }

  // ---- el/er epilogue: wave == head
  {
    const int head = wave;
    const float* alh = alp + head*64;
    const float* arh = arp + head*64;
    float alv[4], arv[4];
    #pragma unroll
    for (int n=0;n<4;n++){ int d = n*16 + (lane&15); alv[n]=alh[d]; arv[n]=arh[d]; }
    float* elo = elp + (long)task*NN*8;
    float* ero = erp + (long)task*NN*8;
    #pragma unroll
    for (int m=0;m<4;m++){
      float e0,e1,e2,e3,r0,r1,r2,r3;
      #pragma unroll
      for (int qq=0;qq<4;qq++){
        float e=0.f, rr=0.f;
        #pragma unroll
        for (int n=0;n<4;n++){ e += acc[m][n][qq]*alv[n]; rr += acc[m][n][qq]*arv[n]; }
        #pragma unroll
        for (int off=1; off<16; off<<=1){ e += __shfl_xor(e, off); rr += __shfl_xor(rr, off); }
        if (qq==0){e0=e;r0=rr;} else if (qq==1){e1=e;r1=rr;} else if (qq==2){e2=e;r2=rr;} else {e3=e;r3=rr;}
      }
      int qq = lane&15;
      if (qq < 4){
        int node = tr*64 + m*16 + ((lane>>4)<<2) + qq;
        if (node < NN){
          float ev = qq==0?e0:(qq==1?e1:(qq==2?e2:e3));
          float rv = qq==0?r0:(qq==1?r1:(qq==2?r2:r3));
          long o = (long)node*8 + head;
          elo[o] = ev;
          ero[o] = rv;
        }
      }
    }
  }
}

// ---------------- classifier GEMM (4 tasks, Nc=128, K=512) ----------------
struct GemmTasks { const f16* A[4]; const f16* B[4]; f16* C[4]; };

__global__ __launch_bounds__(256,3) void k_gemmb(GemmTasks p, int ntpb, int ntn,
                                                 int Nc, int K){
  __shared__ f16 lds[2][12288];
  const int bid = blockIdx.x;
  const int task = bid / ntpb;
  const int orig = bid - task*ntpb;
  const int q = ntpb >> 3, r = ntpb & 7;
  const int xcd = orig & 7, bx = orig >> 3;
  const int wid = (xcd < r ? xcd*(q+1) : r*(q+1) + (xcd-r)*q) + bx;
  const int tr = wid / ntn, tc = wid - tr*ntn;

  const f16* A = p.A[task];
  const f16* B = p.B[task];
  f16* C = p.C[task];

  const int t = threadIdx.x;
  const int wave = t >> 6, lane = t & 63;
  const int wr = wave >> 1, wc = wave & 1;

  const f16* Ab = A + (long)tr*64*K;
  const f16* Bb = B + (long)tc*128*K;

  const int slot = (lane&7) ^ (lane>>3);
  const int rbase = wave*8 + (lane>>3);

  f32x4 zero4 = {0.f,0.f,0.f,0.f};
  f32x4 acc[2][4];
  #pragma unroll
  for (int m=0;m<2;m++)
    #pragma unroll
    for (int n=0;n<4;n++) acc[m][n] = zero4;

  int abyte[2][2], bbyte[2][4];
  #pragma unroll
  for (int ks=0;ks<2;ks++){
    #pragma unroll
    for (int m=0;m<2;m++){
      int row = wr*32 + m*16 + (lane&15);
      abyte[ks][m] = row*128 + (((ks*4 + (lane>>4))*16) ^ ((row&7)<<4));
    }
    #pragma unroll
    for (int n=0;n<4;n++){
      int brow = wc*64 + n*16 + (lane&15);
      bbyte[ks][n] = 8192 + brow*128 + (((ks*4 + (lane>>4))*16) ^ ((brow&7)<<4));
    }
  }

  const int nt = K >> 6;
  int cur = 0;

  #pragma unroll
  for (int i=0;i<2;i++)
    __builtin_amdgcn_global_load_lds((const AS1 void*)(Ab + (i*32+rbase)*K + slot*8),
        (AS3 void*)(&lds[0][i*2048 + wave*512]), 16, 0, 0);
  #pragma unroll
  for (int i=0;i<4;i++)
    __builtin_amdgcn_global_load_lds((const AS1 void*)(Bb + (i*32+rbase)*K + slot*8),
        (AS3 void*)(&lds[0][4096 + i*2048 + wave*512]), 16, 0, 0);
  __syncthreads();

  for (int kt=0; kt<nt; kt++){
    if (kt+1 < nt){
      int ko = (kt+1)<<6;
      #pragma unroll
      for (int i=0;i<2;i++)
        __builtin_amdgcn_global_load_lds((const AS1 void*)(Ab + ko + (i*32+rbase)*K + slot*8),
            (AS3 void*)(&lds[cur^1][i*2048 + wave*512]), 16, 0, 0);
      #pragma unroll
      for (int i=0;i<4;i++)
        __builtin_amdgcn_global_load_lds((const AS1 void*)(Bb + ko + (i*32+rbase)*K + slot*8),
            (AS3 void*)(&lds[cur^1][4096 + i*2048 + wave*512]), 16, 0, 0);
    }
    const char* Ls = (const char*)&lds[cur][0];
    #pragma unroll
    for (int ks=0;ks<2;ks++){
      f16x8 af[2], bf[4];
      #pragma unroll
      for (int m=0;m<2;m++) af[m] = *(const f16x8*)(Ls + abyte[ks][m]);
      #pragma unroll
      for (int n=0;n<4;n++) bf[n] = *(const f16x8*)(Ls + bbyte[ks][n]);
      #pragma unroll
      for (int m=0;m<2;m++)
        #pragma unroll
        for (int n=0;n<4;n++)
          acc[m][n] = __builtin_amdgcn_mfma_f32_16x16x32_f16(af[m], bf[n], acc[m][n], 0, 0, 0);
    }
    __syncthreads();
    cur ^= 1;
  }

  #pragma unroll
  for (int m=0;m<2;m++){
    int row0 = tr*64 + wr*32 + m*16 + ((lane>>4)<<2);
    #pragma unroll
    for (int n=0;n<4;n++){
      int col = tc*128 + wc*64 + n*16 + (lane&15);
      #pragma unroll
      for (int q2=0;q2<4;q2++)
        C[(long)(row0+q2)*Nc + col] = (f16)acc[m][n][q2];
    }
  }
}

// ---------------- attention aggregation (batched over graphs) ----------------
#define MAXD 128

struct AggArgs {
  const int* rp[3]; const int* cs[3];
  const float* el; const float* er;
  const f16* feat[3];
  const float* bias;
  f16* outH[3];
  float* outF[3];
};

__global__ __launch_bounds__(256) void k_agg_b(AggArgs a){
  int b = blockIdx.x;
  int g = b / NN, n = b - g*NN;
  const int* rowptr = a.rp[g];
  const int* colsrc = a.cs[g];
  const float* el = a.el + (long)g*NN*8;
  const f16* featH = a.feat[g];
  int t = threadIdx.x;
  __shared__ float sm[MAXD*8];
  __shared__ int   scol[MAXD];
  __shared__ float red[256];
  __shared__ float inv[8];
  __shared__ float ern[8];
  if (t < 8) ern[t] = a.er[((long)g*NN+n)*8+t];
  __syncthreads();
  int j0 = rowptr[n], deg = rowptr[n+1]-j0;
  {
    int h = t & 7;
    float dsum = 0.f;
    for (int jj = t>>3; jj < deg; jj += 32){
      int s = colsrc[j0+jj];
      float v = el[s*8+h] + ern[h];
      v = (v>0.f)? v : 0.2f*v;
      float ex = __expf(v);
      dsum += ex;
      if (jj < MAXD){
        sm[jj*8+h] = ex;
        if (h==0) scol[jj] = s;
      }
    }
    red[t] = dsum; __syncthreads();
    if (t<128) red[t] += red[t+128]; __syncthreads();
    if (t<64)  red[t] += red[t+64];  __syncthreads();
    if (t<32)  red[t] += red[t+32];  __syncthreads();
    if (t<16)  red[t] += red[t+16];  __syncthreads();
    if (t<8)   inv[t] = 1.0f / (red[t] + red[t+8]);
    __syncthreads();
  }
  int h = t >> 5;
  int c = t*2;
  float a0=0.f, a1=0.f;
  float ivh = inv[h];
  for (int jj=0; jj<deg; jj++){
    int s; float ex;
    if (jj < MAXD){ s = scol[jj]; ex = sm[jj*8+h]; }
    else {
      s = colsrc[j0+jj];
      float v = el[s*8+h] + ern[h];
      v = (v>0.f)? v : 0.2f*v;
      ex = __expf(v);
    }
    float alpha = ex * ivh;
    f16x2 f = *(const f16x2*)(featH + (long)s*FF + c);
    a0 += alpha*(float)f[0];
    a1 += alpha*(float)f[1];
  }
  a0 += a.bias[c]; a1 += a.bias[c+1];
  a0 = (a0>0.f)? a0 : __expf(a0)-1.f;
  a1 = (a1>0.f)? a1 : __expf(a1)-1.f;
  f16x2 o; o[0]=(f16)a0; o[1]=(f16)a1;
  *(f16x2*)(a.outH[g] + (long)n*FF + c) = o;
  float* oF = a.outF[g];
  if (oF){
    oF[(long)n*FF + c]     = a0;
    oF[(long)n*FF + c + 1] = a1;
  }
}

// classifier el/er over 4 tasks
__global__ void k_elerc_b(const f16* __restrict__ fc,
    const float* __restrict__ alc0, const float* __restrict__ arc0,
    const float* __restrict__ alc1, const float* __restrict__ arc1,
    float* __restrict__ el, float* __restrict__ er){
  int idx = blockIdx.x*256 + threadIdx.x;
  if (idx >= 4*NN*8) return;
  int ti = idx / (NN*8);
  int rem = idx - ti*NN*8;
  int n = rem>>3, hh = rem&7;
  const f16* featc = fc + (long)ti*NP*128;
  const float* al = (ti&1) ? alc1 : alc0;
  const float* ar_ = (ti&1) ? arc1 : arc0;
  float a=0.f, bsum=0.f;
  #pragma unroll
  for (int cc=0; cc<5; cc++){
    float v = (float)featc[(long)n*128 + hh*5 + cc];
    a += v*al[hh*5+cc];
    bsum += v*ar_[hh*5+cc];
  }
  el[idx]=a; er[idx]=bsum;
}

struct ClsArgs {
  const int* rp[3]; const int* cs[3];
  const float* el; const float* er;
  const f16* fc;
  const float* bc[2];
  float* pred;
};

__global__ __launch_bounds__(64) void k_cls_b(ClsArgs a){
  int b = blockIdx.x;
  int ti = b / NN, n = b - ti*NN;
  int g = ti<2 ? ti : 2;
  int ci = ti&1;
  const int* rowptr = a.rp[g];
  const int* colsrc = a.cs[g];
  const float* el = a.el + (long)ti*NN*8;
  const f16* featc = a.fc + (long)ti*NP*128;
  const float* bc = a.bc[ci];
  float* pred = a.pred + (long)ti*5*NN;
  int l = threadIdx.x;
  __shared__ float sm[MAXD*8];
  __shared__ int   scol[MAXD];
  __shared__ float inv[8];
  __shared__ float ern[8];
  __shared__ float lg[40];
  if (l<8) ern[l] = a.er[((long)ti*NN+n)*8+l];
  __syncthreads();
  int j0 = rowptr[n], deg = rowptr[n+1]-j0;
  {
    int h = l & 7;
    float dsum = 0.f;
    for (int jj = l>>3; jj < deg; jj += 8){
      int s = colsrc[j0+jj];
      float v = el[s*8+h] + ern[h];
      v = (v>0.f)? v : 0.2f*v;
      float ex = __expf(v);
      dsum += ex;
      if (jj < MAXD){
        sm[jj*8+h] = ex;
        if (h==0) scol[jj] = s;
      }
    }
    dsum += __shfl_xor(dsum, 8);
    dsum += __shfl_xor(dsum, 16);
    dsum += __shfl_xor(dsum, 32);
    if (l<8) inv[l] = 1.0f/dsum;
  }
  __syncthreads();
  if (l<40){
    int h = l/5;
    float ivh = inv[h];
    float acc = 0.f;
    for (int jj=0; jj<deg; jj++){
      int s; float ex;
      if (jj < MAXD){ s = scol[jj]; ex = sm[jj*8+h]; }
      else {
        s = colsrc[j0+jj];
        float v = el[s*8+h] + ern[h];
        v = (v>0.f)? v : 0.2f*v;
        ex = __expf(v);
      }
      acc += ex*ivh * (float)featc[(long)s*128 + l];
    }
    acc += (float)featc[(long)n*128 + 40 + l];
    acc += bc[l];
    lg[l] = acc;
  }
  __syncthreads();
  if (l<5){
    float p=0.f;
    #pragma unroll
    for (int h=0;h<8;h++) p += lg[h*5+l];
    pred[(long)n*5 + l] = p*0.125f;
  }
}

// ---------------- host orchestration ----------------
extern "C" void kernel_launch(void* const* d_in, const int* in_sizes, int n_in,
                              void* d_out, int out_size, void* d_ws, size_t ws_size,
                              hipStream_t stream){
  const int* srcs[3] = {(const int*)d_in[0], (const int*)d_in[2], (const int*)d_in[4]};
  const int* dsts[3] = {(const int*)d_in[1], (const int*)d_in[3], (const int*)d_in[5]};
  int E[3] = {in_sizes[0], in_sizes[2], in_sizes[4]};
  const float* X[3] = {(const float*)d_in[6], (const float*)d_in[7], (const float*)d_in[8]};
  const float* W0  = (const float*)d_in[9];
  const float* al0 = (const float*)d_in[10];
  const float* ar0 = (const float*)d_in[11];
  const float* b0  = (const float*)d_in[12];
  const float* W1  = (const float*)d_in[13];
  const float* al1 = (const float*)d_in[14];
  const float* ar1 = (const float*)d_in[15];
  const float* b1  = (const float*)d_in[16];
  const float* Wcv[2] = {(const float*)d_in[17], (const float*)d_in[22]};
  const float* alc[2] = {(const float*)d_in[18], (const float*)d_in[23]};
  const float* arc[2] = {(const float*)d_in[19], (const float*)d_in[24]};
  const float* bcv[2] = {(const float*)d_in[20], (const float*)d_in[25]};
  const float* rWv[2] = {(const float*)d_in[21], (const float*)d_in[26]};

  float* out = (float*)d_out;
  float* embOut[3] = {out+200000, out+200000+(long)NN*FF, out+200000+2L*NN*FF};

  char* w = (char*)d_ws;
  size_t off = 0;
  auto alloc = [&](size_t bytes)->void*{
    void* p = (void*)(w + off);
    off += (bytes + 255) & ~((size_t)255);
    return p;
  };
  f16* W0T = (f16*)alloc((size_t)FF*KK0*2);
  f16* W1T = (f16*)alloc((size_t)FF*FF*2);
  f16* WcT[2] = {(f16*)alloc(128*512*2), (f16*)alloc(128*512*2)};
  f16* feat0H[3], *h0H[3], *feat1H[3], *embH[3];
  for (int g=0;g<3;g++) feat0H[g] = (f16*)alloc((size_t)NP*FF*2);
  for (int g=0;g<3;g++) h0H[g]    = (f16*)alloc((size_t)NP*FF*2);
  for (int g=0;g<3;g++) feat1H[g] = (f16*)alloc((size_t)NP*FF*2);
  for (int g=0;g<3;g++) embH[g]   = (f16*)alloc((size_t)NP*FF*2);
  f16* featc = (f16*)alloc((size_t)4*NP*128*2);
  float* el_e = (float*)alloc((size_t)3*NN*8*4);
  float* er_e = (float*)alloc((size_t)3*NN*8*4);
  float* el_c = (float*)alloc((size_t)4*NN*8*4);
  float* er_c = (float*)alloc((size_t)4*NN*8*4);
  int* deg    = (int*)alloc((size_t)3*NN*4);
  int* cursor = (int*)alloc((size_t)3*NN*4);
  int* rowptr = (int*)alloc((size_t)3*(NN+1)*4);
  int* colsrc[3];
  for (int g=0;g<3;g++) colsrc[g] = (int*)alloc((size_t)E[g]*4);
  (void)ws_size; (void)n_in; (void)out_size;

  // ---- CSR (3 graphs, batched) ----
  int nb[3] = {(E[0]+255)/256, (E[1]+255)/256, (E[2]+255)/256};
  hipMemsetAsync(deg, 0, (size_t)3*NN*4, stream);
  k_count_b<<<nb[0]+nb[1]+nb[2], 256, 0, stream>>>(dsts[0], dsts[1], dsts[2],
      E[0], E[1], E[2], nb[0], nb[1], deg);
  k_scan_b<<<3, 1024, 0, stream>>>(deg, rowptr, cursor);
  k_fill_b<<<nb[0]+nb[1]+nb[2], 256, 0, stream>>>(srcs[0], dsts[0], srcs[1], dsts[1],
      srcs[2], dsts[2], E[0], E[1], E[2], nb[0], nb[1], cursor,
      colsrc[0], colsrc[1], colsrc[2]);

  // ---- weight prep ----
  k_transpose_t<<<dim3(FF/32, KK0/32), dim3(32,8), 0, stream>>>(W0, W0T, KK0, FF);
  k_transpose_t<<<dim3(FF/32, FF/32), dim3(32,8), 0, stream>>>(W1, W1T, FF, FF);
  k_pack_wc<<<(128*512+255)/256, 256, 0, stream>>>(Wcv[0], rWv[0], WcT[0]);
  k_pack_wc<<<(128*512+255)/256, 256, 0, stream>>>(Wcv[1], rWv[1], WcT[1]);

  const int* rp[3] = {rowptr, rowptr+(NN+1), rowptr+2*(NN+1)};

  // ---- layer 0: fused convert+GEMM+eler (wide tile), then aggregation ----
  k_gemmw<true><<<474, 512, 0, stream>>>(X[0], X[1], X[2],
      feat0H[0], feat0H[1], feat0H[2], W0T, al0, ar0, el_e, er_e);
  {
    AggArgs a;
    for (int g=0;g<3;g++){ a.rp[g]=rp[g]; a.cs[g]=colsrc[g]; a.feat[g]=feat0H[g];
                           a.outH[g]=h0H[g]; a.outF[g]=nullptr; }
    a.el = el_e; a.er = er_e; a.bias = b0;
    k_agg_b<<<3*NN, 256, 0, stream>>>(a);
  }

  // ---- layer 1: wide-tile GEMM+eler, then aggregation ----
  k_gemmw<false><<<474, 512, 0, stream>>>(h0H[0], h0H[1], h0H[2],
      feat1H[0], feat1H[1], feat1H[2], W1T, al1, ar1, el_e, er_e);
  {
    AggArgs a;
    for (int g=0;g<3;g++){ a.rp[g]=rp[g]; a.cs[g]=colsrc[g]; a.feat[g]=feat1H[g];
                           a.outH[g]=embH[g]; a.outF[g]=embOut[g]; }
    a.el = el_e; a.er = er_e; a.bias = b1;
    k_agg_b<<<3*NN, 256, 0, stream>>>(a);
  }

  // ---- classifiers (4 tasks batched): (g,c) = (0,0),(1,1),(2,0),(2,1) ----
  {
    GemmTasks p;
    const int tg[4] = {0,1,2,2};
    for (int i=0;i<4;i++){ p.A[i]=embH[tg[i]]; p.B[i]=WcT[i&1]; p.C[i]=featc + (long)i*NP*128; }
    k_gemmb<<<4*158, 256, 0, stream>>>(p, 158, 1, 128, FF);
  }
  k_elerc_b<<<(4*NN*8+255)/256, 256, 0, stream>>>(featc, alc[0], arc[0], alc[1], arc[1], el_c, er_c);
  {
    ClsArgs a;
    for (int g=0;g<3;g++){ a.rp[g]=rp[g]; a.cs[g]=colsrc[g]; }
    a.el = el_c; a.er = er_c; a.fc = featc;
    a.bc[0] = bcv[0]; a.bc[1] = bcv[1];
    a.pred = out;
    k_cls_b<<<4*NN, 64, 0, stream>>>(a);
  }
}

// Round 7
// 538.530 us; speedup vs baseline: 2.3067x; 1.1427x over previous
//
#include <hip/hip_runtime.h>
#include <stdint.h>

typedef _Float16 f16;
typedef _Float16 f16x2 __attribute__((ext_vector_type(2)));
typedef _Float16 f16x8 __attribute__((ext_vector_type(8)));
typedef float f32x4 __attribute__((ext_vector_type(4)));

#define AS1 __attribute__((address_space(1)))
#define AS3 __attribute__((address_space(3)))

#define NN 10000
#define NP 10112
#define KK0 4096
#define FF 512

// ---------------- CSR build (batched over 3 graphs) ----------------
__global__ void k_count_b(const int* __restrict__ d0, const int* __restrict__ d1,
                          const int* __restrict__ d2, int E0, int E1, int E2,
                          int nb0, int nb1, int* __restrict__ deg){
  int b = blockIdx.x;
  const int* d; int Eg, base, lb;
  if (b < nb0){ d=d0; Eg=E0; base=0; lb=b; }
  else if (b < nb0+nb1){ d=d1; Eg=E1; base=NN; lb=b-nb0; }
  else { d=d2; Eg=E2; base=2*NN; lb=b-nb0-nb1; }
  int i = lb*256 + threadIdx.x;
  if (i < Eg) atomicAdd(&deg[base + d[i]], 1);
}

__global__ __launch_bounds__(1024) void k_scan_b(const int* __restrict__ deg_all,
    int* __restrict__ rowptr_all, int* __restrict__ cursor_all){
  int g = blockIdx.x;
  const int* deg = deg_all + g*NN;
  int* rowptr = rowptr_all + g*(NN+1);
  int* cursor = cursor_all + g*NN;
  __shared__ int ps[1024];
  int t = threadIdx.x;
  const int CH = 16;
  int i0 = t*CH;
  int sum = 0;
  for (int k=0;k<CH;k++){ int i=i0+k; if (i<NN) sum += deg[i]; }
  ps[t]=sum; __syncthreads();
  for (int off=1; off<1024; off<<=1){
    int v = (t>=off)? ps[t-off] : 0;
    __syncthreads();
    ps[t] += v;
    __syncthreads();
  }
  int run = ps[t]-sum;
  for (int k=0;k<CH;k++){
    int i=i0+k;
    if (i<=NN) rowptr[i]=run;
    if (i<NN){ cursor[i]=run; run += deg[i]; }
  }
}

__global__ void k_fill_b(const int* __restrict__ s0, const int* __restrict__ d0,
                         const int* __restrict__ s1, const int* __restrict__ d1,
                         const int* __restrict__ s2, const int* __restrict__ d2,
                         int E0, int E1, int E2, int nb0, int nb1,
                         int* __restrict__ cursor_all,
                         int* __restrict__ c0, int* __restrict__ c1, int* __restrict__ c2){
  int b = blockIdx.x;
  const int *s, *d; int Eg, lb; int* cur; int* col;
  if (b < nb0){ s=s0; d=d0; Eg=E0; lb=b; cur=cursor_all; col=c0; }
  else if (b < nb0+nb1){ s=s1; d=d1; Eg=E1; lb=b-nb0; cur=cursor_all+NN; col=c1; }
  else { s=s2; d=d2; Eg=E2; lb=b-nb0-nb1; cur=cursor_all+2*NN; col=c2; }
  int i = lb*256 + threadIdx.x;
  if (i >= Eg) return;
  int slot = atomicAdd(&cur[d[i]], 1);
  col[slot] = s[i];
}

// ---------------- weight prep ----------------
__global__ void k_transpose_t(const float* __restrict__ W, f16* __restrict__ WT,
                              int K, int Nc){
  __shared__ float tile[32][33];
  int n0 = blockIdx.x*32, k0 = blockIdx.y*32;
  int tx = threadIdx.x, ty = threadIdx.y;
  #pragma unroll
  for (int i=0;i<32;i+=8)
    tile[ty+i][tx] = W[(long)(k0+ty+i)*Nc + n0+tx];
  __syncthreads();
  #pragma unroll
  for (int i=0;i<32;i+=8)
    WT[(long)(n0+ty+i)*K + k0+tx] = (f16)tile[tx][ty+i];
}

__global__ void k_pack_wc(const float* __restrict__ Wc, const float* __restrict__ rW,
                          f16* __restrict__ WT){
  int idx = blockIdx.x*256 + threadIdx.x;
  if (idx >= 128*512) return;
  int n = idx >> 9; int k = idx & 511;
  float v = 0.f;
  if (n < 40) v = Wc[k*40 + n];
  else if (n < 80) v = rW[k*40 + (n-40)];
  WT[idx] = (f16)v;
}

// ---------------- wide-tile GEMM: C (Np x 512) = A * B^T, 3 tasks in one grid
// BM=128, BN=512 (A read ONCE; B L2-traffic halved vs BM=64), 512 threads = 8
// waves, wave = 128x64 sub-tile = one head. LDS 2 x (A 16KB + B 64KB) = 160KB.
// CVT=true: A fp32 (reg-staged convert, counted-vmcnt pipeline), K=4096.
// CVT=false: A f16 via global_load_lds, K=512.
template<bool CVT>
__global__ __launch_bounds__(512,1) void k_gemmw(
    const void* __restrict__ A0v, const void* __restrict__ A1v, const void* __restrict__ A2v,
    f16* __restrict__ C0, f16* __restrict__ C1, f16* __restrict__ C2,
    const f16* __restrict__ B,
    const float* __restrict__ alp, const float* __restrict__ arp,
    float* __restrict__ elp, float* __restrict__ erp)
{
  constexpr int K = CVT ? KK0 : FF;
  constexpr int nt = K >> 6;
  __shared__ f16 lds[2][40960];   // per buf: A 128x64 (16KB) + B 512x64 (64KB)

  const int nwg = gridDim.x;               // 237
  const int qd = nwg>>3, rd = nwg&7;
  const int xcd = blockIdx.x & 7, bx = blockIdx.x >> 3;
  const int wid = (xcd < rd ? xcd*(qd+1) : rd*(qd+1) + (xcd-rd)*qd) + bx;
  const int task = wid / 79;
  const int tr = wid - task*79;

  f16* C = task==0?C0:(task==1?C1:C2);

  const int t = threadIdx.x;
  const int wave = t >> 6, lane = t & 63;
  const int slot = (lane&7) ^ (lane>>3);
  const int arow0 = t >> 3;                 // 0..63 (also covers arow0+64)
  const int ak8 = t & 7;

  // B staging: 8 x global_load_lds per thread (512 rows x 64 k)
  #define GLDSB(kt, buf) { \
    int ko = (kt)*64; \
    _Pragma("unroll") \
    for (int i=0;i<8;i++){ \
      int br = i*64 + wave*8 + (lane>>3); \
      __builtin_amdgcn_global_load_lds((const AS1 void*)(B + (long)br*K + ko + slot*8), \
          (AS3 void*)(&lds[buf][8192 + i*4096 + wave*512]), 16, 0, 0); \
    } }

  // fragment addresses (byte offsets into lds[buf])
  int abyte[2][8], bbyte[2][4];
  #pragma unroll
  for (int ks=0;ks<2;ks++){
    #pragma unroll
    for (int m=0;m<8;m++){
      int row = m*16 + (lane&15);
      abyte[ks][m] = row*128 + (((ks*4 + (lane>>4))*16) ^ ((row&7)<<4));
    }
    #pragma unroll
    for (int n=0;n<4;n++){
      int brow = wave*64 + n*16 + (lane&15);
      bbyte[ks][n] = 16384 + brow*128 + (((ks*4 + (lane>>4))*16) ^ ((brow&7)<<4));
    }
  }

  f32x4 zero4 = {0.f,0.f,0.f,0.f};
  f32x4 acc[8][4];
  #pragma unroll
  for (int m=0;m<8;m++)
    #pragma unroll
    for (int n=0;n<4;n++) acc[m][n] = zero4;

  #define MFMA_TILE(buf) { \
    const char* Ls = (const char*)&lds[buf][0]; \
    _Pragma("unroll") \
    for (int ks=0;ks<2;ks++){ \
      f16x8 bf[4]; \
      _Pragma("unroll") \
      for (int n=0;n<4;n++) bf[n] = *(const f16x8*)(Ls + bbyte[ks][n]); \
      _Pragma("unroll") \
      for (int m=0;m<8;m++){ \
        f16x8 af = *(const f16x8*)(Ls + abyte[ks][m]); \
        _Pragma("unroll") \
        for (int n=0;n<4;n++) \
          acc[m][n] = __builtin_amdgcn_mfma_f32_16x16x32_f16(af, bf[n], acc[m][n], 0, 0, 0); \
      } \
    } }

  int cur = 0;
  if constexpr (CVT){
    // ---- fp32 A, reg-staged conversion, counted-vmcnt pipeline ----
    const float* Af = task==0?(const float*)A0v:(task==1?(const float*)A1v:(const float*)A2v);
    const float* gA[2];
    bool okA[2];
    #pragma unroll
    for (int s=0;s<2;s++){
      int grow = tr*128 + arow0 + s*64;
      okA[s] = grow < NN;
      gA[s] = Af + (long)(okA[s] ? grow : 0)*KK0 + ak8*8;
    }
    f32x4 arE[2][2];   // [row-slot][half] -- static indices ONLY

    #define LOADA(kt) { \
      _Pragma("unroll") \
      for (int s=0;s<2;s++){ \
        arE[s][0] = *(const f32x4*)(gA[s] + (kt)*64); \
        arE[s][1] = *(const f32x4*)(gA[s] + (kt)*64 + 4); \
      } }
    #define WRITEA(buf) { \
      _Pragma("unroll") \
      for (int s=0;s<2;s++){ \
        int row = arow0 + s*64; \
        f16x8 v; \
        _Pragma("unroll") \
        for (int j=0;j<4;j++){ \
          v[j]   = okA[s] ? (f16)arE[s][0][j] : (f16)0.f; \
          v[4+j] = okA[s] ? (f16)arE[s][1][j] : (f16)0.f; \
        } \
        *(f16x8*)(&lds[buf][row*64 + ((ak8 ^ (arow0&7))*8)]) = v; \
      } }

    LOADA(0);                      // vm: L_A(0)=4
    __builtin_amdgcn_sched_barrier(0);
    GLDSB(0, 0);                   // +8
    __builtin_amdgcn_sched_barrier(0);
    WRITEA(0);                     // compiler waits L_A(0) -> vmcnt(8)
    __builtin_amdgcn_sched_barrier(0);
    LOADA(1);                      // +4
    __builtin_amdgcn_sched_barrier(0);
    asm volatile("s_waitcnt vmcnt(4) lgkmcnt(0)" ::: "memory");  // B staged; L_A(1) flying
    __builtin_amdgcn_s_barrier();

    for (int kt=0; kt<nt; kt++){
      if (kt+1 < nt){
        WRITEA(cur^1);             // waits L_A(kt+1) (only outstanding)
        __builtin_amdgcn_sched_barrier(0);
        GLDSB(kt+1, cur^1);        // +8
        __builtin_amdgcn_sched_barrier(0);
      }
      if (kt+2 < nt){
        LOADA(kt+2);               // +4, after B-stage in queue order
        __builtin_amdgcn_sched_barrier(0);
      }
      MFMA_TILE(cur);
      if (kt+1 < nt){
        __builtin_amdgcn_sched_barrier(0);
        if (kt+2 < nt)
          asm volatile("s_waitcnt vmcnt(4) lgkmcnt(0)" ::: "memory");
        else
          asm volatile("s_waitcnt vmcnt(0) lgkmcnt(0)" ::: "memory");
        __builtin_amdgcn_s_barrier();
      }
      cur ^= 1;
    }
    #undef LOADA
    #undef WRITEA
  } else {
    // ---- f16 A via global_load_lds, simple double-buffered loop ----
    const f16* Ah = task==0?(const f16*)A0v:(task==1?(const f16*)A1v:(const f16*)A2v);
    const f16* Ab = Ah + (long)tr*128*K;
    const int r8 = lane>>3;   // row-within-wave-group; row&7 == r8

    #define GLDSA(kt, buf) { \
      _Pragma("unroll") \
      for (int s=0;s<2;s++){ \
        int arow = wave*8 + r8 + s*64; \
        __builtin_amdgcn_global_load_lds((const AS1 void*)(Ab + (long)arow*K + (kt)*64 + slot*8), \
            (AS3 void*)(&lds[buf][s*4096 + wave*512]), 16, 0, 0); \
      } }

    GLDSA(0, 0);
    GLDSB(0, 0);
    __syncthreads();
    for (int kt=0; kt<nt; kt++){
      if (kt+1 < nt){
        GLDSA(kt+1, cur^1);
        GLDSB(kt+1, cur^1);
      }
      MFMA_TILE(cur);
      __syncthreads();
      cur ^= 1;
    }
    #undef GLDSA
  }
  #undef GLDSB
  #undef MFMA_TILE

  // ---- C write: row = m*16 + (lane>>4)*4 + q, col = wave*64 + n*16 + (lane&15)
  #pragma unroll
  for (int m=0;m<8;m++){
    int row0 = tr*128 + m*16 + ((lane>>4)<<2);
    #pragma unroll
    for (int n=0;n<4;n++){
      int col = wave*64 + n*16 + (lane&15);
      #pragma unroll
      for (int q2=0;q2<4;q2++)
        C[(long)(row0+q2)*FF + col] = (f16)acc[m][n][q2];
    }
  }

  // ---- el/er epilogue: wave == head
  {
    const int head = wave;
    const float* alh = alp + head*64;
    const float* arh = arp + head*64;
    float alv[4], arv[4];
    #pragma unroll
    for (int n=0;n<4;n++){ int d = n*16 + (lane&15); alv[n]=alh[d]; arv[n]=arh[d]; }
    float* elo = elp + (long)task*NN*8;
    float* ero = erp + (long)task*NN*8;
    #pragma unroll
    for (int m=0;m<8;m++){
      float e0,e1,e2,e3,r0,r1,r2,r3;
      #pragma unroll
      for (int qq=0;qq<4;qq++){
        float e=0.f, rr=0.f;
        #pragma unroll
        for (int n=0;n<4;n++){ e += acc[m][n][qq]*alv[n]; rr += acc[m][n][qq]*arv[n]; }
        #pragma unroll
        for (int off=1; off<16; off<<=1){ e += __shfl_xor(e, off); rr += __shfl_xor(rr, off); }
        if (qq==0){e0=e;r0=rr;} else if (qq==1){e1=e;r1=rr;} else if (qq==2){e2=e;r2=rr;} else {e3=e;r3=rr;}
      }
      int qq = lane&15;
      if (qq < 4){
        int node = tr*128 + m*16 + ((lane>>4)<<2) + qq;
        if (node < NN){
          float ev = qq==0?e0:(qq==1?e1:(qq==2?e2:e3));
          float rv = qq==0?r0:(qq==1?r1:(qq==2?r2:r3));
          long o = (long)node*8 + head;
          elo[o] = ev;
          ero[o] = rv;
        }
      }
    }
  }
}

// ---------------- classifier GEMM (4 tasks, Nc=128, K=512) ----------------
struct GemmTasks { const f16* A[4]; const f16* B[4]; f16* C[4]; };

__global__ __launch_bounds__(256,3) void k_gemmb(GemmTasks p, int ntpb, int ntn,
                                                 int Nc, int K){
  __shared__ f16 lds[2][12288];
  const int bid = blockIdx.x;
  const int task = bid / ntpb;
  const int orig = bid - task*ntpb;
  const int q = ntpb >> 3, r = ntpb & 7;
  const int xcd = orig & 7, bx = orig >> 3;
  const int wid = (xcd < r ? xcd*(q+1) : r*(q+1) + (xcd-r)*q) + bx;
  const int tr = wid / ntn, tc = wid - tr*ntn;

  const f16* A = p.A[task];
  const f16* B = p.B[task];
  f16* C = p.C[task];

  const int t = threadIdx.x;
  const int wave = t >> 6, lane = t & 63;
  const int wr = wave >> 1, wc = wave & 1;

  const f16* Ab = A + (long)tr*64*K;
  const f16* Bb = B + (long)tc*128*K;

  const int slot = (lane&7) ^ (lane>>3);
  const int rbase = wave*8 + (lane>>3);

  f32x4 zero4 = {0.f,0.f,0.f,0.f};
  f32x4 acc[2][4];
  #pragma unroll
  for (int m=0;m<2;m++)
    #pragma unroll
    for (int n=0;n<4;n++) acc[m][n] = zero4;

  int abyte[2][2], bbyte[2][4];
  #pragma unroll
  for (int ks=0;ks<2;ks++){
    #pragma unroll
    for (int m=0;m<2;m++){
      int row = wr*32 + m*16 + (lane&15);
      abyte[ks][m] = row*128 + (((ks*4 + (lane>>4))*16) ^ ((row&7)<<4));
    }
    #pragma unroll
    for (int n=0;n<4;n++){
      int brow = wc*64 + n*16 + (lane&15);
      bbyte[ks][n] = 8192 + brow*128 + (((ks*4 + (lane>>4))*16) ^ ((brow&7)<<4));
    }
  }

  const int nt = K >> 6;
  int cur = 0;

  #pragma unroll
  for (int i=0;i<2;i++)
    __builtin_amdgcn_global_load_lds((const AS1 void*)(Ab + (i*32+rbase)*K + slot*8),
        (AS3 void*)(&lds[0][i*2048 + wave*512]), 16, 0, 0);
  #pragma unroll
  for (int i=0;i<4;i++)
    __builtin_amdgcn_global_load_lds((const AS1 void*)(Bb + (i*32+rbase)*K + slot*8),
        (AS3 void*)(&lds[0][4096 + i*2048 + wave*512]), 16, 0, 0);
  __syncthreads();

  for (int kt=0; kt<nt; kt++){
    if (kt+1 < nt){
      int ko = (kt+1)<<6;
      #pragma unroll
      for (int i=0;i<2;i++)
        __builtin_amdgcn_global_load_lds((const AS1 void*)(Ab + ko + (i*32+rbase)*K + slot*8),
            (AS3 void*)(&lds[cur^1][i*2048 + wave*512]), 16, 0, 0);
      #pragma unroll
      for (int i=0;i<4;i++)
        __builtin_amdgcn_global_load_lds((const AS1 void*)(Bb + ko + (i*32+rbase)*K + slot*8),
            (AS3 void*)(&lds[cur^1][4096 + i*2048 + wave*512]), 16, 0, 0);
    }
    const char* Ls = (const char*)&lds[cur][0];
    #pragma unroll
    for (int ks=0;ks<2;ks++){
      f16x8 af[2], bf[4];
      #pragma unroll
      for (int m=0;m<2;m++) af[m] = *(const f16x8*)(Ls + abyte[ks][m]);
      #pragma unroll
      for (int n=0;n<4;n++) bf[n] = *(const f16x8*)(Ls + bbyte[ks][n]);
      #pragma unroll
      for (int m=0;m<2;m++)
        #pragma unroll
        for (int n=0;n<4;n++)
          acc[m][n] = __builtin_amdgcn_mfma_f32_16x16x32_f16(af[m], bf[n], acc[m][n], 0, 0, 0);
    }
    __syncthreads();
    cur ^= 1;
  }

  #pragma unroll
  for (int m=0;m<2;m++){
    int row0 = tr*64 + wr*32 + m*16 + ((lane>>4)<<2);
    #pragma unroll
    for (int n=0;n<4;n++){
      int col = tc*128 + wc*64 + n*16 + (lane&15);
      #pragma unroll
      for (int q2=0;q2<4;q2++)
        C[(long)(row0+q2)*Nc + col] = (f16)acc[m][n][q2];
    }
  }
}

// ---------------- attention aggregation (batched over graphs) ----------------
#define MAXD 128

struct AggArgs {
  const int* rp[3]; const int* cs[3];
  const float* el; const float* er;
  const f16* feat[3];
  const float* bias;
  f16* outH[3];
  float* outF[3];
};

__global__ __launch_bounds__(256) void k_agg_b(AggArgs a){
  int b = blockIdx.x;
  int g = b / NN, n = b - g*NN;
  const int* rowptr = a.rp[g];
  const int* colsrc = a.cs[g];
  const float* el = a.el + (long)g*NN*8;
  const f16* featH = a.feat[g];
  int t = threadIdx.x;
  __shared__ float sm[MAXD*8];
  __shared__ int   scol[MAXD];
  __shared__ float red[256];
  __shared__ float inv[8];
  __shared__ float ern[8];
  if (t < 8) ern[t] = a.er[((long)g*NN+n)*8+t];
  __syncthreads();
  int j0 = rowptr[n], deg = rowptr[n+1]-j0;
  {
    int h = t & 7;
    float dsum = 0.f;
    for (int jj = t>>3; jj < deg; jj += 32){
      int s = colsrc[j0+jj];
      float v = el[s*8+h] + ern[h];
      v = (v>0.f)? v : 0.2f*v;
      float ex = __expf(v);
      dsum += ex;
      if (jj < MAXD){
        sm[jj*8+h] = ex;
        if (h==0) scol[jj] = s;
      }
    }
    red[t] = dsum; __syncthreads();
    if (t<128) red[t] += red[t+128]; __syncthreads();
    if (t<64)  red[t] += red[t+64];  __syncthreads();
    if (t<32)  red[t] += red[t+32];  __syncthreads();
    if (t<16)  red[t] += red[t+16];  __syncthreads();
    if (t<8)   inv[t] = 1.0f / (red[t] + red[t+8]);
    __syncthreads();
  }
  int h = t >> 5;
  int c = t*2;
  float a0=0.f, a1=0.f;
  float ivh = inv[h];
  for (int jj=0; jj<deg; jj++){
    int s; float ex;
    if (jj < MAXD){ s = scol[jj]; ex = sm[jj*8+h]; }
    else {
      s = colsrc[j0+jj];
      float v = el[s*8+h] + ern[h];
      v = (v>0.f)? v : 0.2f*v;
      ex = __expf(v);
    }
    float alpha = ex * ivh;
    f16x2 f = *(const f16x2*)(featH + (long)s*FF + c);
    a0 += alpha*(float)f[0];
    a1 += alpha*(float)f[1];
  }
  a0 += a.bias[c]; a1 += a.bias[c+1];
  a0 = (a0>0.f)? a0 : __expf(a0)-1.f;
  a1 = (a1>0.f)? a1 : __expf(a1)-1.f;
  f16x2 o; o[0]=(f16)a0; o[1]=(f16)a1;
  *(f16x2*)(a.outH[g] + (long)n*FF + c) = o;
  float* oF = a.outF[g];
  if (oF){
    oF[(long)n*FF + c]     = a0;
    oF[(long)n*FF + c + 1] = a1;
  }
}

// classifier el/er over 4 tasks
__global__ void k_elerc_b(const f16* __restrict__ fc,
    const float* __restrict__ alc0, const float* __restrict__ arc0,
    const float* __restrict__ alc1, const float* __restrict__ arc1,
    float* __restrict__ el, float* __restrict__ er){
  int idx = blockIdx.x*256 + threadIdx.x;
  if (idx >= 4*NN*8) return;
  int ti = idx / (NN*8);
  int rem = idx - ti*NN*8;
  int n = rem>>3, hh = rem&7;
  const f16* featc = fc + (long)ti*NP*128;
  const float* al = (ti&1) ? alc1 : alc0;
  const float* ar_ = (ti&1) ? arc1 : arc0;
  float a=0.f, bsum=0.f;
  #pragma unroll
  for (int cc=0; cc<5; cc++){
    float v = (float)featc[(long)n*128 + hh*5 + cc];
    a += v*al[hh*5+cc];
    bsum += v*ar_[hh*5+cc];
  }
  el[idx]=a; er[idx]=bsum;
}

struct ClsArgs {
  const int* rp[3]; const int* cs[3];
  const float* el; const float* er;
  const f16* fc;
  const float* bc[2];
  float* pred;
};

__global__ __launch_bounds__(64) void k_cls_b(ClsArgs a){
  int b = blockIdx.x;
  int ti = b / NN, n = b - ti*NN;
  int g = ti<2 ? ti : 2;
  int ci = ti&1;
  const int* rowptr = a.rp[g];
  const int* colsrc = a.cs[g];
  const float* el = a.el + (long)ti*NN*8;
  const f16* featc = a.fc + (long)ti*NP*128;
  const float* bc = a.bc[ci];
  float* pred = a.pred + (long)ti*5*NN;
  int l = threadIdx.x;
  __shared__ float sm[MAXD*8];
  __shared__ int   scol[MAXD];
  __shared__ float inv[8];
  __shared__ float ern[8];
  __shared__ float lg[40];
  if (l<8) ern[l] = a.er[((long)ti*NN+n)*8+l];
  __syncthreads();
  int j0 = rowptr[n], deg = rowptr[n+1]-j0;
  {
    int h = l & 7;
    float dsum = 0.f;
    for (int jj = l>>3; jj < deg; jj += 8){
      int s = colsrc[j0+jj];
      float v = el[s*8+h] + ern[h];
      v = (v>0.f)? v : 0.2f*v;
      float ex = __expf(v);
      dsum += ex;
      if (jj < MAXD){
        sm[jj*8+h] = ex;
        if (h==0) scol[jj] = s;
      }
    }
    dsum += __shfl_xor(dsum, 8);
    dsum += __shfl_xor(dsum, 16);
    dsum += __shfl_xor(dsum, 32);
    if (l<8) inv[l] = 1.0f/dsum;
  }
  __syncthreads();
  if (l<40){
    int h = l/5;
    float ivh = inv[h];
    float acc = 0.f;
    for (int jj=0; jj<deg; jj++){
      int s; float ex;
      if (jj < MAXD){ s = scol[jj]; ex = sm[jj*8+h]; }
      else {
        s = colsrc[j0+jj];
        float v = el[s*8+h] + ern[h];
        v = (v>0.f)? v : 0.2f*v;
        ex = __expf(v);
      }
      acc += ex*ivh * (float)featc[(long)s*128 + l];
    }
    acc += (float)featc[(long)n*128 + 40 + l];
    acc += bc[l];
    lg[l] = acc;
  }
  __syncthreads();
  if (l<5){
    float p=0.f;
    #pragma unroll
    for (int h=0;h<8;h++) p += lg[h*5+l];
    pred[(long)n*5 + l] = p*0.125f;
  }
}

// ---------------- host orchestration ----------------
extern "C" void kernel_launch(void* const* d_in, const int* in_sizes, int n_in,
                              void* d_out, int out_size, void* d_ws, size_t ws_size,
                              hipStream_t stream){
  const int* srcs[3] = {(const int*)d_in[0], (const int*)d_in[2], (const int*)d_in[4]};
  const int* dsts[3] = {(const int*)d_in[1], (const int*)d_in[3], (const int*)d_in[5]};
  int E[3] = {in_sizes[0], in_sizes[2], in_sizes[4]};
  const float* X[3] = {(const float*)d_in[6], (const float*)d_in[7], (const float*)d_in[8]};
  const float* W0  = (const float*)d_in[9];
  const float* al0 = (const float*)d_in[10];
  const float* ar0 = (const float*)d_in[11];
  const float* b0  = (const float*)d_in[12];
  const float* W1  = (const float*)d_in[13];
  const float* al1 = (const float*)d_in[14];
  const float* ar1 = (const float*)d_in[15];
  const float* b1  = (const float*)d_in[16];
  const float* Wcv[2] = {(const float*)d_in[17], (const float*)d_in[22]};
  const float* alc[2] = {(const float*)d_in[18], (const float*)d_in[23]};
  const float* arc[2] = {(const float*)d_in[19], (const float*)d_in[24]};
  const float* bcv[2] = {(const float*)d_in[20], (const float*)d_in[25]};
  const float* rWv[2] = {(const float*)d_in[21], (const float*)d_in[26]};

  float* out = (float*)d_out;
  float* embOut[3] = {out+200000, out+200000+(long)NN*FF, out+200000+2L*NN*FF};

  char* w = (char*)d_ws;
  size_t off = 0;
  auto alloc = [&](size_t bytes)->void*{
    void* p = (void*)(w + off);
    off += (bytes + 255) & ~((size_t)255);
    return p;
  };
  f16* W0T = (f16*)alloc((size_t)FF*KK0*2);
  f16* W1T = (f16*)alloc((size_t)FF*FF*2);
  f16* WcT[2] = {(f16*)alloc(128*512*2), (f16*)alloc(128*512*2)};
  f16* feat0H[3], *h0H[3], *feat1H[3], *embH[3];
  for (int g=0;g<3;g++) feat0H[g] = (f16*)alloc((size_t)NP*FF*2);
  for (int g=0;g<3;g++) h0H[g]    = (f16*)alloc((size_t)NP*FF*2);
  for (int g=0;g<3;g++) feat1H[g] = (f16*)alloc((size_t)NP*FF*2);
  for (int g=0;g<3;g++) embH[g]   = (f16*)alloc((size_t)NP*FF*2);
  f16* featc = (f16*)alloc((size_t)4*NP*128*2);
  float* el_e = (float*)alloc((size_t)3*NN*8*4);
  float* er_e = (float*)alloc((size_t)3*NN*8*4);
  float* el_c = (float*)alloc((size_t)4*NN*8*4);
  float* er_c = (float*)alloc((size_t)4*NN*8*4);
  int* deg    = (int*)alloc((size_t)3*NN*4);
  int* cursor = (int*)alloc((size_t)3*NN*4);
  int* rowptr = (int*)alloc((size_t)3*(NN+1)*4);
  int* colsrc[3];
  for (int g=0;g<3;g++) colsrc[g] = (int*)alloc((size_t)E[g]*4);
  (void)ws_size; (void)n_in; (void)out_size;

  // ---- CSR (3 graphs, batched) ----
  int nb[3] = {(E[0]+255)/256, (E[1]+255)/256, (E[2]+255)/256};
  hipMemsetAsync(deg, 0, (size_t)3*NN*4, stream);
  k_count_b<<<nb[0]+nb[1]+nb[2], 256, 0, stream>>>(dsts[0], dsts[1], dsts[2],
      E[0], E[1], E[2], nb[0], nb[1], deg);
  k_scan_b<<<3, 1024, 0, stream>>>(deg, rowptr, cursor);
  k_fill_b<<<nb[0]+nb[1]+nb[2], 256, 0, stream>>>(srcs[0], dsts[0], srcs[1], dsts[1],
      srcs[2], dsts[2], E[0], E[1], E[2], nb[0], nb[1], cursor,
      colsrc[0], colsrc[1], colsrc[2]);

  // ---- weight prep ----
  k_transpose_t<<<dim3(FF/32, KK0/32), dim3(32,8), 0, stream>>>(W0, W0T, KK0, FF);
  k_transpose_t<<<dim3(FF/32, FF/32), dim3(32,8), 0, stream>>>(W1, W1T, FF, FF);
  k_pack_wc<<<(128*512+255)/256, 256, 0, stream>>>(Wcv[0], rWv[0], WcT[0]);
  k_pack_wc<<<(128*512+255)/256, 256, 0, stream>>>(Wcv[1], rWv[1], WcT[1]);

  const int* rp[3] = {rowptr, rowptr+(NN+1), rowptr+2*(NN+1)};

  // ---- layer 0: fused convert+GEMM+eler (wide tile), then aggregation ----
  k_gemmw<true><<<237, 512, 0, stream>>>(X[0], X[1], X[2],
      feat0H[0], feat0H[1], feat0H[2], W0T, al0, ar0, el_e, er_e);
  {
    AggArgs a;
    for (int g=0;g<3;g++){ a.rp[g]=rp[g]; a.cs[g]=colsrc[g]; a.feat[g]=feat0H[g];
                           a.outH[g]=h0H[g]; a.outF[g]=nullptr; }
    a.el = el_e; a.er = er_e; a.bias = b0;
    k_agg_b<<<3*NN, 256, 0, stream>>>(a);
  }

  // ---- layer 1: wide-tile GEMM+eler, then aggregation ----
  k_gemmw<false><<<237, 512, 0, stream>>>(h0H[0], h0H[1], h0H[2],
      feat1H[0], feat1H[1], feat1H[2], W1T, al1, ar1, el_e, er_e);
  {
    AggArgs a;
    for (int g=0;g<3;g++){ a.rp[g]=rp[g]; a.cs[g]=colsrc[g]; a.feat[g]=feat1H[g];
                           a.outH[g]=embH[g]; a.outF[g]=embOut[g]; }
    a.el = el_e; a.er = er_e; a.bias = b1;
    k_agg_b<<<3*NN, 256, 0, stream>>>(a);
  }

  // ---- classifiers (4 tasks batched): (g,c) = (0,0),(1,1),(2,0),(2,1) ----
  {
    GemmTasks p;
    const int tg[4] = {0,1,2,2};
    for (int i=0;i<4;i++){ p.A[i]=embH[tg[i]]; p.B[i]=WcT[i&1]; p.C[i]=featc + (long)i*NP*128; }
    k_gemmb<<<4*158, 256, 0, stream>>>(p, 158, 1, 128, FF);
  }
  k_elerc_b<<<(4*NN*8+255)/256, 256, 0, stream>>>(featc, alc[0], arc[0], alc[1], arc[1], el_c, er_c);
  {
    ClsArgs a;
    for (int g=0;g<3;g++){ a.rp[g]=rp[g]; a.cs[g]=colsrc[g]; }
    a.el = el_c; a.er = er_c; a.fc = featc;
    a.bc[0] = bcv[0]; a.bc[1] = bcv[1];
    a.pred = out;
    k_cls_b<<<4*NN, 64, 0, stream>>>(a);
  }
}

// Round 8
// 512.157 us; speedup vs baseline: 2.4255x; 1.0515x over previous
//
#include <hip/hip_runtime.h>
#include <stdint.h>

typedef _Float16 f16;
typedef _Float16 f16x2 __attribute__((ext_vector_type(2)));
typedef _Float16 f16x8 __attribute__((ext_vector_type(8)));
typedef float f32x4 __attribute__((ext_vector_type(4)));

#define AS1 __attribute__((address_space(1)))
#define AS3 __attribute__((address_space(3)))

#define NN 10000
#define NP 10112
#define KK0 4096
#define FF 512

// ---------------- CSR build (batched over 3 graphs) ----------------
__global__ void k_count_b(const int* __restrict__ d0, const int* __restrict__ d1,
                          const int* __restrict__ d2, int E0, int E1, int E2,
                          int nb0, int nb1, int* __restrict__ deg){
  int b = blockIdx.x;
  const int* d; int Eg, base, lb;
  if (b < nb0){ d=d0; Eg=E0; base=0; lb=b; }
  else if (b < nb0+nb1){ d=d1; Eg=E1; base=NN; lb=b-nb0; }
  else { d=d2; Eg=E2; base=2*NN; lb=b-nb0-nb1; }
  int i = lb*256 + threadIdx.x;
  if (i < Eg) atomicAdd(&deg[base + d[i]], 1);
}

__global__ __launch_bounds__(1024) void k_scan_b(const int* __restrict__ deg_all,
    int* __restrict__ rowptr_all, int* __restrict__ cursor_all){
  int g = blockIdx.x;
  const int* deg = deg_all + g*NN;
  int* rowptr = rowptr_all + g*(NN+1);
  int* cursor = cursor_all + g*NN;
  __shared__ int ps[1024];
  int t = threadIdx.x;
  const int CH = 16;
  int i0 = t*CH;
  int sum = 0;
  for (int k=0;k<CH;k++){ int i=i0+k; if (i<NN) sum += deg[i]; }
  ps[t]=sum; __syncthreads();
  for (int off=1; off<1024; off<<=1){
    int v = (t>=off)? ps[t-off] : 0;
    __syncthreads();
    ps[t] += v;
    __syncthreads();
  }
  int run = ps[t]-sum;
  for (int k=0;k<CH;k++){
    int i=i0+k;
    if (i<=NN) rowptr[i]=run;
    if (i<NN){ cursor[i]=run; run += deg[i]; }
  }
}

__global__ void k_fill_b(const int* __restrict__ s0, const int* __restrict__ d0,
                         const int* __restrict__ s1, const int* __restrict__ d1,
                         const int* __restrict__ s2, const int* __restrict__ d2,
                         int E0, int E1, int E2, int nb0, int nb1,
                         int* __restrict__ cursor_all,
                         int* __restrict__ c0, int* __restrict__ c1, int* __restrict__ c2){
  int b = blockIdx.x;
  const int *s, *d; int Eg, lb; int* cur; int* col;
  if (b < nb0){ s=s0; d=d0; Eg=E0; lb=b; cur=cursor_all; col=c0; }
  else if (b < nb0+nb1){ s=s1; d=d1; Eg=E1; lb=b-nb0; cur=cursor_all+NN; col=c1; }
  else { s=s2; d=d2; Eg=E2; lb=b-nb0-nb1; cur=cursor_all+2*NN; col=c2; }
  int i = lb*256 + threadIdx.x;
  if (i >= Eg) return;
  int slot = atomicAdd(&cur[d[i]], 1);
  col[slot] = s[i];
}

// ---------------- weight prep ----------------
__global__ void k_transpose_t(const float* __restrict__ W, f16* __restrict__ WT,
                              int K, int Nc){
  __shared__ float tile[32][33];
  int n0 = blockIdx.x*32, k0 = blockIdx.y*32;
  int tx = threadIdx.x, ty = threadIdx.y;
  #pragma unroll
  for (int i=0;i<32;i+=8)
    tile[ty+i][tx] = W[(long)(k0+ty+i)*Nc + n0+tx];
  __syncthreads();
  #pragma unroll
  for (int i=0;i<32;i+=8)
    WT[(long)(n0+ty+i)*K + k0+tx] = (f16)tile[tx][ty+i];
}

__global__ void k_pack_wc(const float* __restrict__ Wc, const float* __restrict__ rW,
                          f16* __restrict__ WT){
  int idx = blockIdx.x*256 + threadIdx.x;
  if (idx >= 128*512) return;
  int n = idx >> 9; int k = idx & 511;
  float v = 0.f;
  if (n < 40) v = Wc[k*40 + n];
  else if (n < 80) v = rW[k*40 + (n-40)];
  WT[idx] = (f16)v;
}

// ---------------- wide-tile GEMM: C (Np x 512) = A * B^T, 3 tasks in one grid
// BM=128, BN=512, 512 threads = 8 waves, wave = 128x64 sub-tile = one head.
// LDS 2 x (A 16KB + B 64KB) = 160KB. CVT=true: A fp32, reg-staged convert,
// phase-split counted-vmcnt pipeline (B-half || MFMA ks, setprio on MFMA).
template<bool CVT>
__global__ __launch_bounds__(512,1) void k_gemmw(
    const void* __restrict__ A0v, const void* __restrict__ A1v, const void* __restrict__ A2v,
    f16* __restrict__ C0, f16* __restrict__ C1, f16* __restrict__ C2,
    const f16* __restrict__ B,
    const float* __restrict__ alp, const float* __restrict__ arp,
    float* __restrict__ elp, float* __restrict__ erp)
{
  constexpr int K = CVT ? KK0 : FF;
  constexpr int nt = K >> 6;
  __shared__ f16 lds[2][40960];   // per buf: A 128x64 (16KB) + B 512x64 (64KB)

  const int nwg = gridDim.x;               // 237
  const int qd = nwg>>3, rd = nwg&7;
  const int xcd = blockIdx.x & 7, bx = blockIdx.x >> 3;
  const int wid = (xcd < rd ? xcd*(qd+1) : rd*(qd+1) + (xcd-rd)*qd) + bx;
  const int task = wid / 79;
  const int tr = wid - task*79;

  f16* C = task==0?C0:(task==1?C1:C2);

  const int t = threadIdx.x;
  const int wave = t >> 6, lane = t & 63;
  const int slot = (lane&7) ^ (lane>>3);
  const int arow0 = t >> 3;                 // 0..63 (also covers arow0+64)
  const int ak8 = t & 7;

  // B staging half: 4 x global_load_lds per thread (256 rows x 64 k)
  #define GLDSB_H(kt, buf, half) { \
    int ko = (kt)*64; \
    _Pragma("unroll") \
    for (int i=(half)*4; i<(half)*4+4; i++){ \
      int br = i*64 + wave*8 + (lane>>3); \
      __builtin_amdgcn_global_load_lds((const AS1 void*)(B + (long)br*K + ko + slot*8), \
          (AS3 void*)(&lds[buf][8192 + i*4096 + wave*512]), 16, 0, 0); \
    } }
  #define GLDSB(kt, buf) { GLDSB_H(kt, buf, 0); GLDSB_H(kt, buf, 1); }

  // fragment addresses (byte offsets into lds[buf])
  int abyte[2][8], bbyte[2][4];
  #pragma unroll
  for (int ks=0;ks<2;ks++){
    #pragma unroll
    for (int m=0;m<8;m++){
      int row = m*16 + (lane&15);
      abyte[ks][m] = row*128 + (((ks*4 + (lane>>4))*16) ^ ((row&7)<<4));
    }
    #pragma unroll
    for (int n=0;n<4;n++){
      int brow = wave*64 + n*16 + (lane&15);
      bbyte[ks][n] = 16384 + brow*128 + (((ks*4 + (lane>>4))*16) ^ ((brow&7)<<4));
    }
  }

  f32x4 zero4 = {0.f,0.f,0.f,0.f};
  f32x4 acc[8][4];
  #pragma unroll
  for (int m=0;m<8;m++)
    #pragma unroll
    for (int n=0;n<4;n++) acc[m][n] = zero4;

  #define MFMA_KS(buf, ks) { \
    const char* Ls = (const char*)&lds[buf][0]; \
    f16x8 bf[4]; \
    _Pragma("unroll") \
    for (int n=0;n<4;n++) bf[n] = *(const f16x8*)(Ls + bbyte[ks][n]); \
    _Pragma("unroll") \
    for (int m=0;m<8;m++){ \
      f16x8 af = *(const f16x8*)(Ls + abyte[ks][m]); \
      _Pragma("unroll") \
      for (int n=0;n<4;n++) \
        acc[m][n] = __builtin_amdgcn_mfma_f32_16x16x32_f16(af, bf[n], acc[m][n], 0, 0, 0); \
    } }

  int cur = 0;
  if constexpr (CVT){
    // ---- fp32 A, reg-staged conversion, phase-split counted-vmcnt pipeline ----
    const float* Af = task==0?(const float*)A0v:(task==1?(const float*)A1v:(const float*)A2v);
    const float* gA[2];
    bool okA[2];
    #pragma unroll
    for (int s=0;s<2;s++){
      int grow = tr*128 + arow0 + s*64;
      okA[s] = grow < NN;
      gA[s] = Af + (long)(okA[s] ? grow : 0)*KK0 + ak8*8;
    }
    f32x4 arE[2][2];   // [row-slot][half] -- static indices ONLY

    #define LOADA(kt) { \
      _Pragma("unroll") \
      for (int s=0;s<2;s++){ \
        arE[s][0] = *(const f32x4*)(gA[s] + (kt)*64); \
        arE[s][1] = *(const f32x4*)(gA[s] + (kt)*64 + 4); \
      } }
    #define WRITEA(buf) { \
      _Pragma("unroll") \
      for (int s=0;s<2;s++){ \
        int row = arow0 + s*64; \
        f16x8 v; \
        _Pragma("unroll") \
        for (int j=0;j<4;j++){ \
          v[j]   = okA[s] ? (f16)arE[s][0][j] : (f16)0.f; \
          v[4+j] = okA[s] ? (f16)arE[s][1][j] : (f16)0.f; \
        } \
        *(f16x8*)(&lds[buf][row*64 + ((ak8 ^ (arow0&7))*8)]) = v; \
      } }

    LOADA(0);                      // vm: L_A(0)=4
    __builtin_amdgcn_sched_barrier(0);
    GLDSB(0, 0);                   // +8
    __builtin_amdgcn_sched_barrier(0);
    WRITEA(0);                     // compiler waits L_A(0) -> vmcnt(8)
    __builtin_amdgcn_sched_barrier(0);
    LOADA(1);                      // +4
    __builtin_amdgcn_sched_barrier(0);
    asm volatile("s_waitcnt vmcnt(4) lgkmcnt(0)" ::: "memory");  // B staged; L_A(1) flying
    __builtin_amdgcn_s_barrier();
    __builtin_amdgcn_sched_barrier(0);

    for (int kt=0; kt<nt; kt++){
      if (kt+1 < nt){
        GLDSB_H(kt+1, cur^1, 0);   // B rows 0-255 of next tile (early issue)
        __builtin_amdgcn_sched_barrier(0);
        WRITEA(cur^1);             // waits L_A(kt+1) -> vmcnt(4)
        __builtin_amdgcn_sched_barrier(0);
      }
      __builtin_amdgcn_s_setprio(1);
      MFMA_KS(cur, 0);
      __builtin_amdgcn_s_setprio(0);
      __builtin_amdgcn_sched_barrier(0);
      if (kt+1 < nt){
        GLDSB_H(kt+1, cur^1, 1);   // B rows 256-511 of next tile
        __builtin_amdgcn_sched_barrier(0);
      }
      if (kt+2 < nt){
        LOADA(kt+2);               // +4, newest in queue
        __builtin_amdgcn_sched_barrier(0);
      }
      __builtin_amdgcn_s_setprio(1);
      MFMA_KS(cur, 1);
      __builtin_amdgcn_s_setprio(0);
      __builtin_amdgcn_sched_barrier(0);
      if (kt+1 < nt){
        if (kt+2 < nt)
          asm volatile("s_waitcnt vmcnt(4) lgkmcnt(0)" ::: "memory");  // drain B; keep L_A
        else
          asm volatile("s_waitcnt vmcnt(0) lgkmcnt(0)" ::: "memory");
        __builtin_amdgcn_s_barrier();
        __builtin_amdgcn_sched_barrier(0);
      }
      cur ^= 1;
    }
    #undef LOADA
    #undef WRITEA
  } else {
    // ---- f16 A via global_load_lds, simple double-buffered loop ----
    const f16* Ah = task==0?(const f16*)A0v:(task==1?(const f16*)A1v:(const f16*)A2v);
    const f16* Ab = Ah + (long)tr*128*K;
    const int r8 = lane>>3;

    #define GLDSA(kt, buf) { \
      _Pragma("unroll") \
      for (int s=0;s<2;s++){ \
        int arow = wave*8 + r8 + s*64; \
        __builtin_amdgcn_global_load_lds((const AS1 void*)(Ab + (long)arow*K + (kt)*64 + slot*8), \
            (AS3 void*)(&lds[buf][s*4096 + wave*512]), 16, 0, 0); \
      } }

    GLDSA(0, 0);
    GLDSB(0, 0);
    __syncthreads();
    for (int kt=0; kt<nt; kt++){
      if (kt+1 < nt){
        GLDSA(kt+1, cur^1);
        GLDSB(kt+1, cur^1);
      }
      MFMA_KS(cur, 0);
      MFMA_KS(cur, 1);
      __syncthreads();
      cur ^= 1;
    }
    #undef GLDSA
  }
  #undef GLDSB
  #undef GLDSB_H
  #undef MFMA_KS

  // ---- C write: row = m*16 + (lane>>4)*4 + q, col = wave*64 + n*16 + (lane&15)
  #pragma unroll
  for (int m=0;m<8;m++){
    int row0 = tr*128 + m*16 + ((lane>>4)<<2);
    #pragma unroll
    for (int n=0;n<4;n++){
      int col = wave*64 + n*16 + (lane&15);
      #pragma unroll
      for (int q2=0;q2<4;q2++)
        C[(long)(row0+q2)*FF + col] = (f16)acc[m][n][q2];
    }
  }

  // ---- el/er epilogue: wave == head
  {
    const int head = wave;
    const float* alh = alp + head*64;
    const float* arh = arp + head*64;
    float alv[4], arv[4];
    #pragma unroll
    for (int n=0;n<4;n++){ int d = n*16 + (lane&15); alv[n]=alh[d]; arv[n]=arh[d]; }
    float* elo = elp + (long)task*NN*8;
    float* ero = erp + (long)task*NN*8;
    #pragma unroll
    for (int m=0;m<8;m++){
      float e0,e1,e2,e3,r0,r1,r2,r3;
      #pragma unroll
      for (int qq=0;qq<4;qq++){
        float e=0.f, rr=0.f;
        #pragma unroll
        for (int n=0;n<4;n++){ e += acc[m][n][qq]*alv[n]; rr += acc[m][n][qq]*arv[n]; }
        #pragma unroll
        for (int off=1; off<16; off<<=1){ e += __shfl_xor(e, off); rr += __shfl_xor(rr, off); }
        if (qq==0){e0=e;r0=rr;} else if (qq==1){e1=e;r1=rr;} else if (qq==2){e2=e;r2=rr;} else {e3=e;r3=rr;}
      }
      int qq = lane&15;
      if (qq < 4){
        int node = tr*128 + m*16 + ((lane>>4)<<2) + qq;
        if (node < NN){
          float ev = qq==0?e0:(qq==1?e1:(qq==2?e2:e3));
          float rv = qq==0?r0:(qq==1?r1:(qq==2?r2:r3));
          long o = (long)node*8 + head;
          elo[o] = ev;
          ero[o] = rv;
        }
      }
    }
  }
}

// ---------------- classifier GEMM (4 tasks, Nc=128, K=512) ----------------
struct GemmTasks { const f16* A[4]; const f16* B[4]; f16* C[4]; };

__global__ __launch_bounds__(256,3) void k_gemmb(GemmTasks p, int ntpb, int ntn,
                                                 int Nc, int K){
  __shared__ f16 lds[2][12288];
  const int bid = blockIdx.x;
  const int task = bid / ntpb;
  const int orig = bid - task*ntpb;
  const int q = ntpb >> 3, r = ntpb & 7;
  const int xcd = orig & 7, bx = orig >> 3;
  const int wid = (xcd < r ? xcd*(q+1) : r*(q+1) + (xcd-r)*q) + bx;
  const int tr = wid / ntn, tc = wid - tr*ntn;

  const f16* A = p.A[task];
  const f16* B = p.B[task];
  f16* C = p.C[task];

  const int t = threadIdx.x;
  const int wave = t >> 6, lane = t & 63;
  const int wr = wave >> 1, wc = wave & 1;

  const f16* Ab = A + (long)tr*64*K;
  const f16* Bb = B + (long)tc*128*K;

  const int slot = (lane&7) ^ (lane>>3);
  const int rbase = wave*8 + (lane>>3);

  f32x4 zero4 = {0.f,0.f,0.f,0.f};
  f32x4 acc[2][4];
  #pragma unroll
  for (int m=0;m<2;m++)
    #pragma unroll
    for (int n=0;n<4;n++) acc[m][n] = zero4;

  int abyte[2][2], bbyte[2][4];
  #pragma unroll
  for (int ks=0;ks<2;ks++){
    #pragma unroll
    for (int m=0;m<2;m++){
      int row = wr*32 + m*16 + (lane&15);
      abyte[ks][m] = row*128 + (((ks*4 + (lane>>4))*16) ^ ((row&7)<<4));
    }
    #pragma unroll
    for (int n=0;n<4;n++){
      int brow = wc*64 + n*16 + (lane&15);
      bbyte[ks][n] = 8192 + brow*128 + (((ks*4 + (lane>>4))*16) ^ ((brow&7)<<4));
    }
  }

  const int nt = K >> 6;
  int cur = 0;

  #pragma unroll
  for (int i=0;i<2;i++)
    __builtin_amdgcn_global_load_lds((const AS1 void*)(Ab + (i*32+rbase)*K + slot*8),
        (AS3 void*)(&lds[0][i*2048 + wave*512]), 16, 0, 0);
  #pragma unroll
  for (int i=0;i<4;i++)
    __builtin_amdgcn_global_load_lds((const AS1 void*)(Bb + (i*32+rbase)*K + slot*8),
        (AS3 void*)(&lds[0][4096 + i*2048 + wave*512]), 16, 0, 0);
  __syncthreads();

  for (int kt=0; kt<nt; kt++){
    if (kt+1 < nt){
      int ko = (kt+1)<<6;
      #pragma unroll
      for (int i=0;i<2;i++)
        __builtin_amdgcn_global_load_lds((const AS1 void*)(Ab + ko + (i*32+rbase)*K + slot*8),
            (AS3 void*)(&lds[cur^1][i*2048 + wave*512]), 16, 0, 0);
      #pragma unroll
      for (int i=0;i<4;i++)
        __builtin_amdgcn_global_load_lds((const AS1 void*)(Bb + ko + (i*32+rbase)*K + slot*8),
            (AS3 void*)(&lds[cur^1][4096 + i*2048 + wave*512]), 16, 0, 0);
    }
    const char* Ls = (const char*)&lds[cur][0];
    #pragma unroll
    for (int ks=0;ks<2;ks++){
      f16x8 af[2], bf[4];
      #pragma unroll
      for (int m=0;m<2;m++) af[m] = *(const f16x8*)(Ls + abyte[ks][m]);
      #pragma unroll
      for (int n=0;n<4;n++) bf[n] = *(const f16x8*)(Ls + bbyte[ks][n]);
      #pragma unroll
      for (int m=0;m<2;m++)
        #pragma unroll
        for (int n=0;n<4;n++)
          acc[m][n] = __builtin_amdgcn_mfma_f32_16x16x32_f16(af[m], bf[n], acc[m][n], 0, 0, 0);
    }
    __syncthreads();
    cur ^= 1;
  }

  #pragma unroll
  for (int m=0;m<2;m++){
    int row0 = tr*64 + wr*32 + m*16 + ((lane>>4)<<2);
    #pragma unroll
    for (int n=0;n<4;n++){
      int col = tc*128 + wc*64 + n*16 + (lane&15);
      #pragma unroll
      for (int q2=0;q2<4;q2++)
        C[(long)(row0+q2)*Nc + col] = (f16)acc[m][n][q2];
    }
  }
}

// ---------------- attention aggregation (batched over graphs) ----------------
#define MAXD 128

struct AggArgs {
  const int* rp[3]; const int* cs[3];
  const float* el; const float* er;
  const f16* feat[3];
  const float* bias;
  f16* outH[3];
  float* outF[3];
};

__global__ __launch_bounds__(256) void k_agg_b(AggArgs a){
  int b = blockIdx.x;
  int g = b / NN, n = b - g*NN;
  const int* rowptr = a.rp[g];
  const int* colsrc = a.cs[g];
  const float* el = a.el + (long)g*NN*8;
  const f16* featH = a.feat[g];
  int t = threadIdx.x;
  __shared__ float sm[MAXD*8];
  __shared__ int   scol[MAXD];
  __shared__ float red[256];
  __shared__ float inv[8];
  __shared__ float ern[8];
  if (t < 8) ern[t] = a.er[((long)g*NN+n)*8+t];
  __syncthreads();
  int j0 = rowptr[n], deg = rowptr[n+1]-j0;
  int h2 = t >> 5;
  int c = t*2;
  float a0=0.f, a1=0.f;

  if (deg <= MAXD){
    // ---- fast path: no per-iter bounds branch, unrolled gather ----
    {
      int h = t & 7;
      float dsum = 0.f;
      for (int jj = t>>3; jj < deg; jj += 32){
        int s = colsrc[j0+jj];
        float v = el[s*8+h] + ern[h];
        v = (v>0.f)? v : 0.2f*v;
        float ex = __expf(v);
        dsum += ex;
        sm[jj*8+h] = ex;
        if (h==0) scol[jj] = s;
      }
      red[t] = dsum; __syncthreads();
      if (t<128) red[t] += red[t+128]; __syncthreads();
      if (t<64)  red[t] += red[t+64];  __syncthreads();
      if (t<32)  red[t] += red[t+32];  __syncthreads();
      if (t<16)  red[t] += red[t+16];  __syncthreads();
      if (t<8)   inv[t] = 1.0f / (red[t] + red[t+8]);
      __syncthreads();
    }
    float ivh = inv[h2];
    int jj = 0;
    for (; jj+4<=deg; jj+=4){
      int s0=scol[jj], s1=scol[jj+1], s2=scol[jj+2], s3=scol[jj+3];
      float x0=sm[(jj+0)*8+h2], x1=sm[(jj+1)*8+h2], x2=sm[(jj+2)*8+h2], x3=sm[(jj+3)*8+h2];
      f16x2 f0 = *(const f16x2*)(featH + (long)s0*FF + c);
      f16x2 f1 = *(const f16x2*)(featH + (long)s1*FF + c);
      f16x2 f2 = *(const f16x2*)(featH + (long)s2*FF + c);
      f16x2 f3 = *(const f16x2*)(featH + (long)s3*FF + c);
      a0 += x0*(float)f0[0] + x1*(float)f1[0] + x2*(float)f2[0] + x3*(float)f3[0];
      a1 += x0*(float)f0[1] + x1*(float)f1[1] + x2*(float)f2[1] + x3*(float)f3[1];
    }
    for (; jj<deg; jj++){
      int s = scol[jj];
      float x = sm[jj*8+h2];
      f16x2 f = *(const f16x2*)(featH + (long)s*FF + c);
      a0 += x*(float)f[0];
      a1 += x*(float)f[1];
    }
    a0 *= ivh; a1 *= ivh;
  } else {
    // ---- slow path (deg > MAXD; statistically never for these graphs) ----
    {
      int h = t & 7;
      float dsum = 0.f;
      for (int jj = t>>3; jj < deg; jj += 32){
        int s = colsrc[j0+jj];
        float v = el[s*8+h] + ern[h];
        v = (v>0.f)? v : 0.2f*v;
        float ex = __expf(v);
        dsum += ex;
        if (jj < MAXD){
          sm[jj*8+h] = ex;
          if (h==0) scol[jj] = s;
        }
      }
      red[t] = dsum; __syncthreads();
      if (t<128) red[t] += red[t+128]; __syncthreads();
      if (t<64)  red[t] += red[t+64];  __syncthreads();
      if (t<32)  red[t] += red[t+32];  __syncthreads();
      if (t<16)  red[t] += red[t+16];  __syncthreads();
      if (t<8)   inv[t] = 1.0f / (red[t] + red[t+8]);
      __syncthreads();
    }
    float ivh = inv[h2];
    for (int jj=0; jj<deg; jj++){
      int s; float ex;
      if (jj < MAXD){ s = scol[jj]; ex = sm[jj*8+h2]; }
      else {
        s = colsrc[j0+jj];
        float v = el[s*8+h2] + ern[h2];
        v = (v>0.f)? v : 0.2f*v;
        ex = __expf(v);
      }
      float alpha = ex * ivh;
      f16x2 f = *(const f16x2*)(featH + (long)s*FF + c);
      a0 += alpha*(float)f[0];
      a1 += alpha*(float)f[1];
    }
  }

  a0 += a.bias[c]; a1 += a.bias[c+1];
  a0 = (a0>0.f)? a0 : __expf(a0)-1.f;
  a1 = (a1>0.f)? a1 : __expf(a1)-1.f;
  f16x2 o; o[0]=(f16)a0; o[1]=(f16)a1;
  *(f16x2*)(a.outH[g] + (long)n*FF + c) = o;
  float* oF = a.outF[g];
  if (oF){
    oF[(long)n*FF + c]     = a0;
    oF[(long)n*FF + c + 1] = a1;
  }
}

// classifier el/er over 4 tasks
__global__ void k_elerc_b(const f16* __restrict__ fc,
    const float* __restrict__ alc0, const float* __restrict__ arc0,
    const float* __restrict__ alc1, const float* __restrict__ arc1,
    float* __restrict__ el, float* __restrict__ er){
  int idx = blockIdx.x*256 + threadIdx.x;
  if (idx >= 4*NN*8) return;
  int ti = idx / (NN*8);
  int rem = idx - ti*NN*8;
  int n = rem>>3, hh = rem&7;
  const f16* featc = fc + (long)ti*NP*128;
  const float* al = (ti&1) ? alc1 : alc0;
  const float* ar_ = (ti&1) ? arc1 : arc0;
  float a=0.f, bsum=0.f;
  #pragma unroll
  for (int cc=0; cc<5; cc++){
    float v = (float)featc[(long)n*128 + hh*5 + cc];
    a += v*al[hh*5+cc];
    bsum += v*ar_[hh*5+cc];
  }
  el[idx]=a; er[idx]=bsum;
}

struct ClsArgs {
  const int* rp[3]; const int* cs[3];
  const float* el; const float* er;
  const f16* fc;
  const float* bc[2];
  float* pred;
};

__global__ __launch_bounds__(64) void k_cls_b(ClsArgs a){
  int b = blockIdx.x;
  int ti = b / NN, n = b - ti*NN;
  int g = ti<2 ? ti : 2;
  int ci = ti&1;
  const int* rowptr = a.rp[g];
  const int* colsrc = a.cs[g];
  const float* el = a.el + (long)ti*NN*8;
  const f16* featc = a.fc + (long)ti*NP*128;
  const float* bc = a.bc[ci];
  float* pred = a.pred + (long)ti*5*NN;
  int l = threadIdx.x;
  __shared__ float sm[MAXD*8];
  __shared__ int   scol[MAXD];
  __shared__ float inv[8];
  __shared__ float ern[8];
  __shared__ float lg[40];
  if (l<8) ern[l] = a.er[((long)ti*NN+n)*8+l];
  __syncthreads();
  int j0 = rowptr[n], deg = rowptr[n+1]-j0;

  if (deg <= MAXD){
    {
      int h = l & 7;
      float dsum = 0.f;
      for (int jj = l>>3; jj < deg; jj += 8){
        int s = colsrc[j0+jj];
        float v = el[s*8+h] + ern[h];
        v = (v>0.f)? v : 0.2f*v;
        float ex = __expf(v);
        dsum += ex;
        sm[jj*8+h] = ex;
        if (h==0) scol[jj] = s;
      }
      dsum += __shfl_xor(dsum, 8);
      dsum += __shfl_xor(dsum, 16);
      dsum += __shfl_xor(dsum, 32);
      if (l<8) inv[l] = 1.0f/dsum;
    }
    __syncthreads();
    if (l<40){
      int h = l/5;
      float ivh = inv[h];
      float acc = 0.f;
      int jj = 0;
      for (; jj+4<=deg; jj+=4){
        int s0=scol[jj], s1=scol[jj+1], s2=scol[jj+2], s3=scol[jj+3];
        float x0=sm[(jj+0)*8+h], x1=sm[(jj+1)*8+h], x2=sm[(jj+2)*8+h], x3=sm[(jj+3)*8+h];
        float v0=(float)featc[(long)s0*128 + l];
        float v1=(float)featc[(long)s1*128 + l];
        float v2=(float)featc[(long)s2*128 + l];
        float v3=(float)featc[(long)s3*128 + l];
        acc += x0*v0 + x1*v1 + x2*v2 + x3*v3;
      }
      for (; jj<deg; jj++)
        acc += sm[jj*8+h] * (float)featc[(long)scol[jj]*128 + l];
      acc *= ivh;
      acc += (float)featc[(long)n*128 + 40 + l];
      acc += bc[l];
      lg[l] = acc;
    }
  } else {
    {
      int h = l & 7;
      float dsum = 0.f;
      for (int jj = l>>3; jj < deg; jj += 8){
        int s = colsrc[j0+jj];
        float v = el[s*8+h] + ern[h];
        v = (v>0.f)? v : 0.2f*v;
        float ex = __expf(v);
        dsum += ex;
        if (jj < MAXD){
          sm[jj*8+h] = ex;
          if (h==0) scol[jj] = s;
        }
      }
      dsum += __shfl_xor(dsum, 8);
      dsum += __shfl_xor(dsum, 16);
      dsum += __shfl_xor(dsum, 32);
      if (l<8) inv[l] = 1.0f/dsum;
    }
    __syncthreads();
    if (l<40){
      int h = l/5;
      float ivh = inv[h];
      float acc = 0.f;
      for (int jj=0; jj<deg; jj++){
        int s; float ex;
        if (jj < MAXD){ s = scol[jj]; ex = sm[jj*8+h]; }
        else {
          s = colsrc[j0+jj];
          float v = el[s*8+h] + ern[h];
          v = (v>0.f)? v : 0.2f*v;
          ex = __expf(v);
        }
        acc += ex*ivh * (float)featc[(long)s*128 + l];
      }
      acc += (float)featc[(long)n*128 + 40 + l];
      acc += bc[l];
      lg[l] = acc;
    }
  }
  __syncthreads();
  if (l<5){
    float p=0.f;
    #pragma unroll
    for (int h=0;h<8;h++) p += lg[h*5+l];
    pred[(long)n*5 + l] = p*0.125f;
  }
}

// ---------------- host orchestration ----------------
extern "C" void kernel_launch(void* const* d_in, const int* in_sizes, int n_in,
                              void* d_out, int out_size, void* d_ws, size_t ws_size,
                              hipStream_t stream){
  const int* srcs[3] = {(const int*)d_in[0], (const int*)d_in[2], (const int*)d_in[4]};
  const int* dsts[3] = {(const int*)d_in[1], (const int*)d_in[3], (const int*)d_in[5]};
  int E[3] = {in_sizes[0], in_sizes[2], in_sizes[4]};
  const float* X[3] = {(const float*)d_in[6], (const float*)d_in[7], (const float*)d_in[8]};
  const float* W0  = (const float*)d_in[9];
  const float* al0 = (const float*)d_in[10];
  const float* ar0 = (const float*)d_in[11];
  const float* b0  = (const float*)d_in[12];
  const float* W1  = (const float*)d_in[13];
  const float* al1 = (const float*)d_in[14];
  const float* ar1 = (const float*)d_in[15];
  const float* b1  = (const float*)d_in[16];
  const float* Wcv[2] = {(const float*)d_in[17], (const float*)d_in[22]};
  const float* alc[2] = {(const float*)d_in[18], (const float*)d_in[23]};
  const float* arc[2] = {(const float*)d_in[19], (const float*)d_in[24]};
  const float* bcv[2] = {(const float*)d_in[20], (const float*)d_in[25]};
  const float* rWv[2] = {(const float*)d_in[21], (const float*)d_in[26]};

  float* out = (float*)d_out;
  float* embOut[3] = {out+200000, out+200000+(long)NN*FF, out+200000+2L*NN*FF};

  char* w = (char*)d_ws;
  size_t off = 0;
  auto alloc = [&](size_t bytes)->void*{
    void* p = (void*)(w + off);
    off += (bytes + 255) & ~((size_t)255);
    return p;
  };
  f16* W0T = (f16*)alloc((size_t)FF*KK0*2);
  f16* W1T = (f16*)alloc((size_t)FF*FF*2);
  f16* WcT[2] = {(f16*)alloc(128*512*2), (f16*)alloc(128*512*2)};
  f16* feat0H[3], *h0H[3], *feat1H[3], *embH[3];
  for (int g=0;g<3;g++) feat0H[g] = (f16*)alloc((size_t)NP*FF*2);
  for (int g=0;g<3;g++) h0H[g]    = (f16*)alloc((size_t)NP*FF*2);
  for (int g=0;g<3;g++) feat1H[g] = (f16*)alloc((size_t)NP*FF*2);
  for (int g=0;g<3;g++) embH[g]   = (f16*)alloc((size_t)NP*FF*2);
  f16* featc = (f16*)alloc((size_t)4*NP*128*2);
  float* el_e = (float*)alloc((size_t)3*NN*8*4);
  float* er_e = (float*)alloc((size_t)3*NN*8*4);
  float* el_c = (float*)alloc((size_t)4*NN*8*4);
  float* er_c = (float*)alloc((size_t)4*NN*8*4);
  int* deg    = (int*)alloc((size_t)3*NN*4);
  int* cursor = (int*)alloc((size_t)3*NN*4);
  int* rowptr = (int*)alloc((size_t)3*(NN+1)*4);
  int* colsrc[3];
  for (int g=0;g<3;g++) colsrc[g] = (int*)alloc((size_t)E[g]*4);
  (void)ws_size; (void)n_in; (void)out_size;

  // ---- CSR (3 graphs, batched) ----
  int nb[3] = {(E[0]+255)/256, (E[1]+255)/256, (E[2]+255)/256};
  hipMemsetAsync(deg, 0, (size_t)3*NN*4, stream);
  k_count_b<<<nb[0]+nb[1]+nb[2], 256, 0, stream>>>(dsts[0], dsts[1], dsts[2],
      E[0], E[1], E[2], nb[0], nb[1], deg);
  k_scan_b<<<3, 1024, 0, stream>>>(deg, rowptr, cursor);
  k_fill_b<<<nb[0]+nb[1]+nb[2], 256, 0, stream>>>(srcs[0], dsts[0], srcs[1], dsts[1],
      srcs[2], dsts[2], E[0], E[1], E[2], nb[0], nb[1], cursor,
      colsrc[0], colsrc[1], colsrc[2]);

  // ---- weight prep ----
  k_transpose_t<<<dim3(FF/32, KK0/32), dim3(32,8), 0, stream>>>(W0, W0T, KK0, FF);
  k_transpose_t<<<dim3(FF/32, FF/32), dim3(32,8), 0, stream>>>(W1, W1T, FF, FF);
  k_pack_wc<<<(128*512+255)/256, 256, 0, stream>>>(Wcv[0], rWv[0], WcT[0]);
  k_pack_wc<<<(128*512+255)/256, 256, 0, stream>>>(Wcv[1], rWv[1], WcT[1]);

  const int* rp[3] = {rowptr, rowptr+(NN+1), rowptr+2*(NN+1)};

  // ---- layer 0: fused convert+GEMM+eler (wide tile), then aggregation ----
  k_gemmw<true><<<237, 512, 0, stream>>>(X[0], X[1], X[2],
      feat0H[0], feat0H[1], feat0H[2], W0T, al0, ar0, el_e, er_e);
  {
    AggArgs a;
    for (int g=0;g<3;g++){ a.rp[g]=rp[g]; a.cs[g]=colsrc[g]; a.feat[g]=feat0H[g];
                           a.outH[g]=h0H[g]; a.outF[g]=nullptr; }
    a.el = el_e; a.er = er_e; a.bias = b0;
    k_agg_b<<<3*NN, 256, 0, stream>>>(a);
  }

  // ---- layer 1: wide-tile GEMM+eler, then aggregation ----
  k_gemmw<false><<<237, 512, 0, stream>>>(h0H[0], h0H[1], h0H[2],
      feat1H[0], feat1H[1], feat1H[2], W1T, al1, ar1, el_e, er_e);
  {
    AggArgs a;
    for (int g=0;g<3;g++){ a.rp[g]=rp[g]; a.cs[g]=colsrc[g]; a.feat[g]=feat1H[g];
                           a.outH[g]=embH[g]; a.outF[g]=embOut[g]; }
    a.el = el_e; a.er = er_e; a.bias = b1;
    k_agg_b<<<3*NN, 256, 0, stream>>>(a);
  }

  // ---- classifiers (4 tasks batched): (g,c) = (0,0),(1,1),(2,0),(2,1) ----
  {
    GemmTasks p;
    const int tg[4] = {0,1,2,2};
    for (int i=0;i<4;i++){ p.A[i]=embH[tg[i]]; p.B[i]=WcT[i&1]; p.C[i]=featc + (long)i*NP*128; }
    k_gemmb<<<4*158, 256, 0, stream>>>(p, 158, 1, 128, FF);
  }
  k_elerc_b<<<(4*NN*8+255)/256, 256, 0, stream>>>(featc, alc[0], arc[0], alc[1], arc[1], el_c, er_c);
  {
    ClsArgs a;
    for (int g=0;g<3;g++){ a.rp[g]=rp[g]; a.cs[g]=colsrc[g]; }
    a.el = el_c; a.er = er_c; a.fc = featc;
    a.bc[0] = bcv[0]; a.bc[1] = bcv[1];
    a.pred = out;
    k_cls_b<<<4*NN, 64, 0, stream>>>(a);
  }
}